// Round 13
// baseline (459.255 us; speedup 1.0000x reference)
//
#include <hip/hip_runtime.h>
#include <hip/hip_bf16.h>
#include <cstddef>
#include <cstdint>

typedef __hip_bfloat16 bf16;
typedef __attribute__((ext_vector_type(8))) short bf16x8;   // 8 bf16 = 4 VGPRs
typedef __attribute__((ext_vector_type(4))) float f32x4;

#define NPT 4096   // points per cloud
#define BB  4      // batch
#define NBR 16     // neighbors (nsample)
#define WD  16     // weightnet output width
#define CDIM 64    // input feature channels
#define MIDD 128   // lin1/lin2 output channels

// async global->LDS, 16B per lane; LDS dest is wave-uniform base + lane*16
#define GLD16(g, l) __builtin_amdgcn_global_load_lds( \
    (const __attribute__((address_space(1))) unsigned int*)(const void*)(g), \
    (__attribute__((address_space(3))) unsigned int*)(void*)(l), 16, 0, 0)

// ---------------------------------------------------------------------------
// Fused prelude kernel: blocks [0,4096) run KNN v7; blocks [4096,6912) run
// prep (feature transposes + weight hi/lo splits). The two are independent;
// fusing lets prep's bandwidth work overlap knn's latency-bound blocks.
//
// KNN v7: two-pass threshold selection, 32 segments x min-only pass 1.
//  - Block = 8 queries x 32 segments; segment s covers per-chunk candidate
//    range [s*32, s*32+32) across 4 staged 1024-candidate chunks.
//  - Pass 1 tracks ONLY the segment minimum (1 fminf/cand vs max+min+min).
//  - Gate = 16th smallest of the 32 published minima ((value, seg) rank):
//    the 32 minima are 32 DISTINCT candidates, so >=16 candidates have
//    d <= gate >= true d16 -> gating drops no true top-16 member.
//  - Segments with min <= gate (about 16) go to a worklist; pass 2 rescans
//    them cooperatively (8-lane units, direct global float4 reads).
//  - Distance chain is the identical fmaf expression everywhere -> survivor
//    set superset of top-16; final exact (d, idx) rank-select => output
//    bit-identical to rounds 4-12.
// ---------------------------------------------------------------------------
#define KQ     8      // queries per block
#define KSEG   32     // segments per query
#define KCHW   32     // candidates per segment per staged chunk
#define KSTAGE 1024
#define KRING  160

__global__ __launch_bounds__(256)
void pre_kernel(const float* __restrict__ pcA, const float* __restrict__ pcB,
                int* __restrict__ idxAB, int* __restrict__ idxBA,
                const float* __restrict__ feat1, const float* __restrict__ feat2,
                float* __restrict__ p1pm, bf16* __restrict__ p1b,
                float* __restrict__ p2pm, bf16* __restrict__ p2b,
                const float* __restrict__ lin1_w, bf16* __restrict__ b1hi, bf16* __restrict__ b1lo,
                const float* __restrict__ lin2_w, bf16* __restrict__ b2hi, bf16* __restrict__ b2lo)
{
    const int bid = blockIdx.x;
    const int tid = threadIdx.x;

    if (bid < 4096) {
        // =================== KNN v7 ===================
        __shared__ float4 cf[KSTAGE + KSTAGE / KCHW];  // skewed (+1 per 32)
        __shared__ float  pubd[KSEG][KQ];
        __shared__ float4 qc[KQ];
        __shared__ float  u16s[KQ];
        __shared__ int    rcnt[KQ];
        __shared__ int    wtot;
        __shared__ int    wl[KQ * KSEG];
        __shared__ float  ringd[KQ][KRING + 1];
        __shared__ int    ringi[KQ][KRING + 1];

        const int dir = bid >> 11;            // 0: A->B, 1: B->A
        const int b   = (bid >> 9) & 3;
        const int g   = bid & 511;
        const float* qxyz = dir ? pcB : pcA;
        const float* cxyz = dir ? pcA : pcB;
        int* idx_out      = dir ? idxBA : idxAB;

        const int q = tid & (KQ - 1);
        const int s = tid >> 3;               // segment 0..31
        const int n = g * KQ + q;

        const float* qp = qxyz + (size_t)b * 3 * NPT;
        const float qx = qp[n], qy = qp[NPT + n], qz = qp[2 * NPT + n];
        const float q2 = fmaf(qx, qx, fmaf(qy, qy, qz * qz));
        const float* c = cxyz + (size_t)b * 3 * NPT;

        if (tid < KQ) rcnt[tid] = 0;
        if (tid == 0) wtot = 0;
        if (s == 0) qc[q] = make_float4(qx, qy, qz, q2);

        // ---- pass 1: per-(q,s) minimum over the segment ----
        float b0 = 3.4e38f;
        for (int st = 0; st < NPT; st += KSTAGE) {
            __syncthreads();
            {   // stage 4 candidates per thread, skew every 32
                const int j4 = tid * 4;
                const int gg = st + j4;
                const float4 xs = *(const float4*)(c + gg);
                const float4 ys = *(const float4*)(c + NPT + gg);
                const float4 zs = *(const float4*)(c + 2 * NPT + gg);
                const float xv[4] = { xs.x, xs.y, xs.z, xs.w };
                const float yv[4] = { ys.x, ys.y, ys.z, ys.w };
                const float zv[4] = { zs.x, zs.y, zs.z, zs.w };
                #pragma unroll
                for (int e = 0; e < 4; ++e) {
                    const int j = j4 + e;
                    cf[j + (j >> 5)] = make_float4(xv[e], yv[e], zv[e],
                        fmaf(xv[e], xv[e], fmaf(yv[e], yv[e], zv[e] * zv[e])));
                }
            }
            __syncthreads();
            const int base = s * (KCHW + 1);   // skewed segment base
            #pragma unroll 4
            for (int t = 0; t < KCHW; ++t) {
                const float4 pv = cf[base + t];
                const float dot = fmaf(qx, pv.x, fmaf(qy, pv.y, qz * pv.z));
                const float d = q2 + pv.w - 2.f * dot;
                b0 = fminf(b0, d);
            }
        }
        pubd[s][q] = b0;
        __syncthreads();

        // ---- gate: 16th smallest of the 32 minima (rank == 15) ----
        {
            float tv[KSEG];
            #pragma unroll
            for (int k = 0; k < KSEG; ++k) tv[k] = pubd[k][q];
            int rank = 0;
            #pragma unroll
            for (int k = 0; k < KSEG; ++k)
                rank += (tv[k] < b0 || (tv[k] == b0 && k < s)) ? 1 : 0;
            if (rank == 15) u16s[q] = b0;
        }
        __syncthreads();

        // ---- classify: flag segments whose minimum can pass the gate ----
        if (b0 <= u16s[q]) {
            const int u = atomicAdd(&wtot, 1);
            wl[u] = (q << 5) | s;
        }
        __syncthreads();

        // ---- pass 2: cooperative rescan of flagged segments (8-lane units) ----
        {
            const int W = wtot;
            const int lu = tid & 7;
            for (int u = tid >> 3; u < W; u += 32) {
                const int qq  = wl[u] >> 5;
                const int seg = wl[u] & 31;
                const float4 qv = qc[qq];
                const float gate = u16s[qq];
                #pragma unroll
                for (int ch = 0; ch < 4; ++ch) {
                    const int j = ch * KSTAGE + seg * KCHW + lu * 4;
                    const float4 xs = *(const float4*)(c + j);
                    const float4 ys = *(const float4*)(c + NPT + j);
                    const float4 zs = *(const float4*)(c + 2 * NPT + j);
                    const float xv[4] = { xs.x, xs.y, xs.z, xs.w };
                    const float yv[4] = { ys.x, ys.y, ys.z, ys.w };
                    const float zv[4] = { zs.x, zs.y, zs.z, zs.w };
                    #pragma unroll
                    for (int e = 0; e < 4; ++e) {
                        const float p2 = fmaf(xv[e], xv[e], fmaf(yv[e], yv[e], zv[e] * zv[e]));
                        const float dot = fmaf(qv.x, xv[e], fmaf(qv.y, yv[e], qv.z * zv[e]));
                        const float d = qv.w + p2 - 2.f * dot;
                        if (d <= gate) {
                            const int slot = atomicAdd(&rcnt[qq], 1);
                            if (slot < KRING) { ringd[qq][slot] = d; ringi[qq][slot] = j + e; }
                        }
                    }
                }
            }
        }
        __syncthreads();

        // ---- final: exact (d, idx) rank-select of top-16 from the ring ----
        {
            const int cnt = min(rcnt[q], KRING);
            int* op = idx_out + ((size_t)b * NPT + n) * NBR;
            for (int e = s; e < cnt; e += KSEG) {
                const float de = ringd[q][e];
                const int   ie = ringi[q][e];
                int rank = 0;
                for (int k = 0; k < cnt; ++k) {
                    const float dk = ringd[q][k];
                    const int   ik = ringi[q][k];
                    rank += (dk < de || (dk == de && ik < ie)) ? 1 : 0;
                }
                if (rank < NBR) op[rank] = ie;
            }
        }
    } else {
        // =================== prep ===================
        __shared__ float t[32][33];
        const int tx = tid & 31, ty = tid >> 5;
        const int id = bid - 4096;
        if (id < 2048) {
            const int which = id >> 10;
            const int nt = id & 1023;
            const int n0 = (nt & 127) * 32;
            const int c0 = ((nt >> 7) & 1) * 32;
            const int b  = nt >> 8;
            const float* in = which ? feat2 : feat1;
            float* out  = which ? p2pm : p1pm;
            bf16*  outb = which ? p2b  : p1b;
            #pragma unroll
            for (int r = ty; r < 32; r += 8)
                t[r][tx] = in[((size_t)b * CDIM + c0 + r) * NPT + n0 + tx];
            __syncthreads();
            #pragma unroll
            for (int r = ty; r < 32; r += 8) {
                const float v = t[tx][r];
                out [((size_t)b * NPT + n0 + r) * CDIM + c0 + tx] = v;
                outb[((size_t)b * NPT + n0 + r) * CDIM + c0 + tx] = __float2bfloat16(v);
            }
        } else {
            const float* w; bf16 *hi, *lo; int K, k0, o0;
            if (id < 2304) {
                const int id2 = id - 2048;
                w = lin1_w; hi = b1hi; lo = b1lo; K = 2048;
                k0 = (id2 & 63) * 32; o0 = (id2 >> 6) * 32;
            } else {
                const int id2 = id - 2304;
                w = lin2_w; hi = b2hi; lo = b2lo; K = 4096;
                k0 = (id2 & 127) * 32; o0 = (id2 >> 7) * 32;
            }
            #pragma unroll
            for (int r = ty; r < 32; r += 8)
                t[r][tx] = w[(size_t)(k0 + r) * MIDD + o0 + tx];
            __syncthreads();
            #pragma unroll
            for (int r = ty; r < 32; r += 8) {
                const float v = t[tx][r];
                const bf16 h = __float2bfloat16(v);
                const bf16 l2 = __float2bfloat16(v - __bfloat162float(h));
                hi[(size_t)(o0 + r) * K + k0 + tx] = h;
                lo[(size_t)(o0 + r) * K + k0 + tx] = l2;
            }
        }
    }
}

// ---------------------------------------------------------------------------
// Weightnet + aggregation: exact round-8 body (F[16] full prefetch, natural
// VGPR allocation ~132, direct global writes — 128 contiguous B per thread).
// ---------------------------------------------------------------------------
template<int D2, int PTS>
__global__ __launch_bounds__(256)
void agg_kernel(const float* __restrict__ qA, const float* __restrict__ cA,
                const float* __restrict__ ownA, const bf16* __restrict__ nbrA,
                const int* __restrict__ idxA,
                const float* __restrict__ qB, const float* __restrict__ cB,
                const float* __restrict__ ownB, const bf16* __restrict__ nbrB,
                const int* __restrict__ idxB, int Msplit,
                const float* __restrict__ w0, const float* __restrict__ b0,
                const float* __restrict__ w1, const float* __restrict__ b1,
                const float* __restrict__ w2, const float* __restrict__ b2,
                bf16* __restrict__ agg, int m0)
{
    constexpr int TPP   = 256 / PTS;
    constexpr int HALF  = TPP / 2;
    constexpr int WSTR  = 276;

    __shared__ float wp[248];
    __shared__ int   nb[PTS * NBR];
    __shared__ float wgt[PTS * WSTR];

    const int tid = threadIdx.x;
    const int mbase = m0 + (int)blockIdx.x * PTS;
    const bool second = mbase >= Msplit;
    const int mrow = second ? mbase - Msplit : mbase;
    const float* qxyz   = second ? qB   : qA;
    const float* cxyz   = second ? cB   : cA;
    const float* own_pm = second ? ownB : ownA;
    const bf16*  nbr_b  = second ? nbrB : nbrA;
    const int*   idx    = second ? idxB : idxA;
    const int b = mrow >> 12;
    const int nbase = mrow & (NPT - 1);

    if (tid < 248) {
        float v;
        if      (tid <  24) v = w0[tid];
        else if (tid <  32) v = b0[tid - 24];
        else if (tid <  96) v = w1[tid - 32];
        else if (tid < 104) v = b1[tid - 96];
        else if (tid < 232) v = w2[tid - 104];
        else                v = b2[tid - 232];
        wp[tid] = v;
    }
    if (tid < PTS * NBR)
        nb[tid] = idx[(size_t)mrow * NBR + tid];
    __syncthreads();

    const int p  = tid & (PTS - 1);
    const int dg = tid / PTS;

    uint2  F[NBR];
    float4 ow;
    if (dg >= HALF) {
        const int d0 = (dg - HALF) * 4;
        const bf16* base = nbr_b + (size_t)b * NPT * D2 + d0;
        #pragma unroll
        for (int k = 0; k < NBR; ++k) {
            const int j = nb[p * NBR + k];
            F[k] = *(const uint2*)(base + (size_t)j * D2);
        }
    } else {
        ow = *(const float4*)(own_pm + ((size_t)mrow + p) * D2 + dg * 4);
    }

    if (tid < PTS * NBR) {
        const int pp = tid / NBR, k = tid % NBR;
        const int n = nbase + pp;
        const int j = nb[tid];
        const float* q = qxyz + (size_t)b * 3 * NPT;
        const float* c = cxyz + (size_t)b * 3 * NPT;
        const float dx = c[j]           - q[n];
        const float dy = c[NPT + j]     - q[NPT + n];
        const float dz = c[2 * NPT + j] - q[2 * NPT + n];
        float h1[8], h2[8];
        #pragma unroll
        for (int o = 0; o < 8; ++o) {
            float v = wp[24 + o];
            v = fmaf(dx, wp[o], v);
            v = fmaf(dy, wp[8 + o], v);
            v = fmaf(dz, wp[16 + o], v);
            h1[o] = fmaxf(v, 0.f);
        }
        #pragma unroll
        for (int o = 0; o < 8; ++o) {
            float v = wp[96 + o];
            #pragma unroll
            for (int i = 0; i < 8; ++i) v = fmaf(h1[i], wp[32 + i * 8 + o], v);
            h2[o] = fmaxf(v, 0.f);
        }
        #pragma unroll
        for (int o = 0; o < WD; ++o) {
            float v = wp[232 + o];
            #pragma unroll
            for (int i = 0; i < 8; ++i) v = fmaf(h2[i], wp[104 + i * WD + o], v);
            wgt[pp * WSTR + k * WD + o] = fmaxf(v, 0.f);
        }
    }
    __syncthreads();

    const float* wg = wgt + p * WSTR;
    bf16* aout = agg + ((size_t)((int)blockIdx.x * PTS + p)) * (2 * D2 * WD);

    if (dg < HALF) {
        const int d0 = dg * 4;
        float sw[16];
        #pragma unroll
        for (int w = 0; w < 16; ++w) sw[w] = 0.f;
        #pragma unroll
        for (int k = 0; k < NBR; ++k) {
            const float4 v0 = *(const float4*)(wg + k * WD);
            const float4 v1 = *(const float4*)(wg + k * WD + 4);
            const float4 v2 = *(const float4*)(wg + k * WD + 8);
            const float4 v3 = *(const float4*)(wg + k * WD + 12);
            sw[0]  += v0.x; sw[1]  += v0.y; sw[2]  += v0.z; sw[3]  += v0.w;
            sw[4]  += v1.x; sw[5]  += v1.y; sw[6]  += v1.z; sw[7]  += v1.w;
            sw[8]  += v2.x; sw[9]  += v2.y; sw[10] += v2.z; sw[11] += v2.w;
            sw[12] += v3.x; sw[13] += v3.y; sw[14] += v3.z; sw[15] += v3.w;
        }
        const float od[4] = { ow.x, ow.y, ow.z, ow.w };
        #pragma unroll
        for (int di = 0; di < 4; ++di) {
            const float f = od[di];
            union { bf16 h[16]; uint4 q[2]; } pk;
            #pragma unroll
            for (int w = 0; w < 16; ++w) pk.h[w] = __float2bfloat16(f * sw[w]);
            bf16* dst = aout + (d0 + di) * WD;
            *(uint4*)dst       = pk.q[0];
            *(uint4*)(dst + 8) = pk.q[1];
        }
    } else {
        const int d0 = (dg - HALF) * 4;
        float acc[4][16];
        #pragma unroll
        for (int di = 0; di < 4; ++di)
            #pragma unroll
            for (int w = 0; w < 16; ++w) acc[di][w] = 0.f;
        #pragma unroll
        for (int k = 0; k < NBR; ++k) {
            union { uint2 u; bf16 h[4]; } uf;
            uf.u = F[k];
            float Fv[4];
            #pragma unroll
            for (int j = 0; j < 4; ++j) Fv[j] = __bfloat162float(uf.h[j]);
            const float4 v0 = *(const float4*)(wg + k * WD);
            const float4 v1 = *(const float4*)(wg + k * WD + 4);
            const float4 v2 = *(const float4*)(wg + k * WD + 8);
            const float4 v3 = *(const float4*)(wg + k * WD + 12);
            float w16[16];
            w16[0]  = v0.x; w16[1]  = v0.y; w16[2]  = v0.z; w16[3]  = v0.w;
            w16[4]  = v1.x; w16[5]  = v1.y; w16[6]  = v1.z; w16[7]  = v1.w;
            w16[8]  = v2.x; w16[9]  = v2.y; w16[10] = v2.z; w16[11] = v2.w;
            w16[12] = v3.x; w16[13] = v3.y; w16[14] = v3.z; w16[15] = v3.w;
            #pragma unroll
            for (int di = 0; di < 4; ++di)
                #pragma unroll
                for (int w = 0; w < 16; ++w)
                    acc[di][w] = fmaf(Fv[di], w16[w], acc[di][w]);
        }
        #pragma unroll
        for (int di = 0; di < 4; ++di) {
            union { bf16 h[16]; uint4 q[2]; } pk;
            #pragma unroll
            for (int w = 0; w < 16; ++w) pk.h[w] = __float2bfloat16(acc[di][w]);
            bf16* dst = aout + (D2 + d0 + di) * WD;
            *(uint4*)dst       = pk.q[0];
            *(uint4*)(dst + 8) = pk.q[1];
        }
    }
}

// ---------------------------------------------------------------------------
// MFMA GEMM (round-7 BM=64 structure, unchanged).
// ---------------------------------------------------------------------------
__global__ __launch_bounds__(256)
void gemm_mfma(const bf16* __restrict__ A, const bf16* __restrict__ Bhi,
               const bf16* __restrict__ Blo, const float* __restrict__ bias,
               float* __restrict__ out_t, float* __restrict__ out_pm,
               bf16* __restrict__ out_pmb, int m0, int K)
{
    __shared__ __align__(16) char smem[40960];
    bf16* lds = (bf16*)smem;

    const int tid  = threadIdx.x;
    const int w    = tid >> 6;
    const int lane = tid & 63;
    const int wr   = w >> 1, wc = w & 1;
    const int mb   = (int)blockIdx.x * 64;
    const int gK   = lane >> 4;
    const int rL   = lane & 15;

    f32x4 acc[2][4];
    #pragma unroll
    for (int i = 0; i < 2; ++i)
        #pragma unroll
        for (int j = 0; j < 4; ++j) acc[i][j] = (f32x4)0.f;

    auto stage = [&](int buf, int kt) {
        const int kb = kt * 32;
        const int bufo = buf * 10240;
        {
            const int row = tid >> 2, ch = tid & 3;
            const int sch = ch ^ (row & 3);
            GLD16(A + (size_t)(mb + row) * K + kb + (sch << 3),
                  lds + bufo + ((w * 64) << 3));
        }
        #pragma unroll
        for (int i = 0; i < 2; ++i) {
            const int s2 = i * 256 + tid;
            const int row = s2 >> 2, ch = s2 & 3;
            const int sch = ch ^ (row & 3);
            const int wb = (i * 256 + w * 64) << 3;
            GLD16(Bhi + (size_t)row * K + kb + (sch << 3), lds + bufo + 2048 + wb);
            GLD16(Blo + (size_t)row * K + kb + (sch << 3), lds + bufo + 6144 + wb);
        }
    };

    stage(0, 0);
    __syncthreads();

    const int nk = K / 32;
    for (int kt = 0; kt < nk; ++kt) {
        const int cur = kt & 1;
        if (kt + 1 < nk) stage(cur ^ 1, kt + 1);

        const bf16* la  = lds + cur * 10240;
        const bf16* lbh = la + 2048;
        const bf16* lbl = la + 6144;

        bf16x8 af[2], bh[4], bl[4];
        #pragma unroll
        for (int mf = 0; mf < 2; ++mf) {
            const int row = wr * 32 + mf * 16 + rL;
            af[mf] = *(const bf16x8*)(la + row * 32 + ((gK ^ (row & 3)) << 3));
        }
        #pragma unroll
        for (int nf = 0; nf < 4; ++nf) {
            const int col = wc * 64 + nf * 16 + rL;
            const int off = col * 32 + ((gK ^ (col & 3)) << 3);
            bh[nf] = *(const bf16x8*)(lbh + off);
            bl[nf] = *(const bf16x8*)(lbl + off);
        }
        #pragma unroll
        for (int mf = 0; mf < 2; ++mf)
            #pragma unroll
            for (int nf = 0; nf < 4; ++nf) {
                acc[mf][nf] = __builtin_amdgcn_mfma_f32_16x16x32_bf16(af[mf], bh[nf], acc[mf][nf], 0, 0, 0);
                acc[mf][nf] = __builtin_amdgcn_mfma_f32_16x16x32_bf16(af[mf], bl[nf], acc[mf][nf], 0, 0, 0);
            }
        __syncthreads();
    }

    float (*tile)[133] = (float(*)[133])smem;
    #pragma unroll
    for (int mf = 0; mf < 2; ++mf)
        #pragma unroll
        for (int nf = 0; nf < 4; ++nf) {
            const int col = wc * 64 + nf * 16 + rL;
            const float bs = bias[col];
            #pragma unroll
            for (int qq = 0; qq < 4; ++qq) {
                const int rrow = wr * 32 + mf * 16 + gK * 4 + qq;
                const float v = acc[mf][nf][qq] + bs;
                tile[rrow][col] = v > 0.f ? v : 0.1f * v;
            }
        }
    __syncthreads();

    const int mrow = m0 + mb;
    const int b = mrow >> 12, n0 = mrow & (NPT - 1);
    for (int e = tid; e < 64 * MIDD; e += 256) {
        const int o = e >> 6, i = e & 63;
        out_t[((size_t)b * MIDD + o) * NPT + n0 + i] = tile[i][o];
    }
    if (out_pm) {
        for (int e = tid; e < 64 * MIDD; e += 256) {
            const int i = e >> 7, o = e & 127;
            const float v = tile[i][o];
            out_pm [(size_t)(mrow + i) * MIDD + o] = v;
            out_pmb[(size_t)(mrow + i) * MIDD + o] = __float2bfloat16(v);
        }
    }
}

// ---------------------------------------------------------------------------
extern "C" void kernel_launch(void* const* d_in, const int* in_sizes, int n_in,
                              void* d_out, int out_size, void* d_ws, size_t ws_size,
                              hipStream_t stream)
{
    (void)in_sizes; (void)n_in; (void)out_size;
    const float* pc1    = (const float*)d_in[0];
    const float* pc2    = (const float*)d_in[1];
    const float* feat1  = (const float*)d_in[2];
    const float* feat2  = (const float*)d_in[3];
    const float* wn1_w0 = (const float*)d_in[4];
    const float* wn1_b0 = (const float*)d_in[5];
    const float* wn1_w1 = (const float*)d_in[6];
    const float* wn1_b1 = (const float*)d_in[7];
    const float* wn1_w2 = (const float*)d_in[8];
    const float* wn1_b2 = (const float*)d_in[9];
    const float* lin1_w = (const float*)d_in[10];
    const float* lin1_b = (const float*)d_in[11];
    const float* wn2_w0 = (const float*)d_in[12];
    const float* wn2_b0 = (const float*)d_in[13];
    const float* wn2_w1 = (const float*)d_in[14];
    const float* wn2_b1 = (const float*)d_in[15];
    const float* wn2_w2 = (const float*)d_in[16];
    const float* wn2_b2 = (const float*)d_in[17];
    const float* lin2_w = (const float*)d_in[18];
    const float* lin2_b = (const float*)d_in[19];
    float* out = (float*)d_out;

    const int M  = BB * NPT;
    const int M2 = 2 * M;
    const int K1 = 2 * CDIM * WD;     // 2048
    const int K2 = 2 * MIDD * WD;     // 4096

    char* ws = (char*)d_ws;
    float* p1pm = (float*)ws;                          // [M][64] f32
    float* p2pm = p1pm + (size_t)M * CDIM;             // [M][64] f32
    float* fpm  = p2pm + (size_t)M * CDIM;             // [2M][128] f32 (f1|f2)
    bf16*  p1b  = (bf16*)(fpm + (size_t)M2 * MIDD);    // [M][64] bf16
    bf16*  p2b  = p1b + (size_t)M * CDIM;              // [M][64] bf16
    bf16*  fb   = p2b + (size_t)M * CDIM;              // [2M][128] bf16
    int* idx12  = (int*)(fb + (size_t)M2 * MIDD);
    int* idx21  = idx12 + (size_t)M * NBR;
    bf16* b1hi  = (bf16*)(idx21 + (size_t)M * NBR);
    bf16* b1lo  = b1hi + (size_t)MIDD * K1;
    bf16* b2hi  = b1lo + (size_t)MIDD * K1;
    bf16* b2lo  = b2hi + (size_t)MIDD * K2;
    bf16* aggbuf = b2lo + (size_t)MIDD * K2;
    const size_t used = (size_t)((char*)aggbuf - ws);
    const size_t avail = ws_size > used ? ws_size - used : 0;

    float* f1t = out;
    float* fft = out + 2 * (size_t)BB * MIDD * NPT;

    pre_kernel<<<4096 + 2816, 256, 0, stream>>>(
        pc1, pc2, idx12, idx21,
        feat1, feat2, p1pm, p1b, p2pm, p2b,
        lin1_w, b1hi, b1lo, lin2_w, b2hi, b2lo);

    auto chunk_rows = [&](int K) -> int {
        long rows = (long)(avail / ((size_t)K * sizeof(bf16)));
        int cm = (int)(rows > M2 ? M2 : rows) & ~127;
        if (cm < 128) cm = 128;
        return cm;
    };

    {   // cross 1 + cross 2 merged (K = 2048), single agg launch per chunk
        const int CMr = chunk_rows(K1);
        for (int m0 = 0; m0 < M2; m0 += CMr) {
            const int cm = (M2 - m0 < CMr) ? (M2 - m0) : CMr;
            agg_kernel<CDIM, 8><<<cm / 8, 256, 0, stream>>>(
                pc1, pc2, p1pm, p2b, idx12,
                pc2, pc1, p2pm, p1b, idx21, M,
                wn1_w0, wn1_b0, wn1_w1, wn1_b1, wn1_w2, wn1_b2, aggbuf, m0);
            gemm_mfma<<<cm / 64, 256, 0, stream>>>(aggbuf, b1hi, b1lo, lin1_b,
                                                   f1t, fpm, fb, m0, K1);
        }
    }
    {   // cross 3 (K = 4096): own = f1 (fp32), neighbors = f2 (bf16)
        const int CMr = chunk_rows(K2);
        for (int m0 = 0; m0 < M; m0 += CMr) {
            const int cm = (M - m0 < CMr) ? (M - m0) : CMr;
            agg_kernel<MIDD, 4><<<cm / 4, 256, 0, stream>>>(
                pc1, pc2, fpm, fb + (size_t)M * MIDD, idx12,
                nullptr, nullptr, nullptr, nullptr, nullptr, M2,
                wn2_w0, wn2_b0, wn2_w1, wn2_b1, wn2_w2, wn2_b2, aggbuf, m0);
            gemm_mfma<<<cm / 64, 256, 0, stream>>>(aggbuf, b2hi, b2lo, lin2_b,
                                                   fft, nullptr, nullptr, m0, K2);
        }
    }
}

// Round 14
// 432.138 us; speedup vs baseline: 1.0627x; 1.0627x over previous
//
#include <hip/hip_runtime.h>
#include <hip/hip_bf16.h>
#include <cstddef>
#include <cstdint>

typedef __hip_bfloat16 bf16;
typedef __attribute__((ext_vector_type(8))) short bf16x8;   // 8 bf16 = 4 VGPRs
typedef __attribute__((ext_vector_type(4))) float f32x4;

#define NPT 4096   // points per cloud
#define BB  4      // batch
#define NBR 16     // neighbors (nsample)
#define WD  16     // weightnet output width
#define CDIM 64    // input feature channels
#define MIDD 128   // lin1/lin2 output channels

// async global->LDS, 16B per lane; LDS dest is wave-uniform base + lane*16
#define GLD16(g, l) __builtin_amdgcn_global_load_lds( \
    (const __attribute__((address_space(1))) unsigned int*)(const void*)(g), \
    (__attribute__((address_space(3))) unsigned int*)(void*)(l), 16, 0, 0)

// ---------------------------------------------------------------------------
// Fused prep: feature transposes (fp32+bf16) + lin-weight hi/lo splits.
// ---------------------------------------------------------------------------
__global__ __launch_bounds__(256)
void prep_kernel(const float* __restrict__ feat1, const float* __restrict__ feat2,
                 float* __restrict__ p1pm, bf16* __restrict__ p1b,
                 float* __restrict__ p2pm, bf16* __restrict__ p2b,
                 const float* __restrict__ lin1_w, bf16* __restrict__ b1hi, bf16* __restrict__ b1lo,
                 const float* __restrict__ lin2_w, bf16* __restrict__ b2hi, bf16* __restrict__ b2lo)
{
    __shared__ float t[32][33];
    const int tx = threadIdx.x & 31, ty = threadIdx.x >> 5;
    const int id = blockIdx.x;
    if (id < 2048) {
        const int which = id >> 10;
        const int nt = id & 1023;
        const int n0 = (nt & 127) * 32;
        const int c0 = ((nt >> 7) & 1) * 32;
        const int b  = nt >> 8;
        const float* in = which ? feat2 : feat1;
        float* out  = which ? p2pm : p1pm;
        bf16*  outb = which ? p2b  : p1b;
        #pragma unroll
        for (int r = ty; r < 32; r += 8)
            t[r][tx] = in[((size_t)b * CDIM + c0 + r) * NPT + n0 + tx];
        __syncthreads();
        #pragma unroll
        for (int r = ty; r < 32; r += 8) {
            const float v = t[tx][r];
            out [((size_t)b * NPT + n0 + r) * CDIM + c0 + tx] = v;
            outb[((size_t)b * NPT + n0 + r) * CDIM + c0 + tx] = __float2bfloat16(v);
        }
    } else {
        const float* w; bf16 *hi, *lo; int K, k0, o0;
        if (id < 2304) {
            const int id2 = id - 2048;
            w = lin1_w; hi = b1hi; lo = b1lo; K = 2048;
            k0 = (id2 & 63) * 32; o0 = (id2 >> 6) * 32;
        } else {
            const int id2 = id - 2304;
            w = lin2_w; hi = b2hi; lo = b2lo; K = 4096;
            k0 = (id2 & 127) * 32; o0 = (id2 >> 7) * 32;
        }
        #pragma unroll
        for (int r = ty; r < 32; r += 8)
            t[r][tx] = w[(size_t)(k0 + r) * MIDD + o0 + tx];
        __syncthreads();
        #pragma unroll
        for (int r = ty; r < 32; r += 8) {
            const float v = t[tx][r];
            const bf16 h = __float2bfloat16(v);
            const bf16 l2 = __float2bfloat16(v - __bfloat162float(h));
            hi[(size_t)(o0 + r) * K + k0 + tx] = h;
            lo[(size_t)(o0 + r) * K + k0 + tx] = l2;
        }
    }
}

// ---------------------------------------------------------------------------
// KNN v5b: round-8 structure with staging-write bank fix.
//  - cf[] skewed (stride 65 float4/segment) -> pass-1 READS conflict-free
//    (segment bases hit banks 4s).
//  - staging writes are THREAD-STRIDED (j = r*256 + tid): lane-consecutive
//    float4 stores sweep all 32 banks -> WRITES conflict-free (round 8's
//    4-consecutive-per-thread staging put lane i at byte 64*i -> 2 banks,
//    8.4M conflict cycles). Scalar coordinate loads stay fully coalesced.
//  - per-candidate arithmetic identical -> output bit-identical.
// ---------------------------------------------------------------------------
#define KQ     16
#define KSEG   16
#define KCH    64
#define KSTAGE 1024
#define KRING  96

__global__ __launch_bounds__(256)
void knn_kernel(const float* __restrict__ pcA, const float* __restrict__ pcB,
                int* __restrict__ idxAB, int* __restrict__ idxBA)
{
    const float *qxyz, *cxyz; int* idx_out;
    if (blockIdx.z == 0) { qxyz = pcA; cxyz = pcB; idx_out = idxAB; }
    else                 { qxyz = pcB; cxyz = pcA; idx_out = idxBA; }

    __shared__ float4 cf[KSTAGE + KSTAGE / KCH];   // skewed
    __shared__ float  pubd[2][KSEG][KQ];
    __shared__ float4 qc[KQ];
    __shared__ float  u16s[KQ];
    __shared__ int    rcnt[KQ];
    __shared__ int    wtot;
    __shared__ int    wl[256];
    __shared__ float  ringd[KQ][KRING + 1];
    __shared__ int    ringi[KQ][KRING + 1];

    const int tid = threadIdx.x;
    const int q   = tid & (KQ - 1);
    const int s   = tid >> 4;
    const int b   = blockIdx.y;
    const int n   = blockIdx.x * KQ + q;

    const float* qp = qxyz + (size_t)b * 3 * NPT;
    const float qx = qp[n], qy = qp[NPT + n], qz = qp[2 * NPT + n];
    const float q2 = fmaf(qx, qx, fmaf(qy, qy, qz * qz));
    const float* c = cxyz + (size_t)b * 3 * NPT;

    if (tid < KQ) rcnt[tid] = 0;
    if (tid == 0) wtot = 0;
    if (s == 0) qc[q] = make_float4(qx, qy, qz, q2);

    // ---- pass 1: two smallest distance values per (q,s) ----
    float b0 = 3.4e38f, b1 = 3.4e38f;
    for (int st = 0; st < NPT; st += KSTAGE) {
        __syncthreads();
        {   // thread-strided staging: conflict-free lane-consecutive writes
            #pragma unroll
            for (int r = 0; r < KSTAGE / 256; ++r) {
                const int j = r * 256 + tid;
                const int g = st + j;
                const float x = c[g], y = c[NPT + g], z = c[2 * NPT + g];
                cf[j + (j >> 6)] = make_float4(x, y, z,
                    fmaf(x, x, fmaf(y, y, z * z)));
            }
        }
        __syncthreads();
        const int base = s * (KCH + 1);   // skewed segment base
        #pragma unroll 4
        for (int jj = 0; jj < KCH; ++jj) {
            const float4 pv = cf[base + jj];
            const float dot = fmaf(qx, pv.x, fmaf(qy, pv.y, qz * pv.z));
            const float d = q2 + pv.w - 2.f * dot;
            const float t = fmaxf(b0, d);
            b0 = fminf(b0, d);
            b1 = fminf(b1, t);
        }
    }
    pubd[0][s][q] = b0;
    pubd[1][s][q] = b1;
    __syncthreads();

    // ---- u16: 16th smallest of 32 published values (rank == 15) ----
    {
        float tv[32];
        #pragma unroll
        for (int j = 0; j < 32; ++j) tv[j] = pubd[j >> 4][j & 15][q];
        #pragma unroll
        for (int rep = 0; rep < 2; ++rep) {
            const int j = rep * 16 + s;
            const float vj = pubd[rep][s][q];
            int rank = 0;
            #pragma unroll
            for (int k = 0; k < 32; ++k)
                rank += (tv[k] < vj || (tv[k] == vj && k < j)) ? 1 : 0;
            if (rank == 15) u16s[q] = vj;
        }
    }
    __syncthreads();

    // ---- classify: flag segments whose minimum can pass the gate ----
    if (b0 <= u16s[q]) {
        const int u = atomicAdd(&wtot, 1);
        wl[u] = (q << 4) | s;
    }
    __syncthreads();

    // ---- pass 2: cooperative rescan of flagged segments only ----
    {
        const int W = wtot;
        const int lu = tid & 15;
        for (int u = tid >> 4; u < W; u += 16) {
            const int qq  = wl[u] >> 4;
            const int seg = wl[u] & 15;
            const float4 qv = qc[qq];
            const float gate = u16s[qq];
            #pragma unroll
            for (int ch = 0; ch < 4; ++ch) {
                const int j = ch * KSTAGE + seg * KCH + lu * 4;
                const float4 xs = *(const float4*)(c + j);
                const float4 ys = *(const float4*)(c + NPT + j);
                const float4 zs = *(const float4*)(c + 2 * NPT + j);
                const float xv[4] = { xs.x, xs.y, xs.z, xs.w };
                const float yv[4] = { ys.x, ys.y, ys.z, ys.w };
                const float zv[4] = { zs.x, zs.y, zs.z, zs.w };
                #pragma unroll
                for (int e = 0; e < 4; ++e) {
                    const float p2 = fmaf(xv[e], xv[e], fmaf(yv[e], yv[e], zv[e] * zv[e]));
                    const float dot = fmaf(qv.x, xv[e], fmaf(qv.y, yv[e], qv.z * zv[e]));
                    const float d = qv.w + p2 - 2.f * dot;
                    if (d <= gate) {
                        const int slot = atomicAdd(&rcnt[qq], 1);
                        if (slot < KRING) { ringd[qq][slot] = d; ringi[qq][slot] = j + e; }
                    }
                }
            }
        }
    }
    __syncthreads();

    // ---- final: exact (d, idx) rank-select of top-16 from the ring ----
    {
        const int cnt = min(rcnt[q], KRING);
        int* op = idx_out + ((size_t)b * NPT + n) * NBR;
        for (int e = s; e < cnt; e += KSEG) {
            const float de = ringd[q][e];
            const int   ie = ringi[q][e];
            int rank = 0;
            for (int k = 0; k < cnt; ++k) {
                const float dk = ringd[q][k];
                const int   ik = ringi[q][k];
                rank += (dk < de || (dk == de && ik < ie)) ? 1 : 0;
            }
            if (rank < NBR) op[rank] = ie;
        }
    }
}

// ---------------------------------------------------------------------------
// Weightnet + aggregation: exact round-8 body (F[16] full prefetch, natural
// VGPR allocation ~132, direct global writes — 128 contiguous B per thread).
// ---------------------------------------------------------------------------
template<int D2, int PTS>
__global__ __launch_bounds__(256)
void agg_kernel(const float* __restrict__ qA, const float* __restrict__ cA,
                const float* __restrict__ ownA, const bf16* __restrict__ nbrA,
                const int* __restrict__ idxA,
                const float* __restrict__ qB, const float* __restrict__ cB,
                const float* __restrict__ ownB, const bf16* __restrict__ nbrB,
                const int* __restrict__ idxB, int Msplit,
                const float* __restrict__ w0, const float* __restrict__ b0,
                const float* __restrict__ w1, const float* __restrict__ b1,
                const float* __restrict__ w2, const float* __restrict__ b2,
                bf16* __restrict__ agg, int m0)
{
    constexpr int TPP   = 256 / PTS;
    constexpr int HALF  = TPP / 2;
    constexpr int WSTR  = 276;

    __shared__ float wp[248];
    __shared__ int   nb[PTS * NBR];
    __shared__ float wgt[PTS * WSTR];

    const int tid = threadIdx.x;
    const int mbase = m0 + (int)blockIdx.x * PTS;
    const bool second = mbase >= Msplit;
    const int mrow = second ? mbase - Msplit : mbase;
    const float* qxyz   = second ? qB   : qA;
    const float* cxyz   = second ? cB   : cA;
    const float* own_pm = second ? ownB : ownA;
    const bf16*  nbr_b  = second ? nbrB : nbrA;
    const int*   idx    = second ? idxB : idxA;
    const int b = mrow >> 12;
    const int nbase = mrow & (NPT - 1);

    if (tid < 248) {
        float v;
        if      (tid <  24) v = w0[tid];
        else if (tid <  32) v = b0[tid - 24];
        else if (tid <  96) v = w1[tid - 32];
        else if (tid < 104) v = b1[tid - 96];
        else if (tid < 232) v = w2[tid - 104];
        else                v = b2[tid - 232];
        wp[tid] = v;
    }
    if (tid < PTS * NBR)
        nb[tid] = idx[(size_t)mrow * NBR + tid];
    __syncthreads();

    const int p  = tid & (PTS - 1);
    const int dg = tid / PTS;

    uint2  F[NBR];
    float4 ow;
    if (dg >= HALF) {
        const int d0 = (dg - HALF) * 4;
        const bf16* base = nbr_b + (size_t)b * NPT * D2 + d0;
        #pragma unroll
        for (int k = 0; k < NBR; ++k) {
            const int j = nb[p * NBR + k];
            F[k] = *(const uint2*)(base + (size_t)j * D2);
        }
    } else {
        ow = *(const float4*)(own_pm + ((size_t)mrow + p) * D2 + dg * 4);
    }

    if (tid < PTS * NBR) {
        const int pp = tid / NBR, k = tid % NBR;
        const int n = nbase + pp;
        const int j = nb[tid];
        const float* q = qxyz + (size_t)b * 3 * NPT;
        const float* c = cxyz + (size_t)b * 3 * NPT;
        const float dx = c[j]           - q[n];
        const float dy = c[NPT + j]     - q[NPT + n];
        const float dz = c[2 * NPT + j] - q[2 * NPT + n];
        float h1[8], h2[8];
        #pragma unroll
        for (int o = 0; o < 8; ++o) {
            float v = wp[24 + o];
            v = fmaf(dx, wp[o], v);
            v = fmaf(dy, wp[8 + o], v);
            v = fmaf(dz, wp[16 + o], v);
            h1[o] = fmaxf(v, 0.f);
        }
        #pragma unroll
        for (int o = 0; o < 8; ++o) {
            float v = wp[96 + o];
            #pragma unroll
            for (int i = 0; i < 8; ++i) v = fmaf(h1[i], wp[32 + i * 8 + o], v);
            h2[o] = fmaxf(v, 0.f);
        }
        #pragma unroll
        for (int o = 0; o < WD; ++o) {
            float v = wp[232 + o];
            #pragma unroll
            for (int i = 0; i < 8; ++i) v = fmaf(h2[i], wp[104 + i * WD + o], v);
            wgt[pp * WSTR + k * WD + o] = fmaxf(v, 0.f);
        }
    }
    __syncthreads();

    const float* wg = wgt + p * WSTR;
    bf16* aout = agg + ((size_t)((int)blockIdx.x * PTS + p)) * (2 * D2 * WD);

    if (dg < HALF) {
        const int d0 = dg * 4;
        float sw[16];
        #pragma unroll
        for (int w = 0; w < 16; ++w) sw[w] = 0.f;
        #pragma unroll
        for (int k = 0; k < NBR; ++k) {
            const float4 v0 = *(const float4*)(wg + k * WD);
            const float4 v1 = *(const float4*)(wg + k * WD + 4);
            const float4 v2 = *(const float4*)(wg + k * WD + 8);
            const float4 v3 = *(const float4*)(wg + k * WD + 12);
            sw[0]  += v0.x; sw[1]  += v0.y; sw[2]  += v0.z; sw[3]  += v0.w;
            sw[4]  += v1.x; sw[5]  += v1.y; sw[6]  += v1.z; sw[7]  += v1.w;
            sw[8]  += v2.x; sw[9]  += v2.y; sw[10] += v2.z; sw[11] += v2.w;
            sw[12] += v3.x; sw[13] += v3.y; sw[14] += v3.z; sw[15] += v3.w;
        }
        const float od[4] = { ow.x, ow.y, ow.z, ow.w };
        #pragma unroll
        for (int di = 0; di < 4; ++di) {
            const float f = od[di];
            union { bf16 h[16]; uint4 q[2]; } pk;
            #pragma unroll
            for (int w = 0; w < 16; ++w) pk.h[w] = __float2bfloat16(f * sw[w]);
            bf16* dst = aout + (d0 + di) * WD;
            *(uint4*)dst       = pk.q[0];
            *(uint4*)(dst + 8) = pk.q[1];
        }
    } else {
        const int d0 = (dg - HALF) * 4;
        float acc[4][16];
        #pragma unroll
        for (int di = 0; di < 4; ++di)
            #pragma unroll
            for (int w = 0; w < 16; ++w) acc[di][w] = 0.f;
        #pragma unroll
        for (int k = 0; k < NBR; ++k) {
            union { uint2 u; bf16 h[4]; } uf;
            uf.u = F[k];
            float Fv[4];
            #pragma unroll
            for (int j = 0; j < 4; ++j) Fv[j] = __bfloat162float(uf.h[j]);
            const float4 v0 = *(const float4*)(wg + k * WD);
            const float4 v1 = *(const float4*)(wg + k * WD + 4);
            const float4 v2 = *(const float4*)(wg + k * WD + 8);
            const float4 v3 = *(const float4*)(wg + k * WD + 12);
            float w16[16];
            w16[0]  = v0.x; w16[1]  = v0.y; w16[2]  = v0.z; w16[3]  = v0.w;
            w16[4]  = v1.x; w16[5]  = v1.y; w16[6]  = v1.z; w16[7]  = v1.w;
            w16[8]  = v2.x; w16[9]  = v2.y; w16[10] = v2.z; w16[11] = v2.w;
            w16[12] = v3.x; w16[13] = v3.y; w16[14] = v3.z; w16[15] = v3.w;
            #pragma unroll
            for (int di = 0; di < 4; ++di)
                #pragma unroll
                for (int w = 0; w < 16; ++w)
                    acc[di][w] = fmaf(Fv[di], w16[w], acc[di][w]);
        }
        #pragma unroll
        for (int di = 0; di < 4; ++di) {
            union { bf16 h[16]; uint4 q[2]; } pk;
            #pragma unroll
            for (int w = 0; w < 16; ++w) pk.h[w] = __float2bfloat16(acc[di][w]);
            bf16* dst = aout + (D2 + d0 + di) * WD;
            *(uint4*)dst       = pk.q[0];
            *(uint4*)(dst + 8) = pk.q[1];
        }
    }
}

// ---------------------------------------------------------------------------
// MFMA GEMM (round-7 BM=64 structure, unchanged).
// ---------------------------------------------------------------------------
__global__ __launch_bounds__(256)
void gemm_mfma(const bf16* __restrict__ A, const bf16* __restrict__ Bhi,
               const bf16* __restrict__ Blo, const float* __restrict__ bias,
               float* __restrict__ out_t, float* __restrict__ out_pm,
               bf16* __restrict__ out_pmb, int m0, int K)
{
    __shared__ __align__(16) char smem[40960];
    bf16* lds = (bf16*)smem;

    const int tid  = threadIdx.x;
    const int w    = tid >> 6;
    const int lane = tid & 63;
    const int wr   = w >> 1, wc = w & 1;
    const int mb   = (int)blockIdx.x * 64;
    const int gK   = lane >> 4;
    const int rL   = lane & 15;

    f32x4 acc[2][4];
    #pragma unroll
    for (int i = 0; i < 2; ++i)
        #pragma unroll
        for (int j = 0; j < 4; ++j) acc[i][j] = (f32x4)0.f;

    auto stage = [&](int buf, int kt) {
        const int kb = kt * 32;
        const int bufo = buf * 10240;
        {
            const int row = tid >> 2, ch = tid & 3;
            const int sch = ch ^ (row & 3);
            GLD16(A + (size_t)(mb + row) * K + kb + (sch << 3),
                  lds + bufo + ((w * 64) << 3));
        }
        #pragma unroll
        for (int i = 0; i < 2; ++i) {
            const int s2 = i * 256 + tid;
            const int row = s2 >> 2, ch = s2 & 3;
            const int sch = ch ^ (row & 3);
            const int wb = (i * 256 + w * 64) << 3;
            GLD16(Bhi + (size_t)row * K + kb + (sch << 3), lds + bufo + 2048 + wb);
            GLD16(Blo + (size_t)row * K + kb + (sch << 3), lds + bufo + 6144 + wb);
        }
    };

    stage(0, 0);
    __syncthreads();

    const int nk = K / 32;
    for (int kt = 0; kt < nk; ++kt) {
        const int cur = kt & 1;
        if (kt + 1 < nk) stage(cur ^ 1, kt + 1);

        const bf16* la  = lds + cur * 10240;
        const bf16* lbh = la + 2048;
        const bf16* lbl = la + 6144;

        bf16x8 af[2], bh[4], bl[4];
        #pragma unroll
        for (int mf = 0; mf < 2; ++mf) {
            const int row = wr * 32 + mf * 16 + rL;
            af[mf] = *(const bf16x8*)(la + row * 32 + ((gK ^ (row & 3)) << 3));
        }
        #pragma unroll
        for (int nf = 0; nf < 4; ++nf) {
            const int col = wc * 64 + nf * 16 + rL;
            const int off = col * 32 + ((gK ^ (col & 3)) << 3);
            bh[nf] = *(const bf16x8*)(lbh + off);
            bl[nf] = *(const bf16x8*)(lbl + off);
        }
        #pragma unroll
        for (int mf = 0; mf < 2; ++mf)
            #pragma unroll
            for (int nf = 0; nf < 4; ++nf) {
                acc[mf][nf] = __builtin_amdgcn_mfma_f32_16x16x32_bf16(af[mf], bh[nf], acc[mf][nf], 0, 0, 0);
                acc[mf][nf] = __builtin_amdgcn_mfma_f32_16x16x32_bf16(af[mf], bl[nf], acc[mf][nf], 0, 0, 0);
            }
        __syncthreads();
    }

    float (*tile)[133] = (float(*)[133])smem;
    #pragma unroll
    for (int mf = 0; mf < 2; ++mf)
        #pragma unroll
        for (int nf = 0; nf < 4; ++nf) {
            const int col = wc * 64 + nf * 16 + rL;
            const float bs = bias[col];
            #pragma unroll
            for (int qq = 0; qq < 4; ++qq) {
                const int rrow = wr * 32 + mf * 16 + gK * 4 + qq;
                const float v = acc[mf][nf][qq] + bs;
                tile[rrow][col] = v > 0.f ? v : 0.1f * v;
            }
        }
    __syncthreads();

    const int mrow = m0 + mb;
    const int b = mrow >> 12, n0 = mrow & (NPT - 1);
    for (int e = tid; e < 64 * MIDD; e += 256) {
        const int o = e >> 6, i = e & 63;
        out_t[((size_t)b * MIDD + o) * NPT + n0 + i] = tile[i][o];
    }
    if (out_pm) {
        for (int e = tid; e < 64 * MIDD; e += 256) {
            const int i = e >> 7, o = e & 127;
            const float v = tile[i][o];
            out_pm [(size_t)(mrow + i) * MIDD + o] = v;
            out_pmb[(size_t)(mrow + i) * MIDD + o] = __float2bfloat16(v);
        }
    }
}

// ---------------------------------------------------------------------------
extern "C" void kernel_launch(void* const* d_in, const int* in_sizes, int n_in,
                              void* d_out, int out_size, void* d_ws, size_t ws_size,
                              hipStream_t stream)
{
    (void)in_sizes; (void)n_in; (void)out_size;
    const float* pc1    = (const float*)d_in[0];
    const float* pc2    = (const float*)d_in[1];
    const float* feat1  = (const float*)d_in[2];
    const float* feat2  = (const float*)d_in[3];
    const float* wn1_w0 = (const float*)d_in[4];
    const float* wn1_b0 = (const float*)d_in[5];
    const float* wn1_w1 = (const float*)d_in[6];
    const float* wn1_b1 = (const float*)d_in[7];
    const float* wn1_w2 = (const float*)d_in[8];
    const float* wn1_b2 = (const float*)d_in[9];
    const float* lin1_w = (const float*)d_in[10];
    const float* lin1_b = (const float*)d_in[11];
    const float* wn2_w0 = (const float*)d_in[12];
    const float* wn2_b0 = (const float*)d_in[13];
    const float* wn2_w1 = (const float*)d_in[14];
    const float* wn2_b1 = (const float*)d_in[15];
    const float* wn2_w2 = (const float*)d_in[16];
    const float* wn2_b2 = (const float*)d_in[17];
    const float* lin2_w = (const float*)d_in[18];
    const float* lin2_b = (const float*)d_in[19];
    float* out = (float*)d_out;

    const int M  = BB * NPT;
    const int M2 = 2 * M;
    const int K1 = 2 * CDIM * WD;     // 2048
    const int K2 = 2 * MIDD * WD;     // 4096

    char* ws = (char*)d_ws;
    float* p1pm = (float*)ws;                          // [M][64] f32
    float* p2pm = p1pm + (size_t)M * CDIM;             // [M][64] f32
    float* fpm  = p2pm + (size_t)M * CDIM;             // [2M][128] f32 (f1|f2)
    bf16*  p1b  = (bf16*)(fpm + (size_t)M2 * MIDD);    // [M][64] bf16
    bf16*  p2b  = p1b + (size_t)M * CDIM;              // [M][64] bf16
    bf16*  fb   = p2b + (size_t)M * CDIM;              // [2M][128] bf16
    int* idx12  = (int*)(fb + (size_t)M2 * MIDD);
    int* idx21  = idx12 + (size_t)M * NBR;
    bf16* b1hi  = (bf16*)(idx21 + (size_t)M * NBR);
    bf16* b1lo  = b1hi + (size_t)MIDD * K1;
    bf16* b2hi  = b1lo + (size_t)MIDD * K1;
    bf16* b2lo  = b2hi + (size_t)MIDD * K2;
    bf16* aggbuf = b2lo + (size_t)MIDD * K2;
    const size_t used = (size_t)((char*)aggbuf - ws);
    const size_t avail = ws_size > used ? ws_size - used : 0;

    float* f1t = out;
    float* fft = out + 2 * (size_t)BB * MIDD * NPT;

    prep_kernel<<<2816, 256, 0, stream>>>(feat1, feat2, p1pm, p1b, p2pm, p2b,
                                          lin1_w, b1hi, b1lo, lin2_w, b2hi, b2lo);
    knn_kernel<<<dim3(NPT / KQ, BB, 2), 256, 0, stream>>>(pc1, pc2, idx12, idx21);

    auto chunk_rows = [&](int K) -> int {
        long rows = (long)(avail / ((size_t)K * sizeof(bf16)));
        int cm = (int)(rows > M2 ? M2 : rows) & ~127;
        if (cm < 128) cm = 128;
        return cm;
    };

    {   // cross 1 + cross 2 merged (K = 2048), single agg launch per chunk
        const int CMr = chunk_rows(K1);
        for (int m0 = 0; m0 < M2; m0 += CMr) {
            const int cm = (M2 - m0 < CMr) ? (M2 - m0) : CMr;
            agg_kernel<CDIM, 8><<<cm / 8, 256, 0, stream>>>(
                pc1, pc2, p1pm, p2b, idx12,
                pc2, pc1, p2pm, p1b, idx21, M,
                wn1_w0, wn1_b0, wn1_w1, wn1_b1, wn1_w2, wn1_b2, aggbuf, m0);
            gemm_mfma<<<cm / 64, 256, 0, stream>>>(aggbuf, b1hi, b1lo, lin1_b,
                                                   f1t, fpm, fb, m0, K1);
        }
    }
    {   // cross 3 (K = 4096): own = f1 (fp32), neighbors = f2 (bf16)
        const int CMr = chunk_rows(K2);
        for (int m0 = 0; m0 < M; m0 += CMr) {
            const int cm = (M - m0 < CMr) ? (M - m0) : CMr;
            agg_kernel<MIDD, 4><<<cm / 4, 256, 0, stream>>>(
                pc1, pc2, fpm, fb + (size_t)M * MIDD, idx12,
                nullptr, nullptr, nullptr, nullptr, nullptr, M2,
                wn2_w0, wn2_b0, wn2_w1, wn2_b1, wn2_w2, wn2_b2, aggbuf, m0);
            gemm_mfma<<<cm / 64, 256, 0, stream>>>(aggbuf, b2hi, b2lo, lin2_b,
                                                   fft, nullptr, nullptr, m0, K2);
        }
    }
}

// Round 15
// 372.778 us; speedup vs baseline: 1.2320x; 1.1592x over previous
//
#include <hip/hip_runtime.h>
#include <hip/hip_bf16.h>
#include <cstddef>
#include <cstdint>

typedef __hip_bfloat16 bf16;
typedef __attribute__((ext_vector_type(8))) short bf16x8;   // 8 bf16 = 4 VGPRs
typedef __attribute__((ext_vector_type(4))) float f32x4;

#define NPT 4096   // points per cloud
#define BB  4      // batch
#define NBR 16     // neighbors (nsample)
#define WD  16     // weightnet output width
#define CDIM 64    // input feature channels
#define MIDD 128   // lin1/lin2 output channels

// async global->LDS, 16B per lane; LDS dest is wave-uniform base + lane*16
#define GLD16(g, l) __builtin_amdgcn_global_load_lds( \
    (const __attribute__((address_space(1))) unsigned int*)(const void*)(g), \
    (__attribute__((address_space(3))) unsigned int*)(void*)(l), 16, 0, 0)

// ---------------------------------------------------------------------------
// Fused prep: feature transposes (fp32+bf16) + lin-weight hi/lo splits.
// ---------------------------------------------------------------------------
__global__ __launch_bounds__(256)
void prep_kernel(const float* __restrict__ feat1, const float* __restrict__ feat2,
                 float* __restrict__ p1pm, bf16* __restrict__ p1b,
                 float* __restrict__ p2pm, bf16* __restrict__ p2b,
                 const float* __restrict__ lin1_w, bf16* __restrict__ b1hi, bf16* __restrict__ b1lo,
                 const float* __restrict__ lin2_w, bf16* __restrict__ b2hi, bf16* __restrict__ b2lo)
{
    __shared__ float t[32][33];
    const int tx = threadIdx.x & 31, ty = threadIdx.x >> 5;
    const int id = blockIdx.x;
    if (id < 2048) {
        const int which = id >> 10;
        const int nt = id & 1023;
        const int n0 = (nt & 127) * 32;
        const int c0 = ((nt >> 7) & 1) * 32;
        const int b  = nt >> 8;
        const float* in = which ? feat2 : feat1;
        float* out  = which ? p2pm : p1pm;
        bf16*  outb = which ? p2b  : p1b;
        #pragma unroll
        for (int r = ty; r < 32; r += 8)
            t[r][tx] = in[((size_t)b * CDIM + c0 + r) * NPT + n0 + tx];
        __syncthreads();
        #pragma unroll
        for (int r = ty; r < 32; r += 8) {
            const float v = t[tx][r];
            out [((size_t)b * NPT + n0 + r) * CDIM + c0 + tx] = v;
            outb[((size_t)b * NPT + n0 + r) * CDIM + c0 + tx] = __float2bfloat16(v);
        }
    } else {
        const float* w; bf16 *hi, *lo; int K, k0, o0;
        if (id < 2304) {
            const int id2 = id - 2048;
            w = lin1_w; hi = b1hi; lo = b1lo; K = 2048;
            k0 = (id2 & 63) * 32; o0 = (id2 >> 6) * 32;
        } else {
            const int id2 = id - 2304;
            w = lin2_w; hi = b2hi; lo = b2lo; K = 4096;
            k0 = (id2 & 127) * 32; o0 = (id2 >> 7) * 32;
        }
        #pragma unroll
        for (int r = ty; r < 32; r += 8)
            t[r][tx] = w[(size_t)(k0 + r) * MIDD + o0 + tx];
        __syncthreads();
        #pragma unroll
        for (int r = ty; r < 32; r += 8) {
            const float v = t[tx][r];
            const bf16 h = __float2bfloat16(v);
            const bf16 l2 = __float2bfloat16(v - __bfloat162float(h));
            hi[(size_t)(o0 + r) * K + k0 + tx] = h;
            lo[(size_t)(o0 + r) * K + k0 + tx] = l2;
        }
    }
}

// ---------------------------------------------------------------------------
// KNN v5b (round-14, unchanged): skewed cf, thread-strided staging writes,
// u16 gate, segment-skip cooperative pass 2, exact (d,idx) rank-select.
// ---------------------------------------------------------------------------
#define KQ     16
#define KSEG   16
#define KCH    64
#define KSTAGE 1024
#define KRING  96

__global__ __launch_bounds__(256)
void knn_kernel(const float* __restrict__ pcA, const float* __restrict__ pcB,
                int* __restrict__ idxAB, int* __restrict__ idxBA)
{
    const float *qxyz, *cxyz; int* idx_out;
    if (blockIdx.z == 0) { qxyz = pcA; cxyz = pcB; idx_out = idxAB; }
    else                 { qxyz = pcB; cxyz = pcA; idx_out = idxBA; }

    __shared__ float4 cf[KSTAGE + KSTAGE / KCH];   // skewed
    __shared__ float  pubd[2][KSEG][KQ];
    __shared__ float4 qc[KQ];
    __shared__ float  u16s[KQ];
    __shared__ int    rcnt[KQ];
    __shared__ int    wtot;
    __shared__ int    wl[256];
    __shared__ float  ringd[KQ][KRING + 1];
    __shared__ int    ringi[KQ][KRING + 1];

    const int tid = threadIdx.x;
    const int q   = tid & (KQ - 1);
    const int s   = tid >> 4;
    const int b   = blockIdx.y;
    const int n   = blockIdx.x * KQ + q;

    const float* qp = qxyz + (size_t)b * 3 * NPT;
    const float qx = qp[n], qy = qp[NPT + n], qz = qp[2 * NPT + n];
    const float q2 = fmaf(qx, qx, fmaf(qy, qy, qz * qz));
    const float* c = cxyz + (size_t)b * 3 * NPT;

    if (tid < KQ) rcnt[tid] = 0;
    if (tid == 0) wtot = 0;
    if (s == 0) qc[q] = make_float4(qx, qy, qz, q2);

    float b0 = 3.4e38f, b1 = 3.4e38f;
    for (int st = 0; st < NPT; st += KSTAGE) {
        __syncthreads();
        {
            #pragma unroll
            for (int r = 0; r < KSTAGE / 256; ++r) {
                const int j = r * 256 + tid;
                const int g = st + j;
                const float x = c[g], y = c[NPT + g], z = c[2 * NPT + g];
                cf[j + (j >> 6)] = make_float4(x, y, z,
                    fmaf(x, x, fmaf(y, y, z * z)));
            }
        }
        __syncthreads();
        const int base = s * (KCH + 1);
        #pragma unroll 4
        for (int jj = 0; jj < KCH; ++jj) {
            const float4 pv = cf[base + jj];
            const float dot = fmaf(qx, pv.x, fmaf(qy, pv.y, qz * pv.z));
            const float d = q2 + pv.w - 2.f * dot;
            const float t = fmaxf(b0, d);
            b0 = fminf(b0, d);
            b1 = fminf(b1, t);
        }
    }
    pubd[0][s][q] = b0;
    pubd[1][s][q] = b1;
    __syncthreads();

    {
        float tv[32];
        #pragma unroll
        for (int j = 0; j < 32; ++j) tv[j] = pubd[j >> 4][j & 15][q];
        #pragma unroll
        for (int rep = 0; rep < 2; ++rep) {
            const int j = rep * 16 + s;
            const float vj = pubd[rep][s][q];
            int rank = 0;
            #pragma unroll
            for (int k = 0; k < 32; ++k)
                rank += (tv[k] < vj || (tv[k] == vj && k < j)) ? 1 : 0;
            if (rank == 15) u16s[q] = vj;
        }
    }
    __syncthreads();

    if (b0 <= u16s[q]) {
        const int u = atomicAdd(&wtot, 1);
        wl[u] = (q << 4) | s;
    }
    __syncthreads();

    {
        const int W = wtot;
        const int lu = tid & 15;
        for (int u = tid >> 4; u < W; u += 16) {
            const int qq  = wl[u] >> 4;
            const int seg = wl[u] & 15;
            const float4 qv = qc[qq];
            const float gate = u16s[qq];
            #pragma unroll
            for (int ch = 0; ch < 4; ++ch) {
                const int j = ch * KSTAGE + seg * KCH + lu * 4;
                const float4 xs = *(const float4*)(c + j);
                const float4 ys = *(const float4*)(c + NPT + j);
                const float4 zs = *(const float4*)(c + 2 * NPT + j);
                const float xv[4] = { xs.x, xs.y, xs.z, xs.w };
                const float yv[4] = { ys.x, ys.y, ys.z, ys.w };
                const float zv[4] = { zs.x, zs.y, zs.z, zs.w };
                #pragma unroll
                for (int e = 0; e < 4; ++e) {
                    const float p2 = fmaf(xv[e], xv[e], fmaf(yv[e], yv[e], zv[e] * zv[e]));
                    const float dot = fmaf(qv.x, xv[e], fmaf(qv.y, yv[e], qv.z * zv[e]));
                    const float d = qv.w + p2 - 2.f * dot;
                    if (d <= gate) {
                        const int slot = atomicAdd(&rcnt[qq], 1);
                        if (slot < KRING) { ringd[qq][slot] = d; ringi[qq][slot] = j + e; }
                    }
                }
            }
        }
    }
    __syncthreads();

    {
        const int cnt = min(rcnt[q], KRING);
        int* op = idx_out + ((size_t)b * NPT + n) * NBR;
        for (int e = s; e < cnt; e += KSEG) {
            const float de = ringd[q][e];
            const int   ie = ringi[q][e];
            int rank = 0;
            for (int k = 0; k < cnt; ++k) {
                const float dk = ringd[q][k];
                const int   ik = ringi[q][k];
                rank += (dk < de || (dk == de && ik < ie)) ? 1 : 0;
            }
            if (rank < NBR) op[rank] = ie;
        }
    }
}

// ---------------------------------------------------------------------------
// Weightnet + aggregation v6 (rank-1 own-half): agg writes ONLY the gather
// half of each row (elements >= D2*WD) plus swb[m][16] (sw[w] = sum_k wgt,
// k ascending — same order as before). The own half is reconstructed inside
// the GEMM from own_pm x sw with identical arithmetic -> bit-identical A.
// Gather half unchanged from round 8/14.
// ---------------------------------------------------------------------------
template<int D2, int PTS>
__global__ __launch_bounds__(256)
void agg_kernel(const float* __restrict__ qA, const float* __restrict__ cA,
                const bf16* __restrict__ nbrA, const int* __restrict__ idxA,
                const float* __restrict__ qB, const float* __restrict__ cB,
                const bf16* __restrict__ nbrB, const int* __restrict__ idxB,
                int Msplit,
                const float* __restrict__ w0, const float* __restrict__ b0,
                const float* __restrict__ w1, const float* __restrict__ b1,
                const float* __restrict__ w2, const float* __restrict__ b2,
                bf16* __restrict__ agg, float* __restrict__ swb, int m0)
{
    constexpr int TPP   = 256 / PTS;
    constexpr int HALF  = TPP / 2;
    constexpr int WSTR  = 276;

    __shared__ float wp[248];
    __shared__ int   nb[PTS * NBR];
    __shared__ float wgt[PTS * WSTR];

    const int tid = threadIdx.x;
    const int mbase = m0 + (int)blockIdx.x * PTS;
    const bool second = mbase >= Msplit;
    const int mrow = second ? mbase - Msplit : mbase;
    const float* qxyz   = second ? qB   : qA;
    const float* cxyz   = second ? cB   : cA;
    const bf16*  nbr_b  = second ? nbrB : nbrA;
    const int*   idx    = second ? idxB : idxA;
    const int b = mrow >> 12;
    const int nbase = mrow & (NPT - 1);

    if (tid < 248) {
        float v;
        if      (tid <  24) v = w0[tid];
        else if (tid <  32) v = b0[tid - 24];
        else if (tid <  96) v = w1[tid - 32];
        else if (tid < 104) v = b1[tid - 96];
        else if (tid < 232) v = w2[tid - 104];
        else                v = b2[tid - 232];
        wp[tid] = v;
    }
    if (tid < PTS * NBR)
        nb[tid] = idx[(size_t)mrow * NBR + tid];
    __syncthreads();

    const int p  = tid & (PTS - 1);
    const int dg = tid / PTS;

    uint2 F[NBR];
    if (dg >= HALF) {
        const int d0 = (dg - HALF) * 4;
        const bf16* base = nbr_b + (size_t)b * NPT * D2 + d0;
        #pragma unroll
        for (int k = 0; k < NBR; ++k) {
            const int j = nb[p * NBR + k];
            F[k] = *(const uint2*)(base + (size_t)j * D2);
        }
    }

    if (tid < PTS * NBR) {
        const int pp = tid / NBR, k = tid % NBR;
        const int n = nbase + pp;
        const int j = nb[tid];
        const float* q = qxyz + (size_t)b * 3 * NPT;
        const float* c = cxyz + (size_t)b * 3 * NPT;
        const float dx = c[j]           - q[n];
        const float dy = c[NPT + j]     - q[NPT + n];
        const float dz = c[2 * NPT + j] - q[2 * NPT + n];
        float h1[8], h2[8];
        #pragma unroll
        for (int o = 0; o < 8; ++o) {
            float v = wp[24 + o];
            v = fmaf(dx, wp[o], v);
            v = fmaf(dy, wp[8 + o], v);
            v = fmaf(dz, wp[16 + o], v);
            h1[o] = fmaxf(v, 0.f);
        }
        #pragma unroll
        for (int o = 0; o < 8; ++o) {
            float v = wp[96 + o];
            #pragma unroll
            for (int i = 0; i < 8; ++i) v = fmaf(h1[i], wp[32 + i * 8 + o], v);
            h2[o] = fmaxf(v, 0.f);
        }
        #pragma unroll
        for (int o = 0; o < WD; ++o) {
            float v = wp[232 + o];
            #pragma unroll
            for (int i = 0; i < 8; ++i) v = fmaf(h2[i], wp[104 + i * WD + o], v);
            wgt[pp * WSTR + k * WD + o] = fmaxf(v, 0.f);
        }
    }
    __syncthreads();

    // ---- sw[p][w] = sum_k wgt[p][k][w] (k ascending), one thread each ----
    if (tid < PTS * 16) {
        const int pp = tid >> 4, w = tid & 15;
        const float* wgp = wgt + pp * WSTR + w;
        float sv = 0.f;
        #pragma unroll
        for (int k = 0; k < NBR; ++k) sv += wgp[k * WD];
        swb[(size_t)((int)blockIdx.x * PTS + pp) * 16 + w] = sv;
    }

    // ---- gather half: acc[4][16] over k, write elements >= D2*WD ----
    if (dg >= HALF) {
        const float* wg = wgt + p * WSTR;
        bf16* aout = agg + ((size_t)((int)blockIdx.x * PTS + p)) * (2 * D2 * WD);
        const int d0 = (dg - HALF) * 4;
        float acc[4][16];
        #pragma unroll
        for (int di = 0; di < 4; ++di)
            #pragma unroll
            for (int w = 0; w < 16; ++w) acc[di][w] = 0.f;
        #pragma unroll
        for (int k = 0; k < NBR; ++k) {
            union { uint2 u; bf16 h[4]; } uf;
            uf.u = F[k];
            float Fv[4];
            #pragma unroll
            for (int j = 0; j < 4; ++j) Fv[j] = __bfloat162float(uf.h[j]);
            const float4 v0 = *(const float4*)(wg + k * WD);
            const float4 v1 = *(const float4*)(wg + k * WD + 4);
            const float4 v2 = *(const float4*)(wg + k * WD + 8);
            const float4 v3 = *(const float4*)(wg + k * WD + 12);
            float w16[16];
            w16[0]  = v0.x; w16[1]  = v0.y; w16[2]  = v0.z; w16[3]  = v0.w;
            w16[4]  = v1.x; w16[5]  = v1.y; w16[6]  = v1.z; w16[7]  = v1.w;
            w16[8]  = v2.x; w16[9]  = v2.y; w16[10] = v2.z; w16[11] = v2.w;
            w16[12] = v3.x; w16[13] = v3.y; w16[14] = v3.z; w16[15] = v3.w;
            #pragma unroll
            for (int di = 0; di < 4; ++di)
                #pragma unroll
                for (int w = 0; w < 16; ++w)
                    acc[di][w] = fmaf(Fv[di], w16[w], acc[di][w]);
        }
        #pragma unroll
        for (int di = 0; di < 4; ++di) {
            union { bf16 h[16]; uint4 q[2]; } pk;
            #pragma unroll
            for (int w = 0; w < 16; ++w) pk.h[w] = __float2bfloat16(acc[di][w]);
            bf16* dst = aout + (D2 + d0 + di) * WD;
            *(uint4*)dst       = pk.q[0];
            *(uint4*)(dst + 8) = pk.q[1];
        }
    }
}

// ---------------------------------------------------------------------------
// MFMA GEMM v3: own-half A (k < K/2) is reconstructed during staging as
// bf16(own[row][d] * sw[row][w]) — identical arithmetic to what agg used to
// write — via ds_write_b128 into the exact slot GLD16 would fill (dest
// element tid*8 holds source chunk sch = ch^(row&3); read side unchanged).
// Gather-half A and B tiles stage via GLD16 as before.
//   ownf: fp32 point-major rows, GLOBAL indexing (m0+mb+row), stride K/32.
//   swb : chunk-local [rows][16] fp32.
// ---------------------------------------------------------------------------
__global__ __launch_bounds__(256)
void gemm_mfma(const bf16* __restrict__ A, const bf16* __restrict__ Bhi,
               const bf16* __restrict__ Blo, const float* __restrict__ bias,
               const float* __restrict__ ownf, const float* __restrict__ swb,
               float* __restrict__ out_t, float* __restrict__ out_pm,
               bf16* __restrict__ out_pmb, int m0, int K)
{
    __shared__ __align__(16) char smem[40960];
    bf16* lds = (bf16*)smem;

    const int tid  = threadIdx.x;
    const int w    = tid >> 6;
    const int lane = tid & 63;
    const int wr   = w >> 1, wc = w & 1;
    const int mb   = (int)blockIdx.x * 64;
    const int gK   = lane >> 4;
    const int rL   = lane & 15;
    const int D2v  = K / 32;            // 64 or 128

    // staging-thread constants (row/ch fixed per thread)
    const int row_s = tid >> 2, ch_s = tid & 3;
    const int sch_s = ch_s ^ (row_s & 3);
    const int w0_s  = (sch_s & 1) * 8;  // (sch*8) & 15
    float sww[8];
    {
        const float* sp = swb + (size_t)(mb + row_s) * 16 + w0_s;
        const float4 a = *(const float4*)sp;
        const float4 b2 = *(const float4*)(sp + 4);
        sww[0] = a.x;  sww[1] = a.y;  sww[2] = a.z;  sww[3] = a.w;
        sww[4] = b2.x; sww[5] = b2.y; sww[6] = b2.z; sww[7] = b2.w;
    }
    const float* ownrow_g = ownf + (size_t)(m0 + mb + row_s) * D2v;

    f32x4 acc[2][4];
    #pragma unroll
    for (int i = 0; i < 2; ++i)
        #pragma unroll
        for (int j = 0; j < 4; ++j) acc[i][j] = (f32x4)0.f;

    const int nk = K / 32;
    const int nkOwn = nk / 2;           // k < K/2 is the own (rank-1) range

    auto stage = [&](int buf, int kt) {
        const int kb = kt * 32;
        const int bufo = buf * 10240;
        if (kt < nkOwn) {   // A own-half: compute bf16(own_d * sw_w)
            const int d = kt * 2 + (sch_s >> 1);
            const float f = ownrow_g[d];
            union { bf16 h[8]; uint4 q; } pk;
            #pragma unroll
            for (int j = 0; j < 8; ++j) pk.h[j] = __float2bfloat16(f * sww[j]);
            *(uint4*)(lds + bufo + tid * 8) = pk.q;
        } else {            // A gather-half via async load
            GLD16(A + (size_t)(mb + row_s) * K + kb + (sch_s << 3),
                  lds + bufo + ((w * 64) << 3));
        }
        #pragma unroll
        for (int i = 0; i < 2; ++i) {   // B tiles (full K range)
            const int s2 = i * 256 + tid;
            const int row = s2 >> 2, ch = s2 & 3;
            const int sch = ch ^ (row & 3);
            const int wb = (i * 256 + w * 64) << 3;
            GLD16(Bhi + (size_t)row * K + kb + (sch << 3), lds + bufo + 2048 + wb);
            GLD16(Blo + (size_t)row * K + kb + (sch << 3), lds + bufo + 6144 + wb);
        }
    };

    stage(0, 0);
    __syncthreads();

    for (int kt = 0; kt < nk; ++kt) {
        const int cur = kt & 1;
        if (kt + 1 < nk) stage(cur ^ 1, kt + 1);

        const bf16* la  = lds + cur * 10240;
        const bf16* lbh = la + 2048;
        const bf16* lbl = la + 6144;

        bf16x8 af[2], bh[4], bl[4];
        #pragma unroll
        for (int mf = 0; mf < 2; ++mf) {
            const int row = wr * 32 + mf * 16 + rL;
            af[mf] = *(const bf16x8*)(la + row * 32 + ((gK ^ (row & 3)) << 3));
        }
        #pragma unroll
        for (int nf = 0; nf < 4; ++nf) {
            const int col = wc * 64 + nf * 16 + rL;
            const int off = col * 32 + ((gK ^ (col & 3)) << 3);
            bh[nf] = *(const bf16x8*)(lbh + off);
            bl[nf] = *(const bf16x8*)(lbl + off);
        }
        #pragma unroll
        for (int mf = 0; mf < 2; ++mf)
            #pragma unroll
            for (int nf = 0; nf < 4; ++nf) {
                acc[mf][nf] = __builtin_amdgcn_mfma_f32_16x16x32_bf16(af[mf], bh[nf], acc[mf][nf], 0, 0, 0);
                acc[mf][nf] = __builtin_amdgcn_mfma_f32_16x16x32_bf16(af[mf], bl[nf], acc[mf][nf], 0, 0, 0);
            }
        __syncthreads();
    }

    float (*tile)[133] = (float(*)[133])smem;
    #pragma unroll
    for (int mf = 0; mf < 2; ++mf)
        #pragma unroll
        for (int nf = 0; nf < 4; ++nf) {
            const int col = wc * 64 + nf * 16 + rL;
            const float bs = bias[col];
            #pragma unroll
            for (int qq = 0; qq < 4; ++qq) {
                const int rrow = wr * 32 + mf * 16 + gK * 4 + qq;
                const float v = acc[mf][nf][qq] + bs;
                tile[rrow][col] = v > 0.f ? v : 0.1f * v;
            }
        }
    __syncthreads();

    const int mrow = m0 + mb;
    const int b = mrow >> 12, n0 = mrow & (NPT - 1);
    for (int e = tid; e < 64 * MIDD; e += 256) {
        const int o = e >> 6, i = e & 63;
        out_t[((size_t)b * MIDD + o) * NPT + n0 + i] = tile[i][o];
    }
    if (out_pm) {
        for (int e = tid; e < 64 * MIDD; e += 256) {
            const int i = e >> 7, o = e & 127;
            const float v = tile[i][o];
            out_pm [(size_t)(mrow + i) * MIDD + o] = v;
            out_pmb[(size_t)(mrow + i) * MIDD + o] = __float2bfloat16(v);
        }
    }
}

// ---------------------------------------------------------------------------
extern "C" void kernel_launch(void* const* d_in, const int* in_sizes, int n_in,
                              void* d_out, int out_size, void* d_ws, size_t ws_size,
                              hipStream_t stream)
{
    (void)in_sizes; (void)n_in; (void)out_size;
    const float* pc1    = (const float*)d_in[0];
    const float* pc2    = (const float*)d_in[1];
    const float* feat1  = (const float*)d_in[2];
    const float* feat2  = (const float*)d_in[3];
    const float* wn1_w0 = (const float*)d_in[4];
    const float* wn1_b0 = (const float*)d_in[5];
    const float* wn1_w1 = (const float*)d_in[6];
    const float* wn1_b1 = (const float*)d_in[7];
    const float* wn1_w2 = (const float*)d_in[8];
    const float* wn1_b2 = (const float*)d_in[9];
    const float* lin1_w = (const float*)d_in[10];
    const float* lin1_b = (const float*)d_in[11];
    const float* wn2_w0 = (const float*)d_in[12];
    const float* wn2_b0 = (const float*)d_in[13];
    const float* wn2_w1 = (const float*)d_in[14];
    const float* wn2_b1 = (const float*)d_in[15];
    const float* wn2_w2 = (const float*)d_in[16];
    const float* wn2_b2 = (const float*)d_in[17];
    const float* lin2_w = (const float*)d_in[18];
    const float* lin2_b = (const float*)d_in[19];
    float* out = (float*)d_out;

    const int M  = BB * NPT;
    const int M2 = 2 * M;
    const int K1 = 2 * CDIM * WD;     // 2048
    const int K2 = 2 * MIDD * WD;     // 4096

    char* ws = (char*)d_ws;
    float* p1pm = (float*)ws;                          // [M][64] f32 (contiguous with p2pm -> [2M][64])
    float* p2pm = p1pm + (size_t)M * CDIM;             // [M][64] f32
    float* fpm  = p2pm + (size_t)M * CDIM;             // [2M][128] f32 (f1|f2)
    bf16*  p1b  = (bf16*)(fpm + (size_t)M2 * MIDD);    // [M][64] bf16
    bf16*  p2b  = p1b + (size_t)M * CDIM;              // [M][64] bf16
    bf16*  fb   = p2b + (size_t)M * CDIM;              // [2M][128] bf16
    int* idx12  = (int*)(fb + (size_t)M2 * MIDD);
    int* idx21  = idx12 + (size_t)M * NBR;
    bf16* b1hi  = (bf16*)(idx21 + (size_t)M * NBR);
    bf16* b1lo  = b1hi + (size_t)MIDD * K1;
    bf16* b2hi  = b1lo + (size_t)MIDD * K1;
    bf16* b2lo  = b2hi + (size_t)MIDD * K2;
    float* swbuf = (float*)(b2lo + (size_t)MIDD * K2); // [<=2M][16] f32 (chunk-local)
    bf16* aggbuf = (bf16*)(swbuf + (size_t)M2 * 16);
    const size_t used = (size_t)((char*)aggbuf - ws);
    const size_t avail = ws_size > used ? ws_size - used : 0;

    float* f1t = out;
    float* fft = out + 2 * (size_t)BB * MIDD * NPT;

    prep_kernel<<<2816, 256, 0, stream>>>(feat1, feat2, p1pm, p1b, p2pm, p2b,
                                          lin1_w, b1hi, b1lo, lin2_w, b2hi, b2lo);
    knn_kernel<<<dim3(NPT / KQ, BB, 2), 256, 0, stream>>>(pc1, pc2, idx12, idx21);

    auto chunk_rows = [&](int K) -> int {
        long rows = (long)(avail / ((size_t)K * sizeof(bf16)));
        int cm = (int)(rows > M2 ? M2 : rows) & ~127;
        if (cm < 128) cm = 128;
        return cm;
    };

    {   // cross 1 + cross 2 merged (K = 2048); own rows = p1pm|p2pm contiguous
        const int CMr = chunk_rows(K1);
        for (int m0 = 0; m0 < M2; m0 += CMr) {
            const int cm = (M2 - m0 < CMr) ? (M2 - m0) : CMr;
            agg_kernel<CDIM, 8><<<cm / 8, 256, 0, stream>>>(
                pc1, pc2, p2b, idx12,
                pc2, pc1, p1b, idx21, M,
                wn1_w0, wn1_b0, wn1_w1, wn1_b1, wn1_w2, wn1_b2,
                aggbuf, swbuf, m0);
            gemm_mfma<<<cm / 64, 256, 0, stream>>>(aggbuf, b1hi, b1lo, lin1_b,
                                                   p1pm, swbuf,
                                                   f1t, fpm, fb, m0, K1);
        }
    }
    {   // cross 3 (K = 4096): own rows = fpm[0..M), gather from f2 (bf16)
        const int CMr = chunk_rows(K2);
        for (int m0 = 0; m0 < M; m0 += CMr) {
            const int cm = (M - m0 < CMr) ? (M - m0) : CMr;
            agg_kernel<MIDD, 4><<<cm / 4, 256, 0, stream>>>(
                pc1, pc2, fb + (size_t)M * MIDD, idx12,
                nullptr, nullptr, nullptr, nullptr, M2,
                wn2_w0, wn2_b0, wn2_w1, wn2_b1, wn2_w2, wn2_b2,
                aggbuf, swbuf, m0);
            gemm_mfma<<<cm / 64, 256, 0, stream>>>(aggbuf, b2hi, b2lo, lin2_b,
                                                   fpm, swbuf,
                                                   fft, nullptr, nullptr, m0, K2);
        }
    }
}

// Round 16
// 362.980 us; speedup vs baseline: 1.2652x; 1.0270x over previous
//
#include <hip/hip_runtime.h>
#include <hip/hip_bf16.h>
#include <cstddef>
#include <cstdint>

typedef __hip_bfloat16 bf16;
typedef __attribute__((ext_vector_type(8))) short bf16x8;   // 8 bf16 = 4 VGPRs
typedef __attribute__((ext_vector_type(4))) float f32x4;

#define NPT 4096   // points per cloud
#define BB  4      // batch
#define NBR 16     // neighbors (nsample)
#define WD  16     // weightnet output width
#define CDIM 64    // input feature channels
#define MIDD 128   // lin1/lin2 output channels

// async global->LDS, 16B per lane; LDS dest is wave-uniform base + lane*16
#define GLD16(g, l) __builtin_amdgcn_global_load_lds( \
    (const __attribute__((address_space(1))) unsigned int*)(const void*)(g), \
    (__attribute__((address_space(3))) unsigned int*)(void*)(l), 16, 0, 0)

// ---------------------------------------------------------------------------
// Fused prep: feature transposes (fp32+bf16) + lin-weight hi/lo splits.
// ---------------------------------------------------------------------------
__global__ __launch_bounds__(256)
void prep_kernel(const float* __restrict__ feat1, const float* __restrict__ feat2,
                 float* __restrict__ p1pm, bf16* __restrict__ p1b,
                 float* __restrict__ p2pm, bf16* __restrict__ p2b,
                 const float* __restrict__ lin1_w, bf16* __restrict__ b1hi, bf16* __restrict__ b1lo,
                 const float* __restrict__ lin2_w, bf16* __restrict__ b2hi, bf16* __restrict__ b2lo)
{
    __shared__ float t[32][33];
    const int tx = threadIdx.x & 31, ty = threadIdx.x >> 5;
    const int id = blockIdx.x;
    if (id < 2048) {
        const int which = id >> 10;
        const int nt = id & 1023;
        const int n0 = (nt & 127) * 32;
        const int c0 = ((nt >> 7) & 1) * 32;
        const int b  = nt >> 8;
        const float* in = which ? feat2 : feat1;
        float* out  = which ? p2pm : p1pm;
        bf16*  outb = which ? p2b  : p1b;
        #pragma unroll
        for (int r = ty; r < 32; r += 8)
            t[r][tx] = in[((size_t)b * CDIM + c0 + r) * NPT + n0 + tx];
        __syncthreads();
        #pragma unroll
        for (int r = ty; r < 32; r += 8) {
            const float v = t[tx][r];
            out [((size_t)b * NPT + n0 + r) * CDIM + c0 + tx] = v;
            outb[((size_t)b * NPT + n0 + r) * CDIM + c0 + tx] = __float2bfloat16(v);
        }
    } else {
        const float* w; bf16 *hi, *lo; int K, k0, o0;
        if (id < 2304) {
            const int id2 = id - 2048;
            w = lin1_w; hi = b1hi; lo = b1lo; K = 2048;
            k0 = (id2 & 63) * 32; o0 = (id2 >> 6) * 32;
        } else {
            const int id2 = id - 2304;
            w = lin2_w; hi = b2hi; lo = b2lo; K = 4096;
            k0 = (id2 & 127) * 32; o0 = (id2 >> 7) * 32;
        }
        #pragma unroll
        for (int r = ty; r < 32; r += 8)
            t[r][tx] = w[(size_t)(k0 + r) * MIDD + o0 + tx];
        __syncthreads();
        #pragma unroll
        for (int r = ty; r < 32; r += 8) {
            const float v = t[tx][r];
            const bf16 h = __float2bfloat16(v);
            const bf16 l2 = __float2bfloat16(v - __bfloat162float(h));
            hi[(size_t)(o0 + r) * K + k0 + tx] = h;
            lo[(size_t)(o0 + r) * K + k0 + tx] = l2;
        }
    }
}

// ---------------------------------------------------------------------------
// KNN v5b (round-14, unchanged).
// ---------------------------------------------------------------------------
#define KQ     16
#define KSEG   16
#define KCH    64
#define KSTAGE 1024
#define KRING  96

__global__ __launch_bounds__(256)
void knn_kernel(const float* __restrict__ pcA, const float* __restrict__ pcB,
                int* __restrict__ idxAB, int* __restrict__ idxBA)
{
    const float *qxyz, *cxyz; int* idx_out;
    if (blockIdx.z == 0) { qxyz = pcA; cxyz = pcB; idx_out = idxAB; }
    else                 { qxyz = pcB; cxyz = pcA; idx_out = idxBA; }

    __shared__ float4 cf[KSTAGE + KSTAGE / KCH];   // skewed
    __shared__ float  pubd[2][KSEG][KQ];
    __shared__ float4 qc[KQ];
    __shared__ float  u16s[KQ];
    __shared__ int    rcnt[KQ];
    __shared__ int    wtot;
    __shared__ int    wl[256];
    __shared__ float  ringd[KQ][KRING + 1];
    __shared__ int    ringi[KQ][KRING + 1];

    const int tid = threadIdx.x;
    const int q   = tid & (KQ - 1);
    const int s   = tid >> 4;
    const int b   = blockIdx.y;
    const int n   = blockIdx.x * KQ + q;

    const float* qp = qxyz + (size_t)b * 3 * NPT;
    const float qx = qp[n], qy = qp[NPT + n], qz = qp[2 * NPT + n];
    const float q2 = fmaf(qx, qx, fmaf(qy, qy, qz * qz));
    const float* c = cxyz + (size_t)b * 3 * NPT;

    if (tid < KQ) rcnt[tid] = 0;
    if (tid == 0) wtot = 0;
    if (s == 0) qc[q] = make_float4(qx, qy, qz, q2);

    float b0 = 3.4e38f, b1 = 3.4e38f;
    for (int st = 0; st < NPT; st += KSTAGE) {
        __syncthreads();
        {
            #pragma unroll
            for (int r = 0; r < KSTAGE / 256; ++r) {
                const int j = r * 256 + tid;
                const int g = st + j;
                const float x = c[g], y = c[NPT + g], z = c[2 * NPT + g];
                cf[j + (j >> 6)] = make_float4(x, y, z,
                    fmaf(x, x, fmaf(y, y, z * z)));
            }
        }
        __syncthreads();
        const int base = s * (KCH + 1);
        #pragma unroll 4
        for (int jj = 0; jj < KCH; ++jj) {
            const float4 pv = cf[base + jj];
            const float dot = fmaf(qx, pv.x, fmaf(qy, pv.y, qz * pv.z));
            const float d = q2 + pv.w - 2.f * dot;
            const float t = fmaxf(b0, d);
            b0 = fminf(b0, d);
            b1 = fminf(b1, t);
        }
    }
    pubd[0][s][q] = b0;
    pubd[1][s][q] = b1;
    __syncthreads();

    {
        float tv[32];
        #pragma unroll
        for (int j = 0; j < 32; ++j) tv[j] = pubd[j >> 4][j & 15][q];
        #pragma unroll
        for (int rep = 0; rep < 2; ++rep) {
            const int j = rep * 16 + s;
            const float vj = pubd[rep][s][q];
            int rank = 0;
            #pragma unroll
            for (int k = 0; k < 32; ++k)
                rank += (tv[k] < vj || (tv[k] == vj && k < j)) ? 1 : 0;
            if (rank == 15) u16s[q] = vj;
        }
    }
    __syncthreads();

    if (b0 <= u16s[q]) {
        const int u = atomicAdd(&wtot, 1);
        wl[u] = (q << 4) | s;
    }
    __syncthreads();

    {
        const int W = wtot;
        const int lu = tid & 15;
        for (int u = tid >> 4; u < W; u += 16) {
            const int qq  = wl[u] >> 4;
            const int seg = wl[u] & 15;
            const float4 qv = qc[qq];
            const float gate = u16s[qq];
            #pragma unroll
            for (int ch = 0; ch < 4; ++ch) {
                const int j = ch * KSTAGE + seg * KCH + lu * 4;
                const float4 xs = *(const float4*)(c + j);
                const float4 ys = *(const float4*)(c + NPT + j);
                const float4 zs = *(const float4*)(c + 2 * NPT + j);
                const float xv[4] = { xs.x, xs.y, xs.z, xs.w };
                const float yv[4] = { ys.x, ys.y, ys.z, ys.w };
                const float zv[4] = { zs.x, zs.y, zs.z, zs.w };
                #pragma unroll
                for (int e = 0; e < 4; ++e) {
                    const float p2 = fmaf(xv[e], xv[e], fmaf(yv[e], yv[e], zv[e] * zv[e]));
                    const float dot = fmaf(qv.x, xv[e], fmaf(qv.y, yv[e], qv.z * zv[e]));
                    const float d = qv.w + p2 - 2.f * dot;
                    if (d <= gate) {
                        const int slot = atomicAdd(&rcnt[qq], 1);
                        if (slot < KRING) { ringd[qq][slot] = d; ringi[qq][slot] = j + e; }
                    }
                }
            }
        }
    }
    __syncthreads();

    {
        const int cnt = min(rcnt[q], KRING);
        int* op = idx_out + ((size_t)b * NPT + n) * NBR;
        for (int e = s; e < cnt; e += KSEG) {
            const float de = ringd[q][e];
            const int   ie = ringi[q][e];
            int rank = 0;
            for (int k = 0; k < cnt; ++k) {
                const float dk = ringd[q][k];
                const int   ik = ringi[q][k];
                rank += (dk < de || (dk == de && ik < ie)) ? 1 : 0;
            }
            if (rank < NBR) op[rank] = ie;
        }
    }
}

// ---------------------------------------------------------------------------
// Weightnet + aggregation v6 (round-15, unchanged): gather half + swb only.
// ---------------------------------------------------------------------------
template<int D2, int PTS>
__global__ __launch_bounds__(256)
void agg_kernel(const float* __restrict__ qA, const float* __restrict__ cA,
                const bf16* __restrict__ nbrA, const int* __restrict__ idxA,
                const float* __restrict__ qB, const float* __restrict__ cB,
                const bf16* __restrict__ nbrB, const int* __restrict__ idxB,
                int Msplit,
                const float* __restrict__ w0, const float* __restrict__ b0,
                const float* __restrict__ w1, const float* __restrict__ b1,
                const float* __restrict__ w2, const float* __restrict__ b2,
                bf16* __restrict__ agg, float* __restrict__ swb, int m0)
{
    constexpr int TPP   = 256 / PTS;
    constexpr int HALF  = TPP / 2;
    constexpr int WSTR  = 276;

    __shared__ float wp[248];
    __shared__ int   nb[PTS * NBR];
    __shared__ float wgt[PTS * WSTR];

    const int tid = threadIdx.x;
    const int mbase = m0 + (int)blockIdx.x * PTS;
    const bool second = mbase >= Msplit;
    const int mrow = second ? mbase - Msplit : mbase;
    const float* qxyz   = second ? qB   : qA;
    const float* cxyz   = second ? cB   : cA;
    const bf16*  nbr_b  = second ? nbrB : nbrA;
    const int*   idx    = second ? idxB : idxA;
    const int b = mrow >> 12;
    const int nbase = mrow & (NPT - 1);

    if (tid < 248) {
        float v;
        if      (tid <  24) v = w0[tid];
        else if (tid <  32) v = b0[tid - 24];
        else if (tid <  96) v = w1[tid - 32];
        else if (tid < 104) v = b1[tid - 96];
        else if (tid < 232) v = w2[tid - 104];
        else                v = b2[tid - 232];
        wp[tid] = v;
    }
    if (tid < PTS * NBR)
        nb[tid] = idx[(size_t)mrow * NBR + tid];
    __syncthreads();

    const int p  = tid & (PTS - 1);
    const int dg = tid / PTS;

    uint2 F[NBR];
    if (dg >= HALF) {
        const int d0 = (dg - HALF) * 4;
        const bf16* base = nbr_b + (size_t)b * NPT * D2 + d0;
        #pragma unroll
        for (int k = 0; k < NBR; ++k) {
            const int j = nb[p * NBR + k];
            F[k] = *(const uint2*)(base + (size_t)j * D2);
        }
    }

    if (tid < PTS * NBR) {
        const int pp = tid / NBR, k = tid % NBR;
        const int n = nbase + pp;
        const int j = nb[tid];
        const float* q = qxyz + (size_t)b * 3 * NPT;
        const float* c = cxyz + (size_t)b * 3 * NPT;
        const float dx = c[j]           - q[n];
        const float dy = c[NPT + j]     - q[NPT + n];
        const float dz = c[2 * NPT + j] - q[2 * NPT + n];
        float h1[8], h2[8];
        #pragma unroll
        for (int o = 0; o < 8; ++o) {
            float v = wp[24 + o];
            v = fmaf(dx, wp[o], v);
            v = fmaf(dy, wp[8 + o], v);
            v = fmaf(dz, wp[16 + o], v);
            h1[o] = fmaxf(v, 0.f);
        }
        #pragma unroll
        for (int o = 0; o < 8; ++o) {
            float v = wp[96 + o];
            #pragma unroll
            for (int i = 0; i < 8; ++i) v = fmaf(h1[i], wp[32 + i * 8 + o], v);
            h2[o] = fmaxf(v, 0.f);
        }
        #pragma unroll
        for (int o = 0; o < WD; ++o) {
            float v = wp[232 + o];
            #pragma unroll
            for (int i = 0; i < 8; ++i) v = fmaf(h2[i], wp[104 + i * WD + o], v);
            wgt[pp * WSTR + k * WD + o] = fmaxf(v, 0.f);
        }
    }
    __syncthreads();

    if (tid < PTS * 16) {
        const int pp = tid >> 4, w = tid & 15;
        const float* wgp = wgt + pp * WSTR + w;
        float sv = 0.f;
        #pragma unroll
        for (int k = 0; k < NBR; ++k) sv += wgp[k * WD];
        swb[(size_t)((int)blockIdx.x * PTS + pp) * 16 + w] = sv;
    }

    if (dg >= HALF) {
        const float* wg = wgt + p * WSTR;
        bf16* aout = agg + ((size_t)((int)blockIdx.x * PTS + p)) * (2 * D2 * WD);
        const int d0 = (dg - HALF) * 4;
        float acc[4][16];
        #pragma unroll
        for (int di = 0; di < 4; ++di)
            #pragma unroll
            for (int w = 0; w < 16; ++w) acc[di][w] = 0.f;
        #pragma unroll
        for (int k = 0; k < NBR; ++k) {
            union { uint2 u; bf16 h[4]; } uf;
            uf.u = F[k];
            float Fv[4];
            #pragma unroll
            for (int j = 0; j < 4; ++j) Fv[j] = __bfloat162float(uf.h[j]);
            const float4 v0 = *(const float4*)(wg + k * WD);
            const float4 v1 = *(const float4*)(wg + k * WD + 4);
            const float4 v2 = *(const float4*)(wg + k * WD + 8);
            const float4 v3 = *(const float4*)(wg + k * WD + 12);
            float w16[16];
            w16[0]  = v0.x; w16[1]  = v0.y; w16[2]  = v0.z; w16[3]  = v0.w;
            w16[4]  = v1.x; w16[5]  = v1.y; w16[6]  = v1.z; w16[7]  = v1.w;
            w16[8]  = v2.x; w16[9]  = v2.y; w16[10] = v2.z; w16[11] = v2.w;
            w16[12] = v3.x; w16[13] = v3.y; w16[14] = v3.z; w16[15] = v3.w;
            #pragma unroll
            for (int di = 0; di < 4; ++di)
                #pragma unroll
                for (int w = 0; w < 16; ++w)
                    acc[di][w] = fmaf(Fv[di], w16[w], acc[di][w]);
        }
        #pragma unroll
        for (int di = 0; di < 4; ++di) {
            union { bf16 h[16]; uint4 q[2]; } pk;
            #pragma unroll
            for (int w = 0; w < 16; ++w) pk.h[w] = __float2bfloat16(acc[di][w]);
            bf16* dst = aout + (D2 + d0 + di) * WD;
            *(uint4*)dst       = pk.q[0];
            *(uint4*)(dst + 8) = pk.q[1];
        }
    }
}

// ---------------------------------------------------------------------------
// MFMA GEMM v4: templated block-M. BM=64 (cross 1/2) or BM=32 (cross 3 —
// 512 blocks = 2 blocks/CU so barrier drains of co-resident blocks overlap).
// Own-half A (k < K/2) reconstructed during staging (round-15 scheme,
// bit-identical); gather-half A + B tiles via GLD16 (A staged by the first
// BM/16 waves only — GLD16 dest is wave-uniform base + lane*16).
// ---------------------------------------------------------------------------
template<int BM>
__global__ __launch_bounds__(256)
void gemm_mfma(const bf16* __restrict__ A, const bf16* __restrict__ Bhi,
               const bf16* __restrict__ Blo, const float* __restrict__ bias,
               const float* __restrict__ ownf, const float* __restrict__ swb,
               float* __restrict__ out_t, float* __restrict__ out_pm,
               bf16* __restrict__ out_pmb, int m0, int K)
{
    constexpr int AE   = BM * 32;          // A tile elements
    constexpr int BUFE = AE + 8192;        // per-buffer elements (A + Bhi + Blo)
    constexpr int MF   = BM / 32;          // A fragments per wave (2 or 1)
    __shared__ __align__(16) char smem[2 * BUFE * 2];
    bf16* lds = (bf16*)smem;

    const int tid  = threadIdx.x;
    const int w    = tid >> 6;
    const int lane = tid & 63;
    const int wr   = w >> 1, wc = w & 1;
    const int mb   = (int)blockIdx.x * BM;
    const int gK   = lane >> 4;
    const int rL   = lane & 15;
    const int D2v  = K / 32;

    // staging-thread constants (clamped for threads beyond the A tile)
    const int row_r = tid >> 2;
    const int row_s = row_r < BM ? row_r : BM - 1;
    const int ch_s  = tid & 3;
    const int sch_s = ch_s ^ (row_s & 3);
    const int w0_s  = (sch_s & 1) * 8;
    float sww[8];
    {
        const float* sp = swb + (size_t)(mb + row_s) * 16 + w0_s;
        const float4 a = *(const float4*)sp;
        const float4 b2 = *(const float4*)(sp + 4);
        sww[0] = a.x;  sww[1] = a.y;  sww[2] = a.z;  sww[3] = a.w;
        sww[4] = b2.x; sww[5] = b2.y; sww[6] = b2.z; sww[7] = b2.w;
    }
    const float* ownrow_g = ownf + (size_t)(m0 + mb + row_s) * D2v;

    f32x4 acc[MF][4];
    #pragma unroll
    for (int i = 0; i < MF; ++i)
        #pragma unroll
        for (int j = 0; j < 4; ++j) acc[i][j] = (f32x4)0.f;

    const int nk = K / 32;
    const int nkOwn = nk / 2;

    auto stage = [&](int buf, int kt) {
        const int kb = kt * 32;
        const int bufo = buf * BUFE;
        if (kt < nkOwn) {
            if (tid < BM * 4) {
                const int d = kt * 2 + (sch_s >> 1);
                const float f = ownrow_g[d];
                union { bf16 h[8]; uint4 q; } pk;
                #pragma unroll
                for (int j = 0; j < 8; ++j) pk.h[j] = __float2bfloat16(f * sww[j]);
                *(uint4*)(lds + bufo + tid * 8) = pk.q;
            }
        } else {
            if (w * 64 < BM * 4)    // wave-uniform guard
                GLD16(A + (size_t)(mb + row_r) * K + kb + (sch_s << 3),
                      lds + bufo + ((w * 64) << 3));
        }
        #pragma unroll
        for (int i = 0; i < 2; ++i) {   // B tiles
            const int s2 = i * 256 + tid;
            const int row = s2 >> 2, ch = s2 & 3;
            const int sch = ch ^ (row & 3);
            const int wb = (i * 256 + w * 64) << 3;
            GLD16(Bhi + (size_t)row * K + kb + (sch << 3), lds + bufo + AE + wb);
            GLD16(Blo + (size_t)row * K + kb + (sch << 3), lds + bufo + AE + 4096 + wb);
        }
    };

    stage(0, 0);
    __syncthreads();

    for (int kt = 0; kt < nk; ++kt) {
        const int cur = kt & 1;
        if (kt + 1 < nk) stage(cur ^ 1, kt + 1);

        const bf16* la  = lds + cur * BUFE;
        const bf16* lbh = la + AE;
        const bf16* lbl = la + AE + 4096;

        bf16x8 af[MF], bh[4], bl[4];
        #pragma unroll
        for (int mf = 0; mf < MF; ++mf) {
            const int row = wr * (BM / 2) + mf * 16 + rL;
            af[mf] = *(const bf16x8*)(la + row * 32 + ((gK ^ (row & 3)) << 3));
        }
        #pragma unroll
        for (int nf = 0; nf < 4; ++nf) {
            const int col = wc * 64 + nf * 16 + rL;
            const int off = col * 32 + ((gK ^ (col & 3)) << 3);
            bh[nf] = *(const bf16x8*)(lbh + off);
            bl[nf] = *(const bf16x8*)(lbl + off);
        }
        #pragma unroll
        for (int mf = 0; mf < MF; ++mf)
            #pragma unroll
            for (int nf = 0; nf < 4; ++nf) {
                acc[mf][nf] = __builtin_amdgcn_mfma_f32_16x16x32_bf16(af[mf], bh[nf], acc[mf][nf], 0, 0, 0);
                acc[mf][nf] = __builtin_amdgcn_mfma_f32_16x16x32_bf16(af[mf], bl[nf], acc[mf][nf], 0, 0, 0);
            }
        __syncthreads();
    }

    float (*tile)[133] = (float(*)[133])smem;
    #pragma unroll
    for (int mf = 0; mf < MF; ++mf)
        #pragma unroll
        for (int nf = 0; nf < 4; ++nf) {
            const int col = wc * 64 + nf * 16 + rL;
            const float bs = bias[col];
            #pragma unroll
            for (int qq = 0; qq < 4; ++qq) {
                const int rrow = wr * (BM / 2) + mf * 16 + gK * 4 + qq;
                const float v = acc[mf][nf][qq] + bs;
                tile[rrow][col] = v > 0.f ? v : 0.1f * v;
            }
        }
    __syncthreads();

    const int mrow = m0 + mb;
    const int b = mrow >> 12, n0 = mrow & (NPT - 1);
    for (int e = tid; e < BM * MIDD; e += 256) {
        const int o = e / BM, i = e % BM;
        out_t[((size_t)b * MIDD + o) * NPT + n0 + i] = tile[i][o];
    }
    if (out_pm) {
        for (int e = tid; e < BM * MIDD; e += 256) {
            const int i = e >> 7, o = e & 127;
            const float v = tile[i][o];
            out_pm [(size_t)(mrow + i) * MIDD + o] = v;
            out_pmb[(size_t)(mrow + i) * MIDD + o] = __float2bfloat16(v);
        }
    }
}

// ---------------------------------------------------------------------------
extern "C" void kernel_launch(void* const* d_in, const int* in_sizes, int n_in,
                              void* d_out, int out_size, void* d_ws, size_t ws_size,
                              hipStream_t stream)
{
    (void)in_sizes; (void)n_in; (void)out_size;
    const float* pc1    = (const float*)d_in[0];
    const float* pc2    = (const float*)d_in[1];
    const float* feat1  = (const float*)d_in[2];
    const float* feat2  = (const float*)d_in[3];
    const float* wn1_w0 = (const float*)d_in[4];
    const float* wn1_b0 = (const float*)d_in[5];
    const float* wn1_w1 = (const float*)d_in[6];
    const float* wn1_b1 = (const float*)d_in[7];
    const float* wn1_w2 = (const float*)d_in[8];
    const float* wn1_b2 = (const float*)d_in[9];
    const float* lin1_w = (const float*)d_in[10];
    const float* lin1_b = (const float*)d_in[11];
    const float* wn2_w0 = (const float*)d_in[12];
    const float* wn2_b0 = (const float*)d_in[13];
    const float* wn2_w1 = (const float*)d_in[14];
    const float* wn2_b1 = (const float*)d_in[15];
    const float* wn2_w2 = (const float*)d_in[16];
    const float* wn2_b2 = (const float*)d_in[17];
    const float* lin2_w = (const float*)d_in[18];
    const float* lin2_b = (const float*)d_in[19];
    float* out = (float*)d_out;

    const int M  = BB * NPT;
    const int M2 = 2 * M;
    const int K1 = 2 * CDIM * WD;     // 2048
    const int K2 = 2 * MIDD * WD;     // 4096

    char* ws = (char*)d_ws;
    float* p1pm = (float*)ws;                          // [M][64] f32 (contig -> [2M][64])
    float* p2pm = p1pm + (size_t)M * CDIM;             // [M][64] f32
    float* fpm  = p2pm + (size_t)M * CDIM;             // [2M][128] f32 (f1|f2)
    bf16*  p1b  = (bf16*)(fpm + (size_t)M2 * MIDD);    // [M][64] bf16
    bf16*  p2b  = p1b + (size_t)M * CDIM;              // [M][64] bf16
    bf16*  fb   = p2b + (size_t)M * CDIM;              // [2M][128] bf16
    int* idx12  = (int*)(fb + (size_t)M2 * MIDD);
    int* idx21  = idx12 + (size_t)M * NBR;
    bf16* b1hi  = (bf16*)(idx21 + (size_t)M * NBR);
    bf16* b1lo  = b1hi + (size_t)MIDD * K1;
    bf16* b2hi  = b1lo + (size_t)MIDD * K1;
    bf16* b2lo  = b2hi + (size_t)MIDD * K2;
    float* swbuf = (float*)(b2lo + (size_t)MIDD * K2); // [<=2M+pad][16] f32
    bf16* aggbuf = (bf16*)(swbuf + (size_t)(M2 + 64) * 16);
    const size_t used = (size_t)((char*)aggbuf - ws);
    const size_t avail = ws_size > used ? ws_size - used : 0;

    float* f1t = out;
    float* fft = out + 2 * (size_t)BB * MIDD * NPT;

    prep_kernel<<<2816, 256, 0, stream>>>(feat1, feat2, p1pm, p1b, p2pm, p2b,
                                          lin1_w, b1hi, b1lo, lin2_w, b2hi, b2lo);
    knn_kernel<<<dim3(NPT / KQ, BB, 2), 256, 0, stream>>>(pc1, pc2, idx12, idx21);

    auto chunk_rows = [&](int K) -> int {
        long rows = (long)(avail / ((size_t)K * sizeof(bf16)));
        int cm = (int)(rows > M2 ? M2 : rows) & ~127;
        if (cm < 128) cm = 128;
        return cm;
    };

    {   // cross 1 + cross 2 merged (K = 2048); BM=64 (already 2 blocks/CU)
        const int CMr = chunk_rows(K1);
        for (int m0 = 0; m0 < M2; m0 += CMr) {
            const int cm = (M2 - m0 < CMr) ? (M2 - m0) : CMr;
            agg_kernel<CDIM, 8><<<cm / 8, 256, 0, stream>>>(
                pc1, pc2, p2b, idx12,
                pc2, pc1, p1b, idx21, M,
                wn1_w0, wn1_b0, wn1_w1, wn1_b1, wn1_w2, wn1_b2,
                aggbuf, swbuf, m0);
            gemm_mfma<64><<<cm / 64, 256, 0, stream>>>(aggbuf, b1hi, b1lo, lin1_b,
                                                       p1pm, swbuf,
                                                       f1t, fpm, fb, m0, K1);
        }
    }
    {   // cross 3 (K = 4096); BM=32 -> 512 blocks = 2 blocks/CU
        const int CMr = chunk_rows(K2);
        for (int m0 = 0; m0 < M; m0 += CMr) {
            const int cm = (M - m0 < CMr) ? (M - m0) : CMr;
            agg_kernel<MIDD, 4><<<cm / 4, 256, 0, stream>>>(
                pc1, pc2, fb + (size_t)M * MIDD, idx12,
                nullptr, nullptr, nullptr, nullptr, M2,
                wn2_w0, wn2_b0, wn2_w1, wn2_b1, wn2_w2, wn2_b2,
                aggbuf, swbuf, m0);
            gemm_mfma<32><<<cm / 32, 256, 0, stream>>>(aggbuf, b2hi, b2lo, lin2_b,
                                                       fpm, swbuf,
                                                       fft, nullptr, nullptr, m0, K2);
        }
    }
}

// Round 17
// 328.843 us; speedup vs baseline: 1.3966x; 1.1038x over previous
//
#include <hip/hip_runtime.h>
#include <hip/hip_bf16.h>
#include <cstddef>
#include <cstdint>

typedef __hip_bfloat16 bf16;
typedef __attribute__((ext_vector_type(8))) short bf16x8;   // 8 bf16 = 4 VGPRs
typedef __attribute__((ext_vector_type(4))) float f32x4;

#define NPT 4096   // points per cloud
#define BB  4      // batch
#define NBR 16     // neighbors (nsample)
#define WD  16     // weightnet output width
#define CDIM 64    // input feature channels
#define MIDD 128   // lin1/lin2 output channels

// async global->LDS, 16B per lane; LDS dest is wave-uniform base + lane*16
#define GLD16(g, l) __builtin_amdgcn_global_load_lds( \
    (const __attribute__((address_space(1))) unsigned int*)(const void*)(g), \
    (__attribute__((address_space(3))) unsigned int*)(void*)(l), 16, 0, 0)

// ---------------------------------------------------------------------------
// Fused prep: feature transposes (fp32+bf16) + lin-weight hi/lo splits.
// ---------------------------------------------------------------------------
__global__ __launch_bounds__(256)
void prep_kernel(const float* __restrict__ feat1, const float* __restrict__ feat2,
                 float* __restrict__ p1pm, bf16* __restrict__ p1b,
                 float* __restrict__ p2pm, bf16* __restrict__ p2b,
                 const float* __restrict__ lin1_w, bf16* __restrict__ b1hi, bf16* __restrict__ b1lo,
                 const float* __restrict__ lin2_w, bf16* __restrict__ b2hi, bf16* __restrict__ b2lo)
{
    __shared__ float t[32][33];
    const int tx = threadIdx.x & 31, ty = threadIdx.x >> 5;
    const int id = blockIdx.x;
    if (id < 2048) {
        const int which = id >> 10;
        const int nt = id & 1023;
        const int n0 = (nt & 127) * 32;
        const int c0 = ((nt >> 7) & 1) * 32;
        const int b  = nt >> 8;
        const float* in = which ? feat2 : feat1;
        float* out  = which ? p2pm : p1pm;
        bf16*  outb = which ? p2b  : p1b;
        #pragma unroll
        for (int r = ty; r < 32; r += 8)
            t[r][tx] = in[((size_t)b * CDIM + c0 + r) * NPT + n0 + tx];
        __syncthreads();
        #pragma unroll
        for (int r = ty; r < 32; r += 8) {
            const float v = t[tx][r];
            out [((size_t)b * NPT + n0 + r) * CDIM + c0 + tx] = v;
            outb[((size_t)b * NPT + n0 + r) * CDIM + c0 + tx] = __float2bfloat16(v);
        }
    } else {
        const float* w; bf16 *hi, *lo; int K, k0, o0;
        if (id < 2304) {
            const int id2 = id - 2048;
            w = lin1_w; hi = b1hi; lo = b1lo; K = 2048;
            k0 = (id2 & 63) * 32; o0 = (id2 >> 6) * 32;
        } else {
            const int id2 = id - 2304;
            w = lin2_w; hi = b2hi; lo = b2lo; K = 4096;
            k0 = (id2 & 127) * 32; o0 = (id2 >> 7) * 32;
        }
        #pragma unroll
        for (int r = ty; r < 32; r += 8)
            t[r][tx] = w[(size_t)(k0 + r) * MIDD + o0 + tx];
        __syncthreads();
        #pragma unroll
        for (int r = ty; r < 32; r += 8) {
            const float v = t[tx][r];
            const bf16 h = __float2bfloat16(v);
            const bf16 l2 = __float2bfloat16(v - __bfloat162float(h));
            hi[(size_t)(o0 + r) * K + k0 + tx] = h;
            lo[(size_t)(o0 + r) * K + k0 + tx] = l2;
        }
    }
}

// ---------------------------------------------------------------------------
// KNN v5b (round-14, unchanged).
// ---------------------------------------------------------------------------
#define KQ     16
#define KSEG   16
#define KCH    64
#define KSTAGE 1024
#define KRING  96

__global__ __launch_bounds__(256)
void knn_kernel(const float* __restrict__ pcA, const float* __restrict__ pcB,
                int* __restrict__ idxAB, int* __restrict__ idxBA)
{
    const float *qxyz, *cxyz; int* idx_out;
    if (blockIdx.z == 0) { qxyz = pcA; cxyz = pcB; idx_out = idxAB; }
    else                 { qxyz = pcB; cxyz = pcA; idx_out = idxBA; }

    __shared__ float4 cf[KSTAGE + KSTAGE / KCH];   // skewed
    __shared__ float  pubd[2][KSEG][KQ];
    __shared__ float4 qc[KQ];
    __shared__ float  u16s[KQ];
    __shared__ int    rcnt[KQ];
    __shared__ int    wtot;
    __shared__ int    wl[256];
    __shared__ float  ringd[KQ][KRING + 1];
    __shared__ int    ringi[KQ][KRING + 1];

    const int tid = threadIdx.x;
    const int q   = tid & (KQ - 1);
    const int s   = tid >> 4;
    const int b   = blockIdx.y;
    const int n   = blockIdx.x * KQ + q;

    const float* qp = qxyz + (size_t)b * 3 * NPT;
    const float qx = qp[n], qy = qp[NPT + n], qz = qp[2 * NPT + n];
    const float q2 = fmaf(qx, qx, fmaf(qy, qy, qz * qz));
    const float* c = cxyz + (size_t)b * 3 * NPT;

    if (tid < KQ) rcnt[tid] = 0;
    if (tid == 0) wtot = 0;
    if (s == 0) qc[q] = make_float4(qx, qy, qz, q2);

    float b0 = 3.4e38f, b1 = 3.4e38f;
    for (int st = 0; st < NPT; st += KSTAGE) {
        __syncthreads();
        {
            #pragma unroll
            for (int r = 0; r < KSTAGE / 256; ++r) {
                const int j = r * 256 + tid;
                const int g = st + j;
                const float x = c[g], y = c[NPT + g], z = c[2 * NPT + g];
                cf[j + (j >> 6)] = make_float4(x, y, z,
                    fmaf(x, x, fmaf(y, y, z * z)));
            }
        }
        __syncthreads();
        const int base = s * (KCH + 1);
        #pragma unroll 4
        for (int jj = 0; jj < KCH; ++jj) {
            const float4 pv = cf[base + jj];
            const float dot = fmaf(qx, pv.x, fmaf(qy, pv.y, qz * pv.z));
            const float d = q2 + pv.w - 2.f * dot;
            const float t = fmaxf(b0, d);
            b0 = fminf(b0, d);
            b1 = fminf(b1, t);
        }
    }
    pubd[0][s][q] = b0;
    pubd[1][s][q] = b1;
    __syncthreads();

    {
        float tv[32];
        #pragma unroll
        for (int j = 0; j < 32; ++j) tv[j] = pubd[j >> 4][j & 15][q];
        #pragma unroll
        for (int rep = 0; rep < 2; ++rep) {
            const int j = rep * 16 + s;
            const float vj = pubd[rep][s][q];
            int rank = 0;
            #pragma unroll
            for (int k = 0; k < 32; ++k)
                rank += (tv[k] < vj || (tv[k] == vj && k < j)) ? 1 : 0;
            if (rank == 15) u16s[q] = vj;
        }
    }
    __syncthreads();

    if (b0 <= u16s[q]) {
        const int u = atomicAdd(&wtot, 1);
        wl[u] = (q << 4) | s;
    }
    __syncthreads();

    {
        const int W = wtot;
        const int lu = tid & 15;
        for (int u = tid >> 4; u < W; u += 16) {
            const int qq  = wl[u] >> 4;
            const int seg = wl[u] & 15;
            const float4 qv = qc[qq];
            const float gate = u16s[qq];
            #pragma unroll
            for (int ch = 0; ch < 4; ++ch) {
                const int j = ch * KSTAGE + seg * KCH + lu * 4;
                const float4 xs = *(const float4*)(c + j);
                const float4 ys = *(const float4*)(c + NPT + j);
                const float4 zs = *(const float4*)(c + 2 * NPT + j);
                const float xv[4] = { xs.x, xs.y, xs.z, xs.w };
                const float yv[4] = { ys.x, ys.y, ys.z, ys.w };
                const float zv[4] = { zs.x, zs.y, zs.z, zs.w };
                #pragma unroll
                for (int e = 0; e < 4; ++e) {
                    const float p2 = fmaf(xv[e], xv[e], fmaf(yv[e], yv[e], zv[e] * zv[e]));
                    const float dot = fmaf(qv.x, xv[e], fmaf(qv.y, yv[e], qv.z * zv[e]));
                    const float d = qv.w + p2 - 2.f * dot;
                    if (d <= gate) {
                        const int slot = atomicAdd(&rcnt[qq], 1);
                        if (slot < KRING) { ringd[qq][slot] = d; ringi[qq][slot] = j + e; }
                    }
                }
            }
        }
    }
    __syncthreads();

    {
        const int cnt = min(rcnt[q], KRING);
        int* op = idx_out + ((size_t)b * NPT + n) * NBR;
        for (int e = s; e < cnt; e += KSEG) {
            const float de = ringd[q][e];
            const int   ie = ringi[q][e];
            int rank = 0;
            for (int k = 0; k < cnt; ++k) {
                const float dk = ringd[q][k];
                const int   ik = ringi[q][k];
                rank += (dk < de || (dk == de && ik < ie)) ? 1 : 0;
            }
            if (rank < NBR) op[rank] = ie;
        }
    }
}

// ---------------------------------------------------------------------------
// Weightnet + aggregation v7: ALL TPP threads participate in the gather
// phase, each covering ND = 2 channels (was: half the threads x 4 channels,
// other half idle after the own-output removal). Per-thread state shrinks
// (F as uint, acc[2][16]); per-(p,d,w) FMA chain and rounding unchanged ->
// bit-identical output. Weightnet/sw phases unchanged.
// ---------------------------------------------------------------------------
template<int D2, int PTS>
__global__ __launch_bounds__(256)
void agg_kernel(const float* __restrict__ qA, const float* __restrict__ cA,
                const bf16* __restrict__ nbrA, const int* __restrict__ idxA,
                const float* __restrict__ qB, const float* __restrict__ cB,
                const bf16* __restrict__ nbrB, const int* __restrict__ idxB,
                int Msplit,
                const float* __restrict__ w0, const float* __restrict__ b0,
                const float* __restrict__ w1, const float* __restrict__ b1,
                const float* __restrict__ w2, const float* __restrict__ b2,
                bf16* __restrict__ agg, float* __restrict__ swb, int m0)
{
    constexpr int TPP  = 256 / PTS;     // 32 (D2=64) or 64 (D2=128)
    constexpr int ND   = D2 / TPP;      // 2
    constexpr int WSTR = 276;

    __shared__ float wp[248];
    __shared__ int   nb[PTS * NBR];
    __shared__ float wgt[PTS * WSTR];

    const int tid = threadIdx.x;
    const int mbase = m0 + (int)blockIdx.x * PTS;
    const bool second = mbase >= Msplit;
    const int mrow = second ? mbase - Msplit : mbase;
    const float* qxyz   = second ? qB   : qA;
    const float* cxyz   = second ? cB   : cA;
    const bf16*  nbr_b  = second ? nbrB : nbrA;
    const int*   idx    = second ? idxB : idxA;
    const int b = mrow >> 12;
    const int nbase = mrow & (NPT - 1);

    if (tid < 248) {
        float v;
        if      (tid <  24) v = w0[tid];
        else if (tid <  32) v = b0[tid - 24];
        else if (tid <  96) v = w1[tid - 32];
        else if (tid < 104) v = b1[tid - 96];
        else if (tid < 232) v = w2[tid - 104];
        else                v = b2[tid - 232];
        wp[tid] = v;
    }
    if (tid < PTS * NBR)
        nb[tid] = idx[(size_t)mrow * NBR + tid];
    __syncthreads();

    const int p  = tid & (PTS - 1);
    const int dg = tid / PTS;
    const int d0 = dg * ND;

    // ---- prefetch gathers (all threads); latency hides under weightnet ----
    unsigned int F[NBR];
    {
        const bf16* base = nbr_b + (size_t)b * NPT * D2 + d0;
        #pragma unroll
        for (int k = 0; k < NBR; ++k) {
            const int j = nb[p * NBR + k];
            F[k] = *(const unsigned int*)(base + (size_t)j * D2);
        }
    }

    if (tid < PTS * NBR) {
        const int pp = tid / NBR, k = tid % NBR;
        const int n = nbase + pp;
        const int j = nb[tid];
        const float* q = qxyz + (size_t)b * 3 * NPT;
        const float* c = cxyz + (size_t)b * 3 * NPT;
        const float dx = c[j]           - q[n];
        const float dy = c[NPT + j]     - q[NPT + n];
        const float dz = c[2 * NPT + j] - q[2 * NPT + n];
        float h1[8], h2[8];
        #pragma unroll
        for (int o = 0; o < 8; ++o) {
            float v = wp[24 + o];
            v = fmaf(dx, wp[o], v);
            v = fmaf(dy, wp[8 + o], v);
            v = fmaf(dz, wp[16 + o], v);
            h1[o] = fmaxf(v, 0.f);
        }
        #pragma unroll
        for (int o = 0; o < 8; ++o) {
            float v = wp[96 + o];
            #pragma unroll
            for (int i = 0; i < 8; ++i) v = fmaf(h1[i], wp[32 + i * 8 + o], v);
            h2[o] = fmaxf(v, 0.f);
        }
        #pragma unroll
        for (int o = 0; o < WD; ++o) {
            float v = wp[232 + o];
            #pragma unroll
            for (int i = 0; i < 8; ++i) v = fmaf(h2[i], wp[104 + i * WD + o], v);
            wgt[pp * WSTR + k * WD + o] = fmaxf(v, 0.f);
        }
    }
    __syncthreads();

    // ---- sw[p][w] = sum_k wgt[p][k][w] (k ascending) ----
    if (tid < PTS * 16) {
        const int pp = tid >> 4, w = tid & 15;
        const float* wgp = wgt + pp * WSTR + w;
        float sv = 0.f;
        #pragma unroll
        for (int k = 0; k < NBR; ++k) sv += wgp[k * WD];
        swb[(size_t)((int)blockIdx.x * PTS + pp) * 16 + w] = sv;
    }

    // ---- gather half: all threads, acc[ND][16] over k ----
    {
        const float* wg = wgt + p * WSTR;
        bf16* aout = agg + ((size_t)((int)blockIdx.x * PTS + p)) * (2 * D2 * WD);
        float acc[ND][16];
        #pragma unroll
        for (int di = 0; di < ND; ++di)
            #pragma unroll
            for (int w = 0; w < 16; ++w) acc[di][w] = 0.f;
        #pragma unroll
        for (int k = 0; k < NBR; ++k) {
            union { unsigned int u; bf16 h[2]; } uf;
            uf.u = F[k];
            float Fv[ND];
            #pragma unroll
            for (int j = 0; j < ND; ++j) Fv[j] = __bfloat162float(uf.h[j]);
            const float4 v0 = *(const float4*)(wg + k * WD);
            const float4 v1 = *(const float4*)(wg + k * WD + 4);
            const float4 v2 = *(const float4*)(wg + k * WD + 8);
            const float4 v3 = *(const float4*)(wg + k * WD + 12);
            float w16[16];
            w16[0]  = v0.x; w16[1]  = v0.y; w16[2]  = v0.z; w16[3]  = v0.w;
            w16[4]  = v1.x; w16[5]  = v1.y; w16[6]  = v1.z; w16[7]  = v1.w;
            w16[8]  = v2.x; w16[9]  = v2.y; w16[10] = v2.z; w16[11] = v2.w;
            w16[12] = v3.x; w16[13] = v3.y; w16[14] = v3.z; w16[15] = v3.w;
            #pragma unroll
            for (int di = 0; di < ND; ++di)
                #pragma unroll
                for (int w = 0; w < 16; ++w)
                    acc[di][w] = fmaf(Fv[di], w16[w], acc[di][w]);
        }
        #pragma unroll
        for (int di = 0; di < ND; ++di) {
            union { bf16 h[16]; uint4 q[2]; } pk;
            #pragma unroll
            for (int w = 0; w < 16; ++w) pk.h[w] = __float2bfloat16(acc[di][w]);
            bf16* dst = aout + (D2 + d0 + di) * WD;
            *(uint4*)dst       = pk.q[0];
            *(uint4*)(dst + 8) = pk.q[1];
        }
    }
}

// ---------------------------------------------------------------------------
// MFMA GEMM v4 (round-16, unchanged): templated BM, own-half reconstruction.
// ---------------------------------------------------------------------------
template<int BM>
__global__ __launch_bounds__(256)
void gemm_mfma(const bf16* __restrict__ A, const bf16* __restrict__ Bhi,
               const bf16* __restrict__ Blo, const float* __restrict__ bias,
               const float* __restrict__ ownf, const float* __restrict__ swb,
               float* __restrict__ out_t, float* __restrict__ out_pm,
               bf16* __restrict__ out_pmb, int m0, int K)
{
    constexpr int AE   = BM * 32;
    constexpr int BUFE = AE + 8192;
    constexpr int MF   = BM / 32;
    __shared__ __align__(16) char smem[2 * BUFE * 2];
    bf16* lds = (bf16*)smem;

    const int tid  = threadIdx.x;
    const int w    = tid >> 6;
    const int lane = tid & 63;
    const int wr   = w >> 1, wc = w & 1;
    const int mb   = (int)blockIdx.x * BM;
    const int gK   = lane >> 4;
    const int rL   = lane & 15;
    const int D2v  = K / 32;

    const int row_r = tid >> 2;
    const int row_s = row_r < BM ? row_r : BM - 1;
    const int ch_s  = tid & 3;
    const int sch_s = ch_s ^ (row_s & 3);
    const int w0_s  = (sch_s & 1) * 8;
    float sww[8];
    {
        const float* sp = swb + (size_t)(mb + row_s) * 16 + w0_s;
        const float4 a = *(const float4*)sp;
        const float4 b2 = *(const float4*)(sp + 4);
        sww[0] = a.x;  sww[1] = a.y;  sww[2] = a.z;  sww[3] = a.w;
        sww[4] = b2.x; sww[5] = b2.y; sww[6] = b2.z; sww[7] = b2.w;
    }
    const float* ownrow_g = ownf + (size_t)(m0 + mb + row_s) * D2v;

    f32x4 acc[MF][4];
    #pragma unroll
    for (int i = 0; i < MF; ++i)
        #pragma unroll
        for (int j = 0; j < 4; ++j) acc[i][j] = (f32x4)0.f;

    const int nk = K / 32;
    const int nkOwn = nk / 2;

    auto stage = [&](int buf, int kt) {
        const int kb = kt * 32;
        const int bufo = buf * BUFE;
        if (kt < nkOwn) {
            if (tid < BM * 4) {
                const int d = kt * 2 + (sch_s >> 1);
                const float f = ownrow_g[d];
                union { bf16 h[8]; uint4 q; } pk;
                #pragma unroll
                for (int j = 0; j < 8; ++j) pk.h[j] = __float2bfloat16(f * sww[j]);
                *(uint4*)(lds + bufo + tid * 8) = pk.q;
            }
        } else {
            if (w * 64 < BM * 4)
                GLD16(A + (size_t)(mb + row_r) * K + kb + (sch_s << 3),
                      lds + bufo + ((w * 64) << 3));
        }
        #pragma unroll
        for (int i = 0; i < 2; ++i) {
            const int s2 = i * 256 + tid;
            const int row = s2 >> 2, ch = s2 & 3;
            const int sch = ch ^ (row & 3);
            const int wb = (i * 256 + w * 64) << 3;
            GLD16(Bhi + (size_t)row * K + kb + (sch << 3), lds + bufo + AE + wb);
            GLD16(Blo + (size_t)row * K + kb + (sch << 3), lds + bufo + AE + 4096 + wb);
        }
    };

    stage(0, 0);
    __syncthreads();

    for (int kt = 0; kt < nk; ++kt) {
        const int cur = kt & 1;
        if (kt + 1 < nk) stage(cur ^ 1, kt + 1);

        const bf16* la  = lds + cur * BUFE;
        const bf16* lbh = la + AE;
        const bf16* lbl = la + AE + 4096;

        bf16x8 af[MF], bh[4], bl[4];
        #pragma unroll
        for (int mf = 0; mf < MF; ++mf) {
            const int row = wr * (BM / 2) + mf * 16 + rL;
            af[mf] = *(const bf16x8*)(la + row * 32 + ((gK ^ (row & 3)) << 3));
        }
        #pragma unroll
        for (int nf = 0; nf < 4; ++nf) {
            const int col = wc * 64 + nf * 16 + rL;
            const int off = col * 32 + ((gK ^ (col & 3)) << 3);
            bh[nf] = *(const bf16x8*)(lbh + off);
            bl[nf] = *(const bf16x8*)(lbl + off);
        }
        #pragma unroll
        for (int mf = 0; mf < MF; ++mf)
            #pragma unroll
            for (int nf = 0; nf < 4; ++nf) {
                acc[mf][nf] = __builtin_amdgcn_mfma_f32_16x16x32_bf16(af[mf], bh[nf], acc[mf][nf], 0, 0, 0);
                acc[mf][nf] = __builtin_amdgcn_mfma_f32_16x16x32_bf16(af[mf], bl[nf], acc[mf][nf], 0, 0, 0);
            }
        __syncthreads();
    }

    float (*tile)[133] = (float(*)[133])smem;
    #pragma unroll
    for (int mf = 0; mf < MF; ++mf)
        #pragma unroll
        for (int nf = 0; nf < 4; ++nf) {
            const int col = wc * 64 + nf * 16 + rL;
            const float bs = bias[col];
            #pragma unroll
            for (int qq = 0; qq < 4; ++qq) {
                const int rrow = wr * (BM / 2) + mf * 16 + gK * 4 + qq;
                const float v = acc[mf][nf][qq] + bs;
                tile[rrow][col] = v > 0.f ? v : 0.1f * v;
            }
        }
    __syncthreads();

    const int mrow = m0 + mb;
    const int b = mrow >> 12, n0 = mrow & (NPT - 1);
    for (int e = tid; e < BM * MIDD; e += 256) {
        const int o = e / BM, i = e % BM;
        out_t[((size_t)b * MIDD + o) * NPT + n0 + i] = tile[i][o];
    }
    if (out_pm) {
        for (int e = tid; e < BM * MIDD; e += 256) {
            const int i = e >> 7, o = e & 127;
            const float v = tile[i][o];
            out_pm [(size_t)(mrow + i) * MIDD + o] = v;
            out_pmb[(size_t)(mrow + i) * MIDD + o] = __float2bfloat16(v);
        }
    }
}

// ---------------------------------------------------------------------------
extern "C" void kernel_launch(void* const* d_in, const int* in_sizes, int n_in,
                              void* d_out, int out_size, void* d_ws, size_t ws_size,
                              hipStream_t stream)
{
    (void)in_sizes; (void)n_in; (void)out_size;
    const float* pc1    = (const float*)d_in[0];
    const float* pc2    = (const float*)d_in[1];
    const float* feat1  = (const float*)d_in[2];
    const float* feat2  = (const float*)d_in[3];
    const float* wn1_w0 = (const float*)d_in[4];
    const float* wn1_b0 = (const float*)d_in[5];
    const float* wn1_w1 = (const float*)d_in[6];
    const float* wn1_b1 = (const float*)d_in[7];
    const float* wn1_w2 = (const float*)d_in[8];
    const float* wn1_b2 = (const float*)d_in[9];
    const float* lin1_w = (const float*)d_in[10];
    const float* lin1_b = (const float*)d_in[11];
    const float* wn2_w0 = (const float*)d_in[12];
    const float* wn2_b0 = (const float*)d_in[13];
    const float* wn2_w1 = (const float*)d_in[14];
    const float* wn2_b1 = (const float*)d_in[15];
    const float* wn2_w2 = (const float*)d_in[16];
    const float* wn2_b2 = (const float*)d_in[17];
    const float* lin2_w = (const float*)d_in[18];
    const float* lin2_b = (const float*)d_in[19];
    float* out = (float*)d_out;

    const int M  = BB * NPT;
    const int M2 = 2 * M;
    const int K1 = 2 * CDIM * WD;     // 2048
    const int K2 = 2 * MIDD * WD;     // 4096

    char* ws = (char*)d_ws;
    float* p1pm = (float*)ws;
    float* p2pm = p1pm + (size_t)M * CDIM;
    float* fpm  = p2pm + (size_t)M * CDIM;
    bf16*  p1b  = (bf16*)(fpm + (size_t)M2 * MIDD);
    bf16*  p2b  = p1b + (size_t)M * CDIM;
    bf16*  fb   = p2b + (size_t)M * CDIM;
    int* idx12  = (int*)(fb + (size_t)M2 * MIDD);
    int* idx21  = idx12 + (size_t)M * NBR;
    bf16* b1hi  = (bf16*)(idx21 + (size_t)M * NBR);
    bf16* b1lo  = b1hi + (size_t)MIDD * K1;
    bf16* b2hi  = b1lo + (size_t)MIDD * K1;
    bf16* b2lo  = b2hi + (size_t)MIDD * K2;
    float* swbuf = (float*)(b2lo + (size_t)MIDD * K2);
    bf16* aggbuf = (bf16*)(swbuf + (size_t)(M2 + 64) * 16);
    const size_t used = (size_t)((char*)aggbuf - ws);
    const size_t avail = ws_size > used ? ws_size - used : 0;

    float* f1t = out;
    float* fft = out + 2 * (size_t)BB * MIDD * NPT;

    prep_kernel<<<2816, 256, 0, stream>>>(feat1, feat2, p1pm, p1b, p2pm, p2b,
                                          lin1_w, b1hi, b1lo, lin2_w, b2hi, b2lo);
    knn_kernel<<<dim3(NPT / KQ, BB, 2), 256, 0, stream>>>(pc1, pc2, idx12, idx21);

    auto chunk_rows = [&](int K) -> int {
        long rows = (long)(avail / ((size_t)K * sizeof(bf16)));
        int cm = (int)(rows > M2 ? M2 : rows) & ~127;
        if (cm < 128) cm = 128;
        return cm;
    };

    {   // cross 1 + cross 2 merged (K = 2048); BM=64
        const int CMr = chunk_rows(K1);
        for (int m0 = 0; m0 < M2; m0 += CMr) {
            const int cm = (M2 - m0 < CMr) ? (M2 - m0) : CMr;
            agg_kernel<CDIM, 8><<<cm / 8, 256, 0, stream>>>(
                pc1, pc2, p2b, idx12,
                pc2, pc1, p1b, idx21, M,
                wn1_w0, wn1_b0, wn1_w1, wn1_b1, wn1_w2, wn1_b2,
                aggbuf, swbuf, m0);
            gemm_mfma<64><<<cm / 64, 256, 0, stream>>>(aggbuf, b1hi, b1lo, lin1_b,
                                                       p1pm, swbuf,
                                                       f1t, fpm, fb, m0, K1);
        }
    }
    {   // cross 3 (K = 4096); BM=32
        const int CMr = chunk_rows(K2);
        for (int m0 = 0; m0 < M; m0 += CMr) {
            const int cm = (M - m0 < CMr) ? (M - m0) : CMr;
            agg_kernel<MIDD, 4><<<cm / 4, 256, 0, stream>>>(
                pc1, pc2, fb + (size_t)M * MIDD, idx12,
                nullptr, nullptr, nullptr, nullptr, M2,
                wn2_w0, wn2_b0, wn2_w1, wn2_b1, wn2_w2, wn2_b2,
                aggbuf, swbuf, m0);
            gemm_mfma<32><<<cm / 32, 256, 0, stream>>>(aggbuf, b2hi, b2lo, lin2_b,
                                                       fpm, swbuf,
                                                       fft, nullptr, nullptr, m0, K2);
        }
    }
}

// Round 18
// 326.387 us; speedup vs baseline: 1.4071x; 1.0075x over previous
//
#include <hip/hip_runtime.h>
#include <hip/hip_bf16.h>
#include <cstddef>
#include <cstdint>

typedef __hip_bfloat16 bf16;
typedef __attribute__((ext_vector_type(8))) short bf16x8;   // 8 bf16 = 4 VGPRs
typedef __attribute__((ext_vector_type(4))) float f32x4;

#define NPT 4096   // points per cloud
#define BB  4      // batch
#define NBR 16     // neighbors (nsample)
#define WD  16     // weightnet output width
#define CDIM 64    // input feature channels
#define MIDD 128   // lin1/lin2 output channels

// async global->LDS, 16B per lane; LDS dest is wave-uniform base + lane*16
#define GLD16(g, l) __builtin_amdgcn_global_load_lds( \
    (const __attribute__((address_space(1))) unsigned int*)(const void*)(g), \
    (__attribute__((address_space(3))) unsigned int*)(void*)(l), 16, 0, 0)

// ---------------------------------------------------------------------------
// Fused prep: feature transposes (fp32+bf16) + lin-weight hi/lo splits.
// ---------------------------------------------------------------------------
__global__ __launch_bounds__(256)
void prep_kernel(const float* __restrict__ feat1, const float* __restrict__ feat2,
                 float* __restrict__ p1pm, bf16* __restrict__ p1b,
                 float* __restrict__ p2pm, bf16* __restrict__ p2b,
                 const float* __restrict__ lin1_w, bf16* __restrict__ b1hi, bf16* __restrict__ b1lo,
                 const float* __restrict__ lin2_w, bf16* __restrict__ b2hi, bf16* __restrict__ b2lo)
{
    __shared__ float t[32][33];
    const int tx = threadIdx.x & 31, ty = threadIdx.x >> 5;
    const int id = blockIdx.x;
    if (id < 2048) {
        const int which = id >> 10;
        const int nt = id & 1023;
        const int n0 = (nt & 127) * 32;
        const int c0 = ((nt >> 7) & 1) * 32;
        const int b  = nt >> 8;
        const float* in = which ? feat2 : feat1;
        float* out  = which ? p2pm : p1pm;
        bf16*  outb = which ? p2b  : p1b;
        #pragma unroll
        for (int r = ty; r < 32; r += 8)
            t[r][tx] = in[((size_t)b * CDIM + c0 + r) * NPT + n0 + tx];
        __syncthreads();
        #pragma unroll
        for (int r = ty; r < 32; r += 8) {
            const float v = t[tx][r];
            out [((size_t)b * NPT + n0 + r) * CDIM + c0 + tx] = v;
            outb[((size_t)b * NPT + n0 + r) * CDIM + c0 + tx] = __float2bfloat16(v);
        }
    } else {
        const float* w; bf16 *hi, *lo; int K, k0, o0;
        if (id < 2304) {
            const int id2 = id - 2048;
            w = lin1_w; hi = b1hi; lo = b1lo; K = 2048;
            k0 = (id2 & 63) * 32; o0 = (id2 >> 6) * 32;
        } else {
            const int id2 = id - 2304;
            w = lin2_w; hi = b2hi; lo = b2lo; K = 4096;
            k0 = (id2 & 127) * 32; o0 = (id2 >> 7) * 32;
        }
        #pragma unroll
        for (int r = ty; r < 32; r += 8)
            t[r][tx] = w[(size_t)(k0 + r) * MIDD + o0 + tx];
        __syncthreads();
        #pragma unroll
        for (int r = ty; r < 32; r += 8) {
            const float v = t[tx][r];
            const bf16 h = __float2bfloat16(v);
            const bf16 l2 = __float2bfloat16(v - __bfloat162float(h));
            hi[(size_t)(o0 + r) * K + k0 + tx] = h;
            lo[(size_t)(o0 + r) * K + k0 + tx] = l2;
        }
    }
}

// ---------------------------------------------------------------------------
// KNN v5b (round-14, unchanged).
// ---------------------------------------------------------------------------
#define KQ     16
#define KSEG   16
#define KCH    64
#define KSTAGE 1024
#define KRING  96

__global__ __launch_bounds__(256)
void knn_kernel(const float* __restrict__ pcA, const float* __restrict__ pcB,
                int* __restrict__ idxAB, int* __restrict__ idxBA)
{
    const float *qxyz, *cxyz; int* idx_out;
    if (blockIdx.z == 0) { qxyz = pcA; cxyz = pcB; idx_out = idxAB; }
    else                 { qxyz = pcB; cxyz = pcA; idx_out = idxBA; }

    __shared__ float4 cf[KSTAGE + KSTAGE / KCH];   // skewed
    __shared__ float  pubd[2][KSEG][KQ];
    __shared__ float4 qc[KQ];
    __shared__ float  u16s[KQ];
    __shared__ int    rcnt[KQ];
    __shared__ int    wtot;
    __shared__ int    wl[256];
    __shared__ float  ringd[KQ][KRING + 1];
    __shared__ int    ringi[KQ][KRING + 1];

    const int tid = threadIdx.x;
    const int q   = tid & (KQ - 1);
    const int s   = tid >> 4;
    const int b   = blockIdx.y;
    const int n   = blockIdx.x * KQ + q;

    const float* qp = qxyz + (size_t)b * 3 * NPT;
    const float qx = qp[n], qy = qp[NPT + n], qz = qp[2 * NPT + n];
    const float q2 = fmaf(qx, qx, fmaf(qy, qy, qz * qz));
    const float* c = cxyz + (size_t)b * 3 * NPT;

    if (tid < KQ) rcnt[tid] = 0;
    if (tid == 0) wtot = 0;
    if (s == 0) qc[q] = make_float4(qx, qy, qz, q2);

    float b0 = 3.4e38f, b1 = 3.4e38f;
    for (int st = 0; st < NPT; st += KSTAGE) {
        __syncthreads();
        {
            #pragma unroll
            for (int r = 0; r < KSTAGE / 256; ++r) {
                const int j = r * 256 + tid;
                const int g = st + j;
                const float x = c[g], y = c[NPT + g], z = c[2 * NPT + g];
                cf[j + (j >> 6)] = make_float4(x, y, z,
                    fmaf(x, x, fmaf(y, y, z * z)));
            }
        }
        __syncthreads();
        const int base = s * (KCH + 1);
        #pragma unroll 4
        for (int jj = 0; jj < KCH; ++jj) {
            const float4 pv = cf[base + jj];
            const float dot = fmaf(qx, pv.x, fmaf(qy, pv.y, qz * pv.z));
            const float d = q2 + pv.w - 2.f * dot;
            const float t = fmaxf(b0, d);
            b0 = fminf(b0, d);
            b1 = fminf(b1, t);
        }
    }
    pubd[0][s][q] = b0;
    pubd[1][s][q] = b1;
    __syncthreads();

    {
        float tv[32];
        #pragma unroll
        for (int j = 0; j < 32; ++j) tv[j] = pubd[j >> 4][j & 15][q];
        #pragma unroll
        for (int rep = 0; rep < 2; ++rep) {
            const int j = rep * 16 + s;
            const float vj = pubd[rep][s][q];
            int rank = 0;
            #pragma unroll
            for (int k = 0; k < 32; ++k)
                rank += (tv[k] < vj || (tv[k] == vj && k < j)) ? 1 : 0;
            if (rank == 15) u16s[q] = vj;
        }
    }
    __syncthreads();

    if (b0 <= u16s[q]) {
        const int u = atomicAdd(&wtot, 1);
        wl[u] = (q << 4) | s;
    }
    __syncthreads();

    {
        const int W = wtot;
        const int lu = tid & 15;
        for (int u = tid >> 4; u < W; u += 16) {
            const int qq  = wl[u] >> 4;
            const int seg = wl[u] & 15;
            const float4 qv = qc[qq];
            const float gate = u16s[qq];
            #pragma unroll
            for (int ch = 0; ch < 4; ++ch) {
                const int j = ch * KSTAGE + seg * KCH + lu * 4;
                const float4 xs = *(const float4*)(c + j);
                const float4 ys = *(const float4*)(c + NPT + j);
                const float4 zs = *(const float4*)(c + 2 * NPT + j);
                const float xv[4] = { xs.x, xs.y, xs.z, xs.w };
                const float yv[4] = { ys.x, ys.y, ys.z, ys.w };
                const float zv[4] = { zs.x, zs.y, zs.z, zs.w };
                #pragma unroll
                for (int e = 0; e < 4; ++e) {
                    const float p2 = fmaf(xv[e], xv[e], fmaf(yv[e], yv[e], zv[e] * zv[e]));
                    const float dot = fmaf(qv.x, xv[e], fmaf(qv.y, yv[e], qv.z * zv[e]));
                    const float d = qv.w + p2 - 2.f * dot;
                    if (d <= gate) {
                        const int slot = atomicAdd(&rcnt[qq], 1);
                        if (slot < KRING) { ringd[qq][slot] = d; ringi[qq][slot] = j + e; }
                    }
                }
            }
        }
    }
    __syncthreads();

    {
        const int cnt = min(rcnt[q], KRING);
        int* op = idx_out + ((size_t)b * NPT + n) * NBR;
        for (int e = s; e < cnt; e += KSEG) {
            const float de = ringd[q][e];
            const int   ie = ringi[q][e];
            int rank = 0;
            for (int k = 0; k < cnt; ++k) {
                const float dk = ringd[q][k];
                const int   ik = ringi[q][k];
                rank += (dk < de || (dk == de && ik < ie)) ? 1 : 0;
            }
            if (rank < NBR) op[rank] = ie;
        }
    }
}

// ---------------------------------------------------------------------------
// Weightnet + aggregation v7 (round-17, unchanged).
// ---------------------------------------------------------------------------
template<int D2, int PTS>
__global__ __launch_bounds__(256)
void agg_kernel(const float* __restrict__ qA, const float* __restrict__ cA,
                const bf16* __restrict__ nbrA, const int* __restrict__ idxA,
                const float* __restrict__ qB, const float* __restrict__ cB,
                const bf16* __restrict__ nbrB, const int* __restrict__ idxB,
                int Msplit,
                const float* __restrict__ w0, const float* __restrict__ b0,
                const float* __restrict__ w1, const float* __restrict__ b1,
                const float* __restrict__ w2, const float* __restrict__ b2,
                bf16* __restrict__ agg, float* __restrict__ swb, int m0)
{
    constexpr int TPP  = 256 / PTS;     // 32 (D2=64) or 64 (D2=128)
    constexpr int ND   = D2 / TPP;      // 2
    constexpr int WSTR = 276;

    __shared__ float wp[248];
    __shared__ int   nb[PTS * NBR];
    __shared__ float wgt[PTS * WSTR];

    const int tid = threadIdx.x;
    const int mbase = m0 + (int)blockIdx.x * PTS;
    const bool second = mbase >= Msplit;
    const int mrow = second ? mbase - Msplit : mbase;
    const float* qxyz   = second ? qB   : qA;
    const float* cxyz   = second ? cB   : cA;
    const bf16*  nbr_b  = second ? nbrB : nbrA;
    const int*   idx    = second ? idxB : idxA;
    const int b = mrow >> 12;
    const int nbase = mrow & (NPT - 1);

    if (tid < 248) {
        float v;
        if      (tid <  24) v = w0[tid];
        else if (tid <  32) v = b0[tid - 24];
        else if (tid <  96) v = w1[tid - 32];
        else if (tid < 104) v = b1[tid - 96];
        else if (tid < 232) v = w2[tid - 104];
        else                v = b2[tid - 232];
        wp[tid] = v;
    }
    if (tid < PTS * NBR)
        nb[tid] = idx[(size_t)mrow * NBR + tid];
    __syncthreads();

    const int p  = tid & (PTS - 1);
    const int dg = tid / PTS;
    const int d0 = dg * ND;

    unsigned int F[NBR];
    {
        const bf16* base = nbr_b + (size_t)b * NPT * D2 + d0;
        #pragma unroll
        for (int k = 0; k < NBR; ++k) {
            const int j = nb[p * NBR + k];
            F[k] = *(const unsigned int*)(base + (size_t)j * D2);
        }
    }

    if (tid < PTS * NBR) {
        const int pp = tid / NBR, k = tid % NBR;
        const int n = nbase + pp;
        const int j = nb[tid];
        const float* q = qxyz + (size_t)b * 3 * NPT;
        const float* c = cxyz + (size_t)b * 3 * NPT;
        const float dx = c[j]           - q[n];
        const float dy = c[NPT + j]     - q[NPT + n];
        const float dz = c[2 * NPT + j] - q[2 * NPT + n];
        float h1[8], h2[8];
        #pragma unroll
        for (int o = 0; o < 8; ++o) {
            float v = wp[24 + o];
            v = fmaf(dx, wp[o], v);
            v = fmaf(dy, wp[8 + o], v);
            v = fmaf(dz, wp[16 + o], v);
            h1[o] = fmaxf(v, 0.f);
        }
        #pragma unroll
        for (int o = 0; o < 8; ++o) {
            float v = wp[96 + o];
            #pragma unroll
            for (int i = 0; i < 8; ++i) v = fmaf(h1[i], wp[32 + i * 8 + o], v);
            h2[o] = fmaxf(v, 0.f);
        }
        #pragma unroll
        for (int o = 0; o < WD; ++o) {
            float v = wp[232 + o];
            #pragma unroll
            for (int i = 0; i < 8; ++i) v = fmaf(h2[i], wp[104 + i * WD + o], v);
            wgt[pp * WSTR + k * WD + o] = fmaxf(v, 0.f);
        }
    }
    __syncthreads();

    if (tid < PTS * 16) {
        const int pp = tid >> 4, w = tid & 15;
        const float* wgp = wgt + pp * WSTR + w;
        float sv = 0.f;
        #pragma unroll
        for (int k = 0; k < NBR; ++k) sv += wgp[k * WD];
        swb[(size_t)((int)blockIdx.x * PTS + pp) * 16 + w] = sv;
    }

    {
        const float* wg = wgt + p * WSTR;
        bf16* aout = agg + ((size_t)((int)blockIdx.x * PTS + p)) * (2 * D2 * WD);
        float acc[ND][16];
        #pragma unroll
        for (int di = 0; di < ND; ++di)
            #pragma unroll
            for (int w = 0; w < 16; ++w) acc[di][w] = 0.f;
        #pragma unroll
        for (int k = 0; k < NBR; ++k) {
            union { unsigned int u; bf16 h[2]; } uf;
            uf.u = F[k];
            float Fv[ND];
            #pragma unroll
            for (int j = 0; j < ND; ++j) Fv[j] = __bfloat162float(uf.h[j]);
            const float4 v0 = *(const float4*)(wg + k * WD);
            const float4 v1 = *(const float4*)(wg + k * WD + 4);
            const float4 v2 = *(const float4*)(wg + k * WD + 8);
            const float4 v3 = *(const float4*)(wg + k * WD + 12);
            float w16[16];
            w16[0]  = v0.x; w16[1]  = v0.y; w16[2]  = v0.z; w16[3]  = v0.w;
            w16[4]  = v1.x; w16[5]  = v1.y; w16[6]  = v1.z; w16[7]  = v1.w;
            w16[8]  = v2.x; w16[9]  = v2.y; w16[10] = v2.z; w16[11] = v2.w;
            w16[12] = v3.x; w16[13] = v3.y; w16[14] = v3.z; w16[15] = v3.w;
            #pragma unroll
            for (int di = 0; di < ND; ++di)
                #pragma unroll
                for (int w = 0; w < 16; ++w)
                    acc[di][w] = fmaf(Fv[di], w16[w], acc[di][w]);
        }
        #pragma unroll
        for (int di = 0; di < ND; ++di) {
            union { bf16 h[16]; uint4 q[2]; } pk;
            #pragma unroll
            for (int w = 0; w < 16; ++w) pk.h[w] = __float2bfloat16(acc[di][w]);
            bf16* dst = aout + (D2 + d0 + di) * WD;
            *(uint4*)dst       = pk.q[0];
            *(uint4*)(dst + 8) = pk.q[1];
        }
    }
}

// ---------------------------------------------------------------------------
// MFMA GEMM v5: chunk swizzle changed from f(row)=row&3 to f(row)=(row>>1)&3.
// Bank-quad of a fragment slot = (4*row + chunk) & 7; with the new f the
// 16 consecutive rows of a lane group map to all 8 quads twice (2-way = free)
// instead of 4 quads (4-way). Pure slot permutation applied consistently to
// staging source and read side -> bit-identical output. Own-half formulas
// (d = kt*2 + sch>>1, w0 = (sch&1)*8) depend only on sch -> unchanged.
// ---------------------------------------------------------------------------
template<int BM>
__global__ __launch_bounds__(256)
void gemm_mfma(const bf16* __restrict__ A, const bf16* __restrict__ Bhi,
               const bf16* __restrict__ Blo, const float* __restrict__ bias,
               const float* __restrict__ ownf, const float* __restrict__ swb,
               float* __restrict__ out_t, float* __restrict__ out_pm,
               bf16* __restrict__ out_pmb, int m0, int K)
{
    constexpr int AE   = BM * 32;
    constexpr int BUFE = AE + 8192;
    constexpr int MF   = BM / 32;
    __shared__ __align__(16) char smem[2 * BUFE * 2];
    bf16* lds = (bf16*)smem;

    const int tid  = threadIdx.x;
    const int w    = tid >> 6;
    const int lane = tid & 63;
    const int wr   = w >> 1, wc = w & 1;
    const int mb   = (int)blockIdx.x * BM;
    const int gK   = lane >> 4;
    const int rL   = lane & 15;
    const int D2v  = K / 32;

    const int row_r = tid >> 2;
    const int row_s = row_r < BM ? row_r : BM - 1;
    const int ch_s  = tid & 3;
    const int sch_s = ch_s ^ ((row_s >> 1) & 3);
    const int w0_s  = (sch_s & 1) * 8;
    float sww[8];
    {
        const float* sp = swb + (size_t)(mb + row_s) * 16 + w0_s;
        const float4 a = *(const float4*)sp;
        const float4 b2 = *(const float4*)(sp + 4);
        sww[0] = a.x;  sww[1] = a.y;  sww[2] = a.z;  sww[3] = a.w;
        sww[4] = b2.x; sww[5] = b2.y; sww[6] = b2.z; sww[7] = b2.w;
    }
    const float* ownrow_g = ownf + (size_t)(m0 + mb + row_s) * D2v;

    f32x4 acc[MF][4];
    #pragma unroll
    for (int i = 0; i < MF; ++i)
        #pragma unroll
        for (int j = 0; j < 4; ++j) acc[i][j] = (f32x4)0.f;

    const int nk = K / 32;
    const int nkOwn = nk / 2;

    auto stage = [&](int buf, int kt) {
        const int kb = kt * 32;
        const int bufo = buf * BUFE;
        if (kt < nkOwn) {
            if (tid < BM * 4) {
                const int d = kt * 2 + (sch_s >> 1);
                const float f = ownrow_g[d];
                union { bf16 h[8]; uint4 q; } pk;
                #pragma unroll
                for (int j = 0; j < 8; ++j) pk.h[j] = __float2bfloat16(f * sww[j]);
                *(uint4*)(lds + bufo + tid * 8) = pk.q;
            }
        } else {
            if (w * 64 < BM * 4)
                GLD16(A + (size_t)(mb + row_r) * K + kb + (sch_s << 3),
                      lds + bufo + ((w * 64) << 3));
        }
        #pragma unroll
        for (int i = 0; i < 2; ++i) {
            const int s2 = i * 256 + tid;
            const int row = s2 >> 2, ch = s2 & 3;
            const int sch = ch ^ ((row >> 1) & 3);
            const int wb = (i * 256 + w * 64) << 3;
            GLD16(Bhi + (size_t)row * K + kb + (sch << 3), lds + bufo + AE + wb);
            GLD16(Blo + (size_t)row * K + kb + (sch << 3), lds + bufo + AE + 4096 + wb);
        }
    };

    stage(0, 0);
    __syncthreads();

    for (int kt = 0; kt < nk; ++kt) {
        const int cur = kt & 1;
        if (kt + 1 < nk) stage(cur ^ 1, kt + 1);

        const bf16* la  = lds + cur * BUFE;
        const bf16* lbh = la + AE;
        const bf16* lbl = la + AE + 4096;

        bf16x8 af[MF], bh[4], bl[4];
        #pragma unroll
        for (int mf = 0; mf < MF; ++mf) {
            const int row = wr * (BM / 2) + mf * 16 + rL;
            af[mf] = *(const bf16x8*)(la + row * 32 + ((gK ^ ((row >> 1) & 3)) << 3));
        }
        #pragma unroll
        for (int nf = 0; nf < 4; ++nf) {
            const int col = wc * 64 + nf * 16 + rL;
            const int off = col * 32 + ((gK ^ ((col >> 1) & 3)) << 3);
            bh[nf] = *(const bf16x8*)(lbh + off);
            bl[nf] = *(const bf16x8*)(lbl + off);
        }
        #pragma unroll
        for (int mf = 0; mf < MF; ++mf)
            #pragma unroll
            for (int nf = 0; nf < 4; ++nf) {
                acc[mf][nf] = __builtin_amdgcn_mfma_f32_16x16x32_bf16(af[mf], bh[nf], acc[mf][nf], 0, 0, 0);
                acc[mf][nf] = __builtin_amdgcn_mfma_f32_16x16x32_bf16(af[mf], bl[nf], acc[mf][nf], 0, 0, 0);
            }
        __syncthreads();
    }

    float (*tile)[133] = (float(*)[133])smem;
    #pragma unroll
    for (int mf = 0; mf < MF; ++mf)
        #pragma unroll
        for (int nf = 0; nf < 4; ++nf) {
            const int col = wc * 64 + nf * 16 + rL;
            const float bs = bias[col];
            #pragma unroll
            for (int qq = 0; qq < 4; ++qq) {
                const int rrow = wr * (BM / 2) + mf * 16 + gK * 4 + qq;
                const float v = acc[mf][nf][qq] + bs;
                tile[rrow][col] = v > 0.f ? v : 0.1f * v;
            }
        }
    __syncthreads();

    const int mrow = m0 + mb;
    const int b = mrow >> 12, n0 = mrow & (NPT - 1);
    for (int e = tid; e < BM * MIDD; e += 256) {
        const int o = e / BM, i = e % BM;
        out_t[((size_t)b * MIDD + o) * NPT + n0 + i] = tile[i][o];
    }
    if (out_pm) {
        for (int e = tid; e < BM * MIDD; e += 256) {
            const int i = e >> 7, o = e & 127;
            const float v = tile[i][o];
            out_pm [(size_t)(mrow + i) * MIDD + o] = v;
            out_pmb[(size_t)(mrow + i) * MIDD + o] = __float2bfloat16(v);
        }
    }
}

// ---------------------------------------------------------------------------
extern "C" void kernel_launch(void* const* d_in, const int* in_sizes, int n_in,
                              void* d_out, int out_size, void* d_ws, size_t ws_size,
                              hipStream_t stream)
{
    (void)in_sizes; (void)n_in; (void)out_size;
    const float* pc1    = (const float*)d_in[0];
    const float* pc2    = (const float*)d_in[1];
    const float* feat1  = (const float*)d_in[2];
    const float* feat2  = (const float*)d_in[3];
    const float* wn1_w0 = (const float*)d_in[4];
    const float* wn1_b0 = (const float*)d_in[5];
    const float* wn1_w1 = (const float*)d_in[6];
    const float* wn1_b1 = (const float*)d_in[7];
    const float* wn1_w2 = (const float*)d_in[8];
    const float* wn1_b2 = (const float*)d_in[9];
    const float* lin1_w = (const float*)d_in[10];
    const float* lin1_b = (const float*)d_in[11];
    const float* wn2_w0 = (const float*)d_in[12];
    const float* wn2_b0 = (const float*)d_in[13];
    const float* wn2_w1 = (const float*)d_in[14];
    const float* wn2_b1 = (const float*)d_in[15];
    const float* wn2_w2 = (const float*)d_in[16];
    const float* wn2_b2 = (const float*)d_in[17];
    const float* lin2_w = (const float*)d_in[18];
    const float* lin2_b = (const float*)d_in[19];
    float* out = (float*)d_out;

    const int M  = BB * NPT;
    const int M2 = 2 * M;
    const int K1 = 2 * CDIM * WD;     // 2048
    const int K2 = 2 * MIDD * WD;     // 4096

    char* ws = (char*)d_ws;
    float* p1pm = (float*)ws;
    float* p2pm = p1pm + (size_t)M * CDIM;
    float* fpm  = p2pm + (size_t)M * CDIM;
    bf16*  p1b  = (bf16*)(fpm + (size_t)M2 * MIDD);
    bf16*  p2b  = p1b + (size_t)M * CDIM;
    bf16*  fb   = p2b + (size_t)M * CDIM;
    int* idx12  = (int*)(fb + (size_t)M2 * MIDD);
    int* idx21  = idx12 + (size_t)M * NBR;
    bf16* b1hi  = (bf16*)(idx21 + (size_t)M * NBR);
    bf16* b1lo  = b1hi + (size_t)MIDD * K1;
    bf16* b2hi  = b1lo + (size_t)MIDD * K1;
    bf16* b2lo  = b2hi + (size_t)MIDD * K2;
    float* swbuf = (float*)(b2lo + (size_t)MIDD * K2);
    bf16* aggbuf = (bf16*)(swbuf + (size_t)(M2 + 64) * 16);
    const size_t used = (size_t)((char*)aggbuf - ws);
    const size_t avail = ws_size > used ? ws_size - used : 0;

    float* f1t = out;
    float* fft = out + 2 * (size_t)BB * MIDD * NPT;

    prep_kernel<<<2816, 256, 0, stream>>>(feat1, feat2, p1pm, p1b, p2pm, p2b,
                                          lin1_w, b1hi, b1lo, lin2_w, b2hi, b2lo);
    knn_kernel<<<dim3(NPT / KQ, BB, 2), 256, 0, stream>>>(pc1, pc2, idx12, idx21);

    auto chunk_rows = [&](int K) -> int {
        long rows = (long)(avail / ((size_t)K * sizeof(bf16)));
        int cm = (int)(rows > M2 ? M2 : rows) & ~127;
        if (cm < 128) cm = 128;
        return cm;
    };

    {   // cross 1 + cross 2 merged (K = 2048); BM=64
        const int CMr = chunk_rows(K1);
        for (int m0 = 0; m0 < M2; m0 += CMr) {
            const int cm = (M2 - m0 < CMr) ? (M2 - m0) : CMr;
            agg_kernel<CDIM, 8><<<cm / 8, 256, 0, stream>>>(
                pc1, pc2, p2b, idx12,
                pc2, pc1, p1b, idx21, M,
                wn1_w0, wn1_b0, wn1_w1, wn1_b1, wn1_w2, wn1_b2,
                aggbuf, swbuf, m0);
            gemm_mfma<64><<<cm / 64, 256, 0, stream>>>(aggbuf, b1hi, b1lo, lin1_b,
                                                       p1pm, swbuf,
                                                       f1t, fpm, fb, m0, K1);
        }
    }
    {   // cross 3 (K = 4096); BM=32
        const int CMr = chunk_rows(K2);
        for (int m0 = 0; m0 < M; m0 += CMr) {
            const int cm = (M - m0 < CMr) ? (M - m0) : CMr;
            agg_kernel<MIDD, 4><<<cm / 4, 256, 0, stream>>>(
                pc1, pc2, fb + (size_t)M * MIDD, idx12,
                nullptr, nullptr, nullptr, nullptr, M2,
                wn2_w0, wn2_b0, wn2_w1, wn2_b1, wn2_w2, wn2_b2,
                aggbuf, swbuf, m0);
            gemm_mfma<32><<<cm / 32, 256, 0, stream>>>(aggbuf, b2hi, b2lo, lin2_b,
                                                       fpm, swbuf,
                                                       fft, nullptr, nullptr, m0, K2);
        }
    }
}

// Round 19
// 316.112 us; speedup vs baseline: 1.4528x; 1.0325x over previous
//
#include <hip/hip_runtime.h>
#include <hip/hip_bf16.h>
#include <cstddef>
#include <cstdint>

typedef __hip_bfloat16 bf16;
typedef __attribute__((ext_vector_type(8))) short bf16x8;   // 8 bf16 = 4 VGPRs
typedef __attribute__((ext_vector_type(4))) float f32x4;

#define NPT 4096   // points per cloud
#define BB  4      // batch
#define NBR 16     // neighbors (nsample)
#define WD  16     // weightnet output width
#define CDIM 64    // input feature channels
#define MIDD 128   // lin1/lin2 output channels

// async global->LDS, 16B per lane; LDS dest is wave-uniform base + lane*16
#define GLD16(g, l) __builtin_amdgcn_global_load_lds( \
    (const __attribute__((address_space(1))) unsigned int*)(const void*)(g), \
    (__attribute__((address_space(3))) unsigned int*)(void*)(l), 16, 0, 0)

// ---------------------------------------------------------------------------
// Fused prep: feature transposes (fp32+bf16) + lin-weight hi/lo splits.
// ---------------------------------------------------------------------------
__global__ __launch_bounds__(256)
void prep_kernel(const float* __restrict__ feat1, const float* __restrict__ feat2,
                 float* __restrict__ p1pm, bf16* __restrict__ p1b,
                 float* __restrict__ p2pm, bf16* __restrict__ p2b,
                 const float* __restrict__ lin1_w, bf16* __restrict__ b1hi, bf16* __restrict__ b1lo,
                 const float* __restrict__ lin2_w, bf16* __restrict__ b2hi, bf16* __restrict__ b2lo)
{
    __shared__ float t[32][33];
    const int tx = threadIdx.x & 31, ty = threadIdx.x >> 5;
    const int id = blockIdx.x;
    if (id < 2048) {
        const int which = id >> 10;
        const int nt = id & 1023;
        const int n0 = (nt & 127) * 32;
        const int c0 = ((nt >> 7) & 1) * 32;
        const int b  = nt >> 8;
        const float* in = which ? feat2 : feat1;
        float* out  = which ? p2pm : p1pm;
        bf16*  outb = which ? p2b  : p1b;
        #pragma unroll
        for (int r = ty; r < 32; r += 8)
            t[r][tx] = in[((size_t)b * CDIM + c0 + r) * NPT + n0 + tx];
        __syncthreads();
        #pragma unroll
        for (int r = ty; r < 32; r += 8) {
            const float v = t[tx][r];
            out [((size_t)b * NPT + n0 + r) * CDIM + c0 + tx] = v;
            outb[((size_t)b * NPT + n0 + r) * CDIM + c0 + tx] = __float2bfloat16(v);
        }
    } else {
        const float* w; bf16 *hi, *lo; int K, k0, o0;
        if (id < 2304) {
            const int id2 = id - 2048;
            w = lin1_w; hi = b1hi; lo = b1lo; K = 2048;
            k0 = (id2 & 63) * 32; o0 = (id2 >> 6) * 32;
        } else {
            const int id2 = id - 2304;
            w = lin2_w; hi = b2hi; lo = b2lo; K = 4096;
            k0 = (id2 & 127) * 32; o0 = (id2 >> 7) * 32;
        }
        #pragma unroll
        for (int r = ty; r < 32; r += 8)
            t[r][tx] = w[(size_t)(k0 + r) * MIDD + o0 + tx];
        __syncthreads();
        #pragma unroll
        for (int r = ty; r < 32; r += 8) {
            const float v = t[tx][r];
            const bf16 h = __float2bfloat16(v);
            const bf16 l2 = __float2bfloat16(v - __bfloat162float(h));
            hi[(size_t)(o0 + r) * K + k0 + tx] = h;
            lo[(size_t)(o0 + r) * K + k0 + tx] = l2;
        }
    }
}

// ---------------------------------------------------------------------------
// KNN v8: v5b + argmin tracking + selective rescan.
//  - pass 1 additionally tracks i0 = index of the FIRST candidate attaining
//    the segment minimum (strict '<' update keeps the earliest index — same
//    candidate a rescan would find). b0/b1 updates unchanged -> gate
//    bit-identical to v5b.
//  - classification: b0 > gate: skip. b0 <= gate < b1: the min is the ONLY
//    survivor in the segment (all others have d >= b1 > gate) -> append
//    (b0, i0) directly. b1 <= gate: rescan (worklist, ~5/16 segments).
//  - ring contents identical as a set; final exact (d, idx) rank-select is
//    order-independent -> output bit-identical.
// ---------------------------------------------------------------------------
#define KQ     16
#define KSEG   16
#define KCH    64
#define KSTAGE 1024
#define KRING  96

__global__ __launch_bounds__(256)
void knn_kernel(const float* __restrict__ pcA, const float* __restrict__ pcB,
                int* __restrict__ idxAB, int* __restrict__ idxBA)
{
    const float *qxyz, *cxyz; int* idx_out;
    if (blockIdx.z == 0) { qxyz = pcA; cxyz = pcB; idx_out = idxAB; }
    else                 { qxyz = pcB; cxyz = pcA; idx_out = idxBA; }

    __shared__ float4 cf[KSTAGE + KSTAGE / KCH];   // skewed
    __shared__ float  pubd[2][KSEG][KQ];
    __shared__ float4 qc[KQ];
    __shared__ float  u16s[KQ];
    __shared__ int    rcnt[KQ];
    __shared__ int    wtot;
    __shared__ int    wl[256];
    __shared__ float  ringd[KQ][KRING + 1];
    __shared__ int    ringi[KQ][KRING + 1];

    const int tid = threadIdx.x;
    const int q   = tid & (KQ - 1);
    const int s   = tid >> 4;
    const int b   = blockIdx.y;
    const int n   = blockIdx.x * KQ + q;

    const float* qp = qxyz + (size_t)b * 3 * NPT;
    const float qx = qp[n], qy = qp[NPT + n], qz = qp[2 * NPT + n];
    const float q2 = fmaf(qx, qx, fmaf(qy, qy, qz * qz));
    const float* c = cxyz + (size_t)b * 3 * NPT;

    if (tid < KQ) rcnt[tid] = 0;
    if (tid == 0) wtot = 0;
    if (s == 0) qc[q] = make_float4(qx, qy, qz, q2);

    // ---- pass 1: min value+index and 2nd-smallest value per (q,s) ----
    float b0 = 3.4e38f, b1 = 3.4e38f;
    int   i0 = 0;
    for (int st = 0; st < NPT; st += KSTAGE) {
        __syncthreads();
        {   // thread-strided staging: conflict-free lane-consecutive writes
            #pragma unroll
            for (int r = 0; r < KSTAGE / 256; ++r) {
                const int j = r * 256 + tid;
                const int g = st + j;
                const float x = c[g], y = c[NPT + g], z = c[2 * NPT + g];
                cf[j + (j >> 6)] = make_float4(x, y, z,
                    fmaf(x, x, fmaf(y, y, z * z)));
            }
        }
        __syncthreads();
        const int base = s * (KCH + 1);   // skewed segment base
        const int gidx = st + s * KCH;    // logical index of slot jj==0
        #pragma unroll 4
        for (int jj = 0; jj < KCH; ++jj) {
            const float4 pv = cf[base + jj];
            const float dot = fmaf(qx, pv.x, fmaf(qy, pv.y, qz * pv.z));
            const float d = q2 + pv.w - 2.f * dot;
            i0 = (d < b0) ? (gidx + jj) : i0;        // before b0 update
            const float t = fmaxf(b0, d);
            b0 = fminf(b0, d);
            b1 = fminf(b1, t);
        }
    }
    pubd[0][s][q] = b0;
    pubd[1][s][q] = b1;
    __syncthreads();

    // ---- u16: 16th smallest of 32 published values (rank == 15) ----
    {
        float tv[32];
        #pragma unroll
        for (int j = 0; j < 32; ++j) tv[j] = pubd[j >> 4][j & 15][q];
        #pragma unroll
        for (int rep = 0; rep < 2; ++rep) {
            const int j = rep * 16 + s;
            const float vj = pubd[rep][s][q];
            int rank = 0;
            #pragma unroll
            for (int k = 0; k < 32; ++k)
                rank += (tv[k] < vj || (tv[k] == vj && k < j)) ? 1 : 0;
            if (rank == 15) u16s[q] = vj;
        }
    }
    __syncthreads();

    // ---- classify: direct-append single-survivor segments; worklist rest ----
    {
        const float gate = u16s[q];
        if (b0 <= gate) {
            if (b1 > gate) {                 // unique survivor: the min
                const int slot = atomicAdd(&rcnt[q], 1);
                if (slot < KRING) { ringd[q][slot] = b0; ringi[q][slot] = i0; }
            } else {                         // >=2 possible survivors: rescan
                const int u = atomicAdd(&wtot, 1);
                wl[u] = (q << 4) | s;
            }
        }
    }
    __syncthreads();

    // ---- pass 2: cooperative rescan of multi-survivor segments only ----
    {
        const int W = wtot;
        const int lu = tid & 15;
        for (int u = tid >> 4; u < W; u += 16) {
            const int qq  = wl[u] >> 4;
            const int seg = wl[u] & 15;
            const float4 qv = qc[qq];
            const float gate = u16s[qq];
            #pragma unroll
            for (int ch = 0; ch < 4; ++ch) {
                const int j = ch * KSTAGE + seg * KCH + lu * 4;
                const float4 xs = *(const float4*)(c + j);
                const float4 ys = *(const float4*)(c + NPT + j);
                const float4 zs = *(const float4*)(c + 2 * NPT + j);
                const float xv[4] = { xs.x, xs.y, xs.z, xs.w };
                const float yv[4] = { ys.x, ys.y, ys.z, ys.w };
                const float zv[4] = { zs.x, zs.y, zs.z, zs.w };
                #pragma unroll
                for (int e = 0; e < 4; ++e) {
                    const float p2 = fmaf(xv[e], xv[e], fmaf(yv[e], yv[e], zv[e] * zv[e]));
                    const float dot = fmaf(qv.x, xv[e], fmaf(qv.y, yv[e], qv.z * zv[e]));
                    const float d = qv.w + p2 - 2.f * dot;
                    if (d <= gate) {
                        const int slot = atomicAdd(&rcnt[qq], 1);
                        if (slot < KRING) { ringd[qq][slot] = d; ringi[qq][slot] = j + e; }
                    }
                }
            }
        }
    }
    __syncthreads();

    // ---- final: exact (d, idx) rank-select of top-16 from the ring ----
    {
        const int cnt = min(rcnt[q], KRING);
        int* op = idx_out + ((size_t)b * NPT + n) * NBR;
        for (int e = s; e < cnt; e += KSEG) {
            const float de = ringd[q][e];
            const int   ie = ringi[q][e];
            int rank = 0;
            for (int k = 0; k < cnt; ++k) {
                const float dk = ringd[q][k];
                const int   ik = ringi[q][k];
                rank += (dk < de || (dk == de && ik < ie)) ? 1 : 0;
            }
            if (rank < NBR) op[rank] = ie;
        }
    }
}

// ---------------------------------------------------------------------------
// Weightnet + aggregation v7 (round-17, unchanged).
// ---------------------------------------------------------------------------
template<int D2, int PTS>
__global__ __launch_bounds__(256)
void agg_kernel(const float* __restrict__ qA, const float* __restrict__ cA,
                const bf16* __restrict__ nbrA, const int* __restrict__ idxA,
                const float* __restrict__ qB, const float* __restrict__ cB,
                const bf16* __restrict__ nbrB, const int* __restrict__ idxB,
                int Msplit,
                const float* __restrict__ w0, const float* __restrict__ b0,
                const float* __restrict__ w1, const float* __restrict__ b1,
                const float* __restrict__ w2, const float* __restrict__ b2,
                bf16* __restrict__ agg, float* __restrict__ swb, int m0)
{
    constexpr int TPP  = 256 / PTS;     // 32 (D2=64) or 64 (D2=128)
    constexpr int ND   = D2 / TPP;      // 2
    constexpr int WSTR = 276;

    __shared__ float wp[248];
    __shared__ int   nb[PTS * NBR];
    __shared__ float wgt[PTS * WSTR];

    const int tid = threadIdx.x;
    const int mbase = m0 + (int)blockIdx.x * PTS;
    const bool second = mbase >= Msplit;
    const int mrow = second ? mbase - Msplit : mbase;
    const float* qxyz   = second ? qB   : qA;
    const float* cxyz   = second ? cB   : cA;
    const bf16*  nbr_b  = second ? nbrB : nbrA;
    const int*   idx    = second ? idxB : idxA;
    const int b = mrow >> 12;
    const int nbase = mrow & (NPT - 1);

    if (tid < 248) {
        float v;
        if      (tid <  24) v = w0[tid];
        else if (tid <  32) v = b0[tid - 24];
        else if (tid <  96) v = w1[tid - 32];
        else if (tid < 104) v = b1[tid - 96];
        else if (tid < 232) v = w2[tid - 104];
        else                v = b2[tid - 232];
        wp[tid] = v;
    }
    if (tid < PTS * NBR)
        nb[tid] = idx[(size_t)mrow * NBR + tid];
    __syncthreads();

    const int p  = tid & (PTS - 1);
    const int dg = tid / PTS;
    const int d0 = dg * ND;

    unsigned int F[NBR];
    {
        const bf16* base = nbr_b + (size_t)b * NPT * D2 + d0;
        #pragma unroll
        for (int k = 0; k < NBR; ++k) {
            const int j = nb[p * NBR + k];
            F[k] = *(const unsigned int*)(base + (size_t)j * D2);
        }
    }

    if (tid < PTS * NBR) {
        const int pp = tid / NBR, k = tid % NBR;
        const int n = nbase + pp;
        const int j = nb[tid];
        const float* q = qxyz + (size_t)b * 3 * NPT;
        const float* c = cxyz + (size_t)b * 3 * NPT;
        const float dx = c[j]           - q[n];
        const float dy = c[NPT + j]     - q[NPT + n];
        const float dz = c[2 * NPT + j] - q[2 * NPT + n];
        float h1[8], h2[8];
        #pragma unroll
        for (int o = 0; o < 8; ++o) {
            float v = wp[24 + o];
            v = fmaf(dx, wp[o], v);
            v = fmaf(dy, wp[8 + o], v);
            v = fmaf(dz, wp[16 + o], v);
            h1[o] = fmaxf(v, 0.f);
        }
        #pragma unroll
        for (int o = 0; o < 8; ++o) {
            float v = wp[96 + o];
            #pragma unroll
            for (int i = 0; i < 8; ++i) v = fmaf(h1[i], wp[32 + i * 8 + o], v);
            h2[o] = fmaxf(v, 0.f);
        }
        #pragma unroll
        for (int o = 0; o < WD; ++o) {
            float v = wp[232 + o];
            #pragma unroll
            for (int i = 0; i < 8; ++i) v = fmaf(h2[i], wp[104 + i * WD + o], v);
            wgt[pp * WSTR + k * WD + o] = fmaxf(v, 0.f);
        }
    }
    __syncthreads();

    if (tid < PTS * 16) {
        const int pp = tid >> 4, w = tid & 15;
        const float* wgp = wgt + pp * WSTR + w;
        float sv = 0.f;
        #pragma unroll
        for (int k = 0; k < NBR; ++k) sv += wgp[k * WD];
        swb[(size_t)((int)blockIdx.x * PTS + pp) * 16 + w] = sv;
    }

    {
        const float* wg = wgt + p * WSTR;
        bf16* aout = agg + ((size_t)((int)blockIdx.x * PTS + p)) * (2 * D2 * WD);
        float acc[ND][16];
        #pragma unroll
        for (int di = 0; di < ND; ++di)
            #pragma unroll
            for (int w = 0; w < 16; ++w) acc[di][w] = 0.f;
        #pragma unroll
        for (int k = 0; k < NBR; ++k) {
            union { unsigned int u; bf16 h[2]; } uf;
            uf.u = F[k];
            float Fv[ND];
            #pragma unroll
            for (int j = 0; j < ND; ++j) Fv[j] = __bfloat162float(uf.h[j]);
            const float4 v0 = *(const float4*)(wg + k * WD);
            const float4 v1 = *(const float4*)(wg + k * WD + 4);
            const float4 v2 = *(const float4*)(wg + k * WD + 8);
            const float4 v3 = *(const float4*)(wg + k * WD + 12);
            float w16[16];
            w16[0]  = v0.x; w16[1]  = v0.y; w16[2]  = v0.z; w16[3]  = v0.w;
            w16[4]  = v1.x; w16[5]  = v1.y; w16[6]  = v1.z; w16[7]  = v1.w;
            w16[8]  = v2.x; w16[9]  = v2.y; w16[10] = v2.z; w16[11] = v2.w;
            w16[12] = v3.x; w16[13] = v3.y; w16[14] = v3.z; w16[15] = v3.w;
            #pragma unroll
            for (int di = 0; di < ND; ++di)
                #pragma unroll
                for (int w = 0; w < 16; ++w)
                    acc[di][w] = fmaf(Fv[di], w16[w], acc[di][w]);
        }
        #pragma unroll
        for (int di = 0; di < ND; ++di) {
            union { bf16 h[16]; uint4 q[2]; } pk;
            #pragma unroll
            for (int w = 0; w < 16; ++w) pk.h[w] = __float2bfloat16(acc[di][w]);
            bf16* dst = aout + (D2 + d0 + di) * WD;
            *(uint4*)dst       = pk.q[0];
            *(uint4*)(dst + 8) = pk.q[1];
        }
    }
}

// ---------------------------------------------------------------------------
// MFMA GEMM v5 (round-18, unchanged): (row>>1)&3 swizzle, templated BM,
// own-half reconstruction.
// ---------------------------------------------------------------------------
template<int BM>
__global__ __launch_bounds__(256)
void gemm_mfma(const bf16* __restrict__ A, const bf16* __restrict__ Bhi,
               const bf16* __restrict__ Blo, const float* __restrict__ bias,
               const float* __restrict__ ownf, const float* __restrict__ swb,
               float* __restrict__ out_t, float* __restrict__ out_pm,
               bf16* __restrict__ out_pmb, int m0, int K)
{
    constexpr int AE   = BM * 32;
    constexpr int BUFE = AE + 8192;
    constexpr int MF   = BM / 32;
    __shared__ __align__(16) char smem[2 * BUFE * 2];
    bf16* lds = (bf16*)smem;

    const int tid  = threadIdx.x;
    const int w    = tid >> 6;
    const int lane = tid & 63;
    const int wr   = w >> 1, wc = w & 1;
    const int mb   = (int)blockIdx.x * BM;
    const int gK   = lane >> 4;
    const int rL   = lane & 15;
    const int D2v  = K / 32;

    const int row_r = tid >> 2;
    const int row_s = row_r < BM ? row_r : BM - 1;
    const int ch_s  = tid & 3;
    const int sch_s = ch_s ^ ((row_s >> 1) & 3);
    const int w0_s  = (sch_s & 1) * 8;
    float sww[8];
    {
        const float* sp = swb + (size_t)(mb + row_s) * 16 + w0_s;
        const float4 a = *(const float4*)sp;
        const float4 b2 = *(const float4*)(sp + 4);
        sww[0] = a.x;  sww[1] = a.y;  sww[2] = a.z;  sww[3] = a.w;
        sww[4] = b2.x; sww[5] = b2.y; sww[6] = b2.z; sww[7] = b2.w;
    }
    const float* ownrow_g = ownf + (size_t)(m0 + mb + row_s) * D2v;

    f32x4 acc[MF][4];
    #pragma unroll
    for (int i = 0; i < MF; ++i)
        #pragma unroll
        for (int j = 0; j < 4; ++j) acc[i][j] = (f32x4)0.f;

    const int nk = K / 32;
    const int nkOwn = nk / 2;

    auto stage = [&](int buf, int kt) {
        const int kb = kt * 32;
        const int bufo = buf * BUFE;
        if (kt < nkOwn) {
            if (tid < BM * 4) {
                const int d = kt * 2 + (sch_s >> 1);
                const float f = ownrow_g[d];
                union { bf16 h[8]; uint4 q; } pk;
                #pragma unroll
                for (int j = 0; j < 8; ++j) pk.h[j] = __float2bfloat16(f * sww[j]);
                *(uint4*)(lds + bufo + tid * 8) = pk.q;
            }
        } else {
            if (w * 64 < BM * 4)
                GLD16(A + (size_t)(mb + row_r) * K + kb + (sch_s << 3),
                      lds + bufo + ((w * 64) << 3));
        }
        #pragma unroll
        for (int i = 0; i < 2; ++i) {
            const int s2 = i * 256 + tid;
            const int row = s2 >> 2, ch = s2 & 3;
            const int sch = ch ^ ((row >> 1) & 3);
            const int wb = (i * 256 + w * 64) << 3;
            GLD16(Bhi + (size_t)row * K + kb + (sch << 3), lds + bufo + AE + wb);
            GLD16(Blo + (size_t)row * K + kb + (sch << 3), lds + bufo + AE + 4096 + wb);
        }
    };

    stage(0, 0);
    __syncthreads();

    for (int kt = 0; kt < nk; ++kt) {
        const int cur = kt & 1;
        if (kt + 1 < nk) stage(cur ^ 1, kt + 1);

        const bf16* la  = lds + cur * BUFE;
        const bf16* lbh = la + AE;
        const bf16* lbl = la + AE + 4096;

        bf16x8 af[MF], bh[4], bl[4];
        #pragma unroll
        for (int mf = 0; mf < MF; ++mf) {
            const int row = wr * (BM / 2) + mf * 16 + rL;
            af[mf] = *(const bf16x8*)(la + row * 32 + ((gK ^ ((row >> 1) & 3)) << 3));
        }
        #pragma unroll
        for (int nf = 0; nf < 4; ++nf) {
            const int col = wc * 64 + nf * 16 + rL;
            const int off = col * 32 + ((gK ^ ((col >> 1) & 3)) << 3);
            bh[nf] = *(const bf16x8*)(lbh + off);
            bl[nf] = *(const bf16x8*)(lbl + off);
        }
        #pragma unroll
        for (int mf = 0; mf < MF; ++mf)
            #pragma unroll
            for (int nf = 0; nf < 4; ++nf) {
                acc[mf][nf] = __builtin_amdgcn_mfma_f32_16x16x32_bf16(af[mf], bh[nf], acc[mf][nf], 0, 0, 0);
                acc[mf][nf] = __builtin_amdgcn_mfma_f32_16x16x32_bf16(af[mf], bl[nf], acc[mf][nf], 0, 0, 0);
            }
        __syncthreads();
    }

    float (*tile)[133] = (float(*)[133])smem;
    #pragma unroll
    for (int mf = 0; mf < MF; ++mf)
        #pragma unroll
        for (int nf = 0; nf < 4; ++nf) {
            const int col = wc * 64 + nf * 16 + rL;
            const float bs = bias[col];
            #pragma unroll
            for (int qq = 0; qq < 4; ++qq) {
                const int rrow = wr * (BM / 2) + mf * 16 + gK * 4 + qq;
                const float v = acc[mf][nf][qq] + bs;
                tile[rrow][col] = v > 0.f ? v : 0.1f * v;
            }
        }
    __syncthreads();

    const int mrow = m0 + mb;
    const int b = mrow >> 12, n0 = mrow & (NPT - 1);
    for (int e = tid; e < BM * MIDD; e += 256) {
        const int o = e / BM, i = e % BM;
        out_t[((size_t)b * MIDD + o) * NPT + n0 + i] = tile[i][o];
    }
    if (out_pm) {
        for (int e = tid; e < BM * MIDD; e += 256) {
            const int i = e >> 7, o = e & 127;
            const float v = tile[i][o];
            out_pm [(size_t)(mrow + i) * MIDD + o] = v;
            out_pmb[(size_t)(mrow + i) * MIDD + o] = __float2bfloat16(v);
        }
    }
}

// ---------------------------------------------------------------------------
extern "C" void kernel_launch(void* const* d_in, const int* in_sizes, int n_in,
                              void* d_out, int out_size, void* d_ws, size_t ws_size,
                              hipStream_t stream)
{
    (void)in_sizes; (void)n_in; (void)out_size;
    const float* pc1    = (const float*)d_in[0];
    const float* pc2    = (const float*)d_in[1];
    const float* feat1  = (const float*)d_in[2];
    const float* feat2  = (const float*)d_in[3];
    const float* wn1_w0 = (const float*)d_in[4];
    const float* wn1_b0 = (const float*)d_in[5];
    const float* wn1_w1 = (const float*)d_in[6];
    const float* wn1_b1 = (const float*)d_in[7];
    const float* wn1_w2 = (const float*)d_in[8];
    const float* wn1_b2 = (const float*)d_in[9];
    const float* lin1_w = (const float*)d_in[10];
    const float* lin1_b = (const float*)d_in[11];
    const float* wn2_w0 = (const float*)d_in[12];
    const float* wn2_b0 = (const float*)d_in[13];
    const float* wn2_w1 = (const float*)d_in[14];
    const float* wn2_b1 = (const float*)d_in[15];
    const float* wn2_w2 = (const float*)d_in[16];
    const float* wn2_b2 = (const float*)d_in[17];
    const float* lin2_w = (const float*)d_in[18];
    const float* lin2_b = (const float*)d_in[19];
    float* out = (float*)d_out;

    const int M  = BB * NPT;
    const int M2 = 2 * M;
    const int K1 = 2 * CDIM * WD;     // 2048
    const int K2 = 2 * MIDD * WD;     // 4096

    char* ws = (char*)d_ws;
    float* p1pm = (float*)ws;
    float* p2pm = p1pm + (size_t)M * CDIM;
    float* fpm  = p2pm + (size_t)M * CDIM;
    bf16*  p1b  = (bf16*)(fpm + (size_t)M2 * MIDD);
    bf16*  p2b  = p1b + (size_t)M * CDIM;
    bf16*  fb   = p2b + (size_t)M * CDIM;
    int* idx12  = (int*)(fb + (size_t)M2 * MIDD);
    int* idx21  = idx12 + (size_t)M * NBR;
    bf16* b1hi  = (bf16*)(idx21 + (size_t)M * NBR);
    bf16* b1lo  = b1hi + (size_t)MIDD * K1;
    bf16* b2hi  = b1lo + (size_t)MIDD * K1;
    bf16* b2lo  = b2hi + (size_t)MIDD * K2;
    float* swbuf = (float*)(b2lo + (size_t)MIDD * K2);
    bf16* aggbuf = (bf16*)(swbuf + (size_t)(M2 + 64) * 16);
    const size_t used = (size_t)((char*)aggbuf - ws);
    const size_t avail = ws_size > used ? ws_size - used : 0;

    float* f1t = out;
    float* fft = out + 2 * (size_t)BB * MIDD * NPT;

    prep_kernel<<<2816, 256, 0, stream>>>(feat1, feat2, p1pm, p1b, p2pm, p2b,
                                          lin1_w, b1hi, b1lo, lin2_w, b2hi, b2lo);
    knn_kernel<<<dim3(NPT / KQ, BB, 2), 256, 0, stream>>>(pc1, pc2, idx12, idx21);

    auto chunk_rows = [&](int K) -> int {
        long rows = (long)(avail / ((size_t)K * sizeof(bf16)));
        int cm = (int)(rows > M2 ? M2 : rows) & ~127;
        if (cm < 128) cm = 128;
        return cm;
    };

    {   // cross 1 + cross 2 merged (K = 2048); BM=64
        const int CMr = chunk_rows(K1);
        for (int m0 = 0; m0 < M2; m0 += CMr) {
            const int cm = (M2 - m0 < CMr) ? (M2 - m0) : CMr;
            agg_kernel<CDIM, 8><<<cm / 8, 256, 0, stream>>>(
                pc1, pc2, p2b, idx12,
                pc2, pc1, p1b, idx21, M,
                wn1_w0, wn1_b0, wn1_w1, wn1_b1, wn1_w2, wn1_b2,
                aggbuf, swbuf, m0);
            gemm_mfma<64><<<cm / 64, 256, 0, stream>>>(aggbuf, b1hi, b1lo, lin1_b,
                                                       p1pm, swbuf,
                                                       f1t, fpm, fb, m0, K1);
        }
    }
    {   // cross 3 (K = 4096); BM=32
        const int CMr = chunk_rows(K2);
        for (int m0 = 0; m0 < M; m0 += CMr) {
            const int cm = (M - m0 < CMr) ? (M - m0) : CMr;
            agg_kernel<MIDD, 4><<<cm / 4, 256, 0, stream>>>(
                pc1, pc2, fb + (size_t)M * MIDD, idx12,
                nullptr, nullptr, nullptr, nullptr, M2,
                wn2_w0, wn2_b0, wn2_w1, wn2_b1, wn2_w2, wn2_b2,
                aggbuf, swbuf, m0);
            gemm_mfma<32><<<cm / 32, 256, 0, stream>>>(aggbuf, b2hi, b2lo, lin2_b,
                                                       fpm, swbuf,
                                                       fft, nullptr, nullptr, m0, K2);
        }
    }
}

// Round 20
// 292.809 us; speedup vs baseline: 1.5684x; 1.0796x over previous
//
#include <hip/hip_runtime.h>
#include <hip/hip_bf16.h>
#include <cstddef>
#include <cstdint>

typedef __hip_bfloat16 bf16;
typedef __attribute__((ext_vector_type(8))) short bf16x8;   // 8 bf16 = 4 VGPRs
typedef __attribute__((ext_vector_type(4))) float f32x4;

#define NPT 4096   // points per cloud
#define BB  4      // batch
#define NBR 16     // neighbors (nsample)
#define WD  16     // weightnet output width
#define CDIM 64    // input feature channels
#define MIDD 128   // lin1/lin2 output channels

// async global->LDS, 16B per lane; LDS dest is wave-uniform base + lane*16
#define GLD16(g, l) __builtin_amdgcn_global_load_lds( \
    (const __attribute__((address_space(1))) unsigned int*)(const void*)(g), \
    (__attribute__((address_space(3))) unsigned int*)(void*)(l), 16, 0, 0)

// ---------------------------------------------------------------------------
// Fused prep: feature transposes (fp32+bf16) + lin-weight hi/lo splits.
// ---------------------------------------------------------------------------
__global__ __launch_bounds__(256)
void prep_kernel(const float* __restrict__ feat1, const float* __restrict__ feat2,
                 float* __restrict__ p1pm, bf16* __restrict__ p1b,
                 float* __restrict__ p2pm, bf16* __restrict__ p2b,
                 const float* __restrict__ lin1_w, bf16* __restrict__ b1hi, bf16* __restrict__ b1lo,
                 const float* __restrict__ lin2_w, bf16* __restrict__ b2hi, bf16* __restrict__ b2lo)
{
    __shared__ float t[32][33];
    const int tx = threadIdx.x & 31, ty = threadIdx.x >> 5;
    const int id = blockIdx.x;
    if (id < 2048) {
        const int which = id >> 10;
        const int nt = id & 1023;
        const int n0 = (nt & 127) * 32;
        const int c0 = ((nt >> 7) & 1) * 32;
        const int b  = nt >> 8;
        const float* in = which ? feat2 : feat1;
        float* out  = which ? p2pm : p1pm;
        bf16*  outb = which ? p2b  : p1b;
        #pragma unroll
        for (int r = ty; r < 32; r += 8)
            t[r][tx] = in[((size_t)b * CDIM + c0 + r) * NPT + n0 + tx];
        __syncthreads();
        #pragma unroll
        for (int r = ty; r < 32; r += 8) {
            const float v = t[tx][r];
            out [((size_t)b * NPT + n0 + r) * CDIM + c0 + tx] = v;
            outb[((size_t)b * NPT + n0 + r) * CDIM + c0 + tx] = __float2bfloat16(v);
        }
    } else {
        const float* w; bf16 *hi, *lo; int K, k0, o0;
        if (id < 2304) {
            const int id2 = id - 2048;
            w = lin1_w; hi = b1hi; lo = b1lo; K = 2048;
            k0 = (id2 & 63) * 32; o0 = (id2 >> 6) * 32;
        } else {
            const int id2 = id - 2304;
            w = lin2_w; hi = b2hi; lo = b2lo; K = 4096;
            k0 = (id2 & 127) * 32; o0 = (id2 >> 7) * 32;
        }
        #pragma unroll
        for (int r = ty; r < 32; r += 8)
            t[r][tx] = w[(size_t)(k0 + r) * MIDD + o0 + tx];
        __syncthreads();
        #pragma unroll
        for (int r = ty; r < 32; r += 8) {
            const float v = t[tx][r];
            const bf16 h = __float2bfloat16(v);
            const bf16 l2 = __float2bfloat16(v - __bfloat162float(h));
            hi[(size_t)(o0 + r) * K + k0 + tx] = h;
            lo[(size_t)(o0 + r) * K + k0 + tx] = l2;
        }
    }
}

// ---------------------------------------------------------------------------
// KNN v8 (round-19, unchanged): argmin tracking + selective rescan.
// ---------------------------------------------------------------------------
#define KQ     16
#define KSEG   16
#define KCH    64
#define KSTAGE 1024
#define KRING  96

__global__ __launch_bounds__(256)
void knn_kernel(const float* __restrict__ pcA, const float* __restrict__ pcB,
                int* __restrict__ idxAB, int* __restrict__ idxBA)
{
    const float *qxyz, *cxyz; int* idx_out;
    if (blockIdx.z == 0) { qxyz = pcA; cxyz = pcB; idx_out = idxAB; }
    else                 { qxyz = pcB; cxyz = pcA; idx_out = idxBA; }

    __shared__ float4 cf[KSTAGE + KSTAGE / KCH];   // skewed
    __shared__ float  pubd[2][KSEG][KQ];
    __shared__ float4 qc[KQ];
    __shared__ float  u16s[KQ];
    __shared__ int    rcnt[KQ];
    __shared__ int    wtot;
    __shared__ int    wl[256];
    __shared__ float  ringd[KQ][KRING + 1];
    __shared__ int    ringi[KQ][KRING + 1];

    const int tid = threadIdx.x;
    const int q   = tid & (KQ - 1);
    const int s   = tid >> 4;
    const int b   = blockIdx.y;
    const int n   = blockIdx.x * KQ + q;

    const float* qp = qxyz + (size_t)b * 3 * NPT;
    const float qx = qp[n], qy = qp[NPT + n], qz = qp[2 * NPT + n];
    const float q2 = fmaf(qx, qx, fmaf(qy, qy, qz * qz));
    const float* c = cxyz + (size_t)b * 3 * NPT;

    if (tid < KQ) rcnt[tid] = 0;
    if (tid == 0) wtot = 0;
    if (s == 0) qc[q] = make_float4(qx, qy, qz, q2);

    float b0 = 3.4e38f, b1 = 3.4e38f;
    int   i0 = 0;
    for (int st = 0; st < NPT; st += KSTAGE) {
        __syncthreads();
        {
            #pragma unroll
            for (int r = 0; r < KSTAGE / 256; ++r) {
                const int j = r * 256 + tid;
                const int g = st + j;
                const float x = c[g], y = c[NPT + g], z = c[2 * NPT + g];
                cf[j + (j >> 6)] = make_float4(x, y, z,
                    fmaf(x, x, fmaf(y, y, z * z)));
            }
        }
        __syncthreads();
        const int base = s * (KCH + 1);
        const int gidx = st + s * KCH;
        #pragma unroll 4
        for (int jj = 0; jj < KCH; ++jj) {
            const float4 pv = cf[base + jj];
            const float dot = fmaf(qx, pv.x, fmaf(qy, pv.y, qz * pv.z));
            const float d = q2 + pv.w - 2.f * dot;
            i0 = (d < b0) ? (gidx + jj) : i0;
            const float t = fmaxf(b0, d);
            b0 = fminf(b0, d);
            b1 = fminf(b1, t);
        }
    }
    pubd[0][s][q] = b0;
    pubd[1][s][q] = b1;
    __syncthreads();

    {
        float tv[32];
        #pragma unroll
        for (int j = 0; j < 32; ++j) tv[j] = pubd[j >> 4][j & 15][q];
        #pragma unroll
        for (int rep = 0; rep < 2; ++rep) {
            const int j = rep * 16 + s;
            const float vj = pubd[rep][s][q];
            int rank = 0;
            #pragma unroll
            for (int k = 0; k < 32; ++k)
                rank += (tv[k] < vj || (tv[k] == vj && k < j)) ? 1 : 0;
            if (rank == 15) u16s[q] = vj;
        }
    }
    __syncthreads();

    {
        const float gate = u16s[q];
        if (b0 <= gate) {
            if (b1 > gate) {
                const int slot = atomicAdd(&rcnt[q], 1);
                if (slot < KRING) { ringd[q][slot] = b0; ringi[q][slot] = i0; }
            } else {
                const int u = atomicAdd(&wtot, 1);
                wl[u] = (q << 4) | s;
            }
        }
    }
    __syncthreads();

    {
        const int W = wtot;
        const int lu = tid & 15;
        for (int u = tid >> 4; u < W; u += 16) {
            const int qq  = wl[u] >> 4;
            const int seg = wl[u] & 15;
            const float4 qv = qc[qq];
            const float gate = u16s[qq];
            #pragma unroll
            for (int ch = 0; ch < 4; ++ch) {
                const int j = ch * KSTAGE + seg * KCH + lu * 4;
                const float4 xs = *(const float4*)(c + j);
                const float4 ys = *(const float4*)(c + NPT + j);
                const float4 zs = *(const float4*)(c + 2 * NPT + j);
                const float xv[4] = { xs.x, xs.y, xs.z, xs.w };
                const float yv[4] = { ys.x, ys.y, ys.z, ys.w };
                const float zv[4] = { zs.x, zs.y, zs.z, zs.w };
                #pragma unroll
                for (int e = 0; e < 4; ++e) {
                    const float p2 = fmaf(xv[e], xv[e], fmaf(yv[e], yv[e], zv[e] * zv[e]));
                    const float dot = fmaf(qv.x, xv[e], fmaf(qv.y, yv[e], qv.z * zv[e]));
                    const float d = qv.w + p2 - 2.f * dot;
                    if (d <= gate) {
                        const int slot = atomicAdd(&rcnt[qq], 1);
                        if (slot < KRING) { ringd[qq][slot] = d; ringi[qq][slot] = j + e; }
                    }
                }
            }
        }
    }
    __syncthreads();

    {
        const int cnt = min(rcnt[q], KRING);
        int* op = idx_out + ((size_t)b * NPT + n) * NBR;
        for (int e = s; e < cnt; e += KSEG) {
            const float de = ringd[q][e];
            const int   ie = ringi[q][e];
            int rank = 0;
            for (int k = 0; k < cnt; ++k) {
                const float dk = ringd[q][k];
                const int   ik = ringi[q][k];
                rank += (dk < de || (dk == de && ik < ie)) ? 1 : 0;
            }
            if (rank < NBR) op[rank] = ie;
        }
    }
}

// ---------------------------------------------------------------------------
// Weightnet + aggregation v7 (round-17, unchanged).
// ---------------------------------------------------------------------------
template<int D2, int PTS>
__global__ __launch_bounds__(256)
void agg_kernel(const float* __restrict__ qA, const float* __restrict__ cA,
                const bf16* __restrict__ nbrA, const int* __restrict__ idxA,
                const float* __restrict__ qB, const float* __restrict__ cB,
                const bf16* __restrict__ nbrB, const int* __restrict__ idxB,
                int Msplit,
                const float* __restrict__ w0, const float* __restrict__ b0,
                const float* __restrict__ w1, const float* __restrict__ b1,
                const float* __restrict__ w2, const float* __restrict__ b2,
                bf16* __restrict__ agg, float* __restrict__ swb, int m0)
{
    constexpr int TPP  = 256 / PTS;
    constexpr int ND   = D2 / TPP;      // 2
    constexpr int WSTR = 276;

    __shared__ float wp[248];
    __shared__ int   nb[PTS * NBR];
    __shared__ float wgt[PTS * WSTR];

    const int tid = threadIdx.x;
    const int mbase = m0 + (int)blockIdx.x * PTS;
    const bool second = mbase >= Msplit;
    const int mrow = second ? mbase - Msplit : mbase;
    const float* qxyz   = second ? qB   : qA;
    const float* cxyz   = second ? cB   : cA;
    const bf16*  nbr_b  = second ? nbrB : nbrA;
    const int*   idx    = second ? idxB : idxA;
    const int b = mrow >> 12;
    const int nbase = mrow & (NPT - 1);

    if (tid < 248) {
        float v;
        if      (tid <  24) v = w0[tid];
        else if (tid <  32) v = b0[tid - 24];
        else if (tid <  96) v = w1[tid - 32];
        else if (tid < 104) v = b1[tid - 96];
        else if (tid < 232) v = w2[tid - 104];
        else                v = b2[tid - 232];
        wp[tid] = v;
    }
    if (tid < PTS * NBR)
        nb[tid] = idx[(size_t)mrow * NBR + tid];
    __syncthreads();

    const int p  = tid & (PTS - 1);
    const int dg = tid / PTS;
    const int d0 = dg * ND;

    unsigned int F[NBR];
    {
        const bf16* base = nbr_b + (size_t)b * NPT * D2 + d0;
        #pragma unroll
        for (int k = 0; k < NBR; ++k) {
            const int j = nb[p * NBR + k];
            F[k] = *(const unsigned int*)(base + (size_t)j * D2);
        }
    }

    if (tid < PTS * NBR) {
        const int pp = tid / NBR, k = tid % NBR;
        const int n = nbase + pp;
        const int j = nb[tid];
        const float* q = qxyz + (size_t)b * 3 * NPT;
        const float* c = cxyz + (size_t)b * 3 * NPT;
        const float dx = c[j]           - q[n];
        const float dy = c[NPT + j]     - q[NPT + n];
        const float dz = c[2 * NPT + j] - q[2 * NPT + n];
        float h1[8], h2[8];
        #pragma unroll
        for (int o = 0; o < 8; ++o) {
            float v = wp[24 + o];
            v = fmaf(dx, wp[o], v);
            v = fmaf(dy, wp[8 + o], v);
            v = fmaf(dz, wp[16 + o], v);
            h1[o] = fmaxf(v, 0.f);
        }
        #pragma unroll
        for (int o = 0; o < 8; ++o) {
            float v = wp[96 + o];
            #pragma unroll
            for (int i = 0; i < 8; ++i) v = fmaf(h1[i], wp[32 + i * 8 + o], v);
            h2[o] = fmaxf(v, 0.f);
        }
        #pragma unroll
        for (int o = 0; o < WD; ++o) {
            float v = wp[232 + o];
            #pragma unroll
            for (int i = 0; i < 8; ++i) v = fmaf(h2[i], wp[104 + i * WD + o], v);
            wgt[pp * WSTR + k * WD + o] = fmaxf(v, 0.f);
        }
    }
    __syncthreads();

    if (tid < PTS * 16) {
        const int pp = tid >> 4, w = tid & 15;
        const float* wgp = wgt + pp * WSTR + w;
        float sv = 0.f;
        #pragma unroll
        for (int k = 0; k < NBR; ++k) sv += wgp[k * WD];
        swb[(size_t)((int)blockIdx.x * PTS + pp) * 16 + w] = sv;
    }

    {
        const float* wg = wgt + p * WSTR;
        bf16* aout = agg + ((size_t)((int)blockIdx.x * PTS + p)) * (2 * D2 * WD);
        float acc[ND][16];
        #pragma unroll
        for (int di = 0; di < ND; ++di)
            #pragma unroll
            for (int w = 0; w < 16; ++w) acc[di][w] = 0.f;
        #pragma unroll
        for (int k = 0; k < NBR; ++k) {
            union { unsigned int u; bf16 h[2]; } uf;
            uf.u = F[k];
            float Fv[ND];
            #pragma unroll
            for (int j = 0; j < ND; ++j) Fv[j] = __bfloat162float(uf.h[j]);
            const float4 v0 = *(const float4*)(wg + k * WD);
            const float4 v1 = *(const float4*)(wg + k * WD + 4);
            const float4 v2 = *(const float4*)(wg + k * WD + 8);
            const float4 v3 = *(const float4*)(wg + k * WD + 12);
            float w16[16];
            w16[0]  = v0.x; w16[1]  = v0.y; w16[2]  = v0.z; w16[3]  = v0.w;
            w16[4]  = v1.x; w16[5]  = v1.y; w16[6]  = v1.z; w16[7]  = v1.w;
            w16[8]  = v2.x; w16[9]  = v2.y; w16[10] = v2.z; w16[11] = v2.w;
            w16[12] = v3.x; w16[13] = v3.y; w16[14] = v3.z; w16[15] = v3.w;
            #pragma unroll
            for (int di = 0; di < ND; ++di)
                #pragma unroll
                for (int w = 0; w < 16; ++w)
                    acc[di][w] = fmaf(Fv[di], w16[w], acc[di][w]);
        }
        #pragma unroll
        for (int di = 0; di < ND; ++di) {
            union { bf16 h[16]; uint4 q[2]; } pk;
            #pragma unroll
            for (int w = 0; w < 16; ++w) pk.h[w] = __float2bfloat16(acc[di][w]);
            bf16* dst = aout + (D2 + d0 + di) * WD;
            *(uint4*)dst       = pk.q[0];
            *(uint4*)(dst + 8) = pk.q[1];
        }
    }
}

// ---------------------------------------------------------------------------
// MFMA GEMM v5 (round-18, unchanged): BM=64, BK=32 — used for cross 1/2.
// ---------------------------------------------------------------------------
template<int BM>
__global__ __launch_bounds__(256)
void gemm_mfma(const bf16* __restrict__ A, const bf16* __restrict__ Bhi,
               const bf16* __restrict__ Blo, const float* __restrict__ bias,
               const float* __restrict__ ownf, const float* __restrict__ swb,
               float* __restrict__ out_t, float* __restrict__ out_pm,
               bf16* __restrict__ out_pmb, int m0, int K)
{
    constexpr int AE   = BM * 32;
    constexpr int BUFE = AE + 8192;
    constexpr int MF   = BM / 32;
    __shared__ __align__(16) char smem[2 * BUFE * 2];
    bf16* lds = (bf16*)smem;

    const int tid  = threadIdx.x;
    const int w    = tid >> 6;
    const int lane = tid & 63;
    const int wr   = w >> 1, wc = w & 1;
    const int mb   = (int)blockIdx.x * BM;
    const int gK   = lane >> 4;
    const int rL   = lane & 15;
    const int D2v  = K / 32;

    const int row_r = tid >> 2;
    const int row_s = row_r < BM ? row_r : BM - 1;
    const int ch_s  = tid & 3;
    const int sch_s = ch_s ^ ((row_s >> 1) & 3);
    const int w0_s  = (sch_s & 1) * 8;
    float sww[8];
    {
        const float* sp = swb + (size_t)(mb + row_s) * 16 + w0_s;
        const float4 a = *(const float4*)sp;
        const float4 b2 = *(const float4*)(sp + 4);
        sww[0] = a.x;  sww[1] = a.y;  sww[2] = a.z;  sww[3] = a.w;
        sww[4] = b2.x; sww[5] = b2.y; sww[6] = b2.z; sww[7] = b2.w;
    }
    const float* ownrow_g = ownf + (size_t)(m0 + mb + row_s) * D2v;

    f32x4 acc[MF][4];
    #pragma unroll
    for (int i = 0; i < MF; ++i)
        #pragma unroll
        for (int j = 0; j < 4; ++j) acc[i][j] = (f32x4)0.f;

    const int nk = K / 32;
    const int nkOwn = nk / 2;

    auto stage = [&](int buf, int kt) {
        const int kb = kt * 32;
        const int bufo = buf * BUFE;
        if (kt < nkOwn) {
            if (tid < BM * 4) {
                const int d = kt * 2 + (sch_s >> 1);
                const float f = ownrow_g[d];
                union { bf16 h[8]; uint4 q; } pk;
                #pragma unroll
                for (int j = 0; j < 8; ++j) pk.h[j] = __float2bfloat16(f * sww[j]);
                *(uint4*)(lds + bufo + tid * 8) = pk.q;
            }
        } else {
            if (w * 64 < BM * 4)
                GLD16(A + (size_t)(mb + row_r) * K + kb + (sch_s << 3),
                      lds + bufo + ((w * 64) << 3));
        }
        #pragma unroll
        for (int i = 0; i < 2; ++i) {
            const int s2 = i * 256 + tid;
            const int row = s2 >> 2, ch = s2 & 3;
            const int sch = ch ^ ((row >> 1) & 3);
            const int wb = (i * 256 + w * 64) << 3;
            GLD16(Bhi + (size_t)row * K + kb + (sch << 3), lds + bufo + AE + wb);
            GLD16(Blo + (size_t)row * K + kb + (sch << 3), lds + bufo + AE + 4096 + wb);
        }
    };

    stage(0, 0);
    __syncthreads();

    for (int kt = 0; kt < nk; ++kt) {
        const int cur = kt & 1;
        if (kt + 1 < nk) stage(cur ^ 1, kt + 1);

        const bf16* la  = lds + cur * BUFE;
        const bf16* lbh = la + AE;
        const bf16* lbl = la + AE + 4096;

        bf16x8 af[MF], bh[4], bl[4];
        #pragma unroll
        for (int mf = 0; mf < MF; ++mf) {
            const int row = wr * (BM / 2) + mf * 16 + rL;
            af[mf] = *(const bf16x8*)(la + row * 32 + ((gK ^ ((row >> 1) & 3)) << 3));
        }
        #pragma unroll
        for (int nf = 0; nf < 4; ++nf) {
            const int col = wc * 64 + nf * 16 + rL;
            const int off = col * 32 + ((gK ^ ((col >> 1) & 3)) << 3);
            bh[nf] = *(const bf16x8*)(lbh + off);
            bl[nf] = *(const bf16x8*)(lbl + off);
        }
        #pragma unroll
        for (int mf = 0; mf < MF; ++mf)
            #pragma unroll
            for (int nf = 0; nf < 4; ++nf) {
                acc[mf][nf] = __builtin_amdgcn_mfma_f32_16x16x32_bf16(af[mf], bh[nf], acc[mf][nf], 0, 0, 0);
                acc[mf][nf] = __builtin_amdgcn_mfma_f32_16x16x32_bf16(af[mf], bl[nf], acc[mf][nf], 0, 0, 0);
            }
        __syncthreads();
    }

    float (*tile)[133] = (float(*)[133])smem;
    #pragma unroll
    for (int mf = 0; mf < MF; ++mf)
        #pragma unroll
        for (int nf = 0; nf < 4; ++nf) {
            const int col = wc * 64 + nf * 16 + rL;
            const float bs = bias[col];
            #pragma unroll
            for (int qq = 0; qq < 4; ++qq) {
                const int rrow = wr * (BM / 2) + mf * 16 + gK * 4 + qq;
                const float v = acc[mf][nf][qq] + bs;
                tile[rrow][col] = v > 0.f ? v : 0.1f * v;
            }
        }
    __syncthreads();

    const int mrow = m0 + mb;
    const int b = mrow >> 12, n0 = mrow & (NPT - 1);
    for (int e = tid; e < BM * MIDD; e += 256) {
        const int o = e / BM, i = e % BM;
        out_t[((size_t)b * MIDD + o) * NPT + n0 + i] = tile[i][o];
    }
    if (out_pm) {
        for (int e = tid; e < BM * MIDD; e += 256) {
            const int i = e >> 7, o = e & 127;
            const float v = tile[i][o];
            out_pm [(size_t)(mrow + i) * MIDD + o] = v;
            out_pmb[(size_t)(mrow + i) * MIDD + o] = __float2bfloat16(v);
        }
    }
}

// ---------------------------------------------------------------------------
// MFMA GEMM k64 (cross 3): BM=32, BK=64 — half the barrier count, 16 MFMA
// per wave per phase. LDS rows are 64 bf16 (128 B); chunk swizzle over 8
// chunks: sch = ch ^ (row&7) -> read bank-quads sweep all 8 per 8 rows
// (2-way = free); staging dest linear-by-tid (GLD16-compatible).
// Own-half (kt < nk/2): d = kt*4 + (sch>>1), w0 = (sch&1)*8 — same element
// values; MFMA issue order (k-ascending, hi-then-lo per nf) preserved ->
// bit-identical output.
// ---------------------------------------------------------------------------
__global__ __launch_bounds__(256)
void gemm_mfma_k64(const bf16* __restrict__ A, const bf16* __restrict__ Bhi,
                   const bf16* __restrict__ Blo, const float* __restrict__ bias,
                   const float* __restrict__ ownf, const float* __restrict__ swb,
                   float* __restrict__ out_t, int m0, int K)
{
    constexpr int BM   = 32;
    constexpr int AE   = BM * 64;          // 2048 elements
    constexpr int BT   = 128 * 64;         // 8192 elements per B tile
    constexpr int BUFE = AE + 2 * BT;      // 18432 elements
    __shared__ __align__(16) char smem[2 * BUFE * 2];   // 72 KB
    bf16* lds = (bf16*)smem;

    const int tid  = threadIdx.x;
    const int w    = tid >> 6;
    const int lane = tid & 63;
    const int wr   = w >> 1, wc = w & 1;
    const int mb   = (int)blockIdx.x * BM;
    const int gK   = lane >> 4;
    const int rL   = lane & 15;
    const int D2v  = K / 32;

    // A staging constants: 256 slots = 32 rows x 8 chunks
    const int rowA = tid >> 3, chA = tid & 7;
    const int schA = chA ^ (rowA & 7);
    const int w0A  = (schA & 1) * 8;
    float sww[8];
    {
        const float* sp = swb + (size_t)(mb + rowA) * 16 + w0A;
        const float4 a = *(const float4*)sp;
        const float4 b2 = *(const float4*)(sp + 4);
        sww[0] = a.x;  sww[1] = a.y;  sww[2] = a.z;  sww[3] = a.w;
        sww[4] = b2.x; sww[5] = b2.y; sww[6] = b2.z; sww[7] = b2.w;
    }
    const float* ownrow_g = ownf + (size_t)(m0 + mb + rowA) * D2v;

    f32x4 acc[4];
    #pragma unroll
    for (int j = 0; j < 4; ++j) acc[j] = (f32x4)0.f;

    const int nk = K / 64;
    const int nkOwn = nk / 2;

    auto stage = [&](int buf, int kt) {
        const int kb = kt * 64;
        const int bufo = buf * BUFE;
        if (kt < nkOwn) {   // own-half: reconstruct bf16(own_d * sw_w)
            const int d = kt * 4 + (schA >> 1);
            const float f = ownrow_g[d];
            union { bf16 h[8]; uint4 q; } pk;
            #pragma unroll
            for (int j = 0; j < 8; ++j) pk.h[j] = __float2bfloat16(f * sww[j]);
            *(uint4*)(lds + bufo + tid * 8) = pk.q;
        } else {            // gather-half via async load (all 4 waves)
            GLD16(A + (size_t)(mb + rowA) * K + kb + (schA << 3),
                  lds + bufo + ((w * 64) << 3));
        }
        #pragma unroll
        for (int i = 0; i < 4; ++i) {   // B tiles: 128 rows x 8 chunks = 1024 slots
            const int s2 = i * 256 + tid;
            const int row = s2 >> 3, ch = s2 & 7;
            const int sch = ch ^ (row & 7);
            const int wb = (i * 256 + w * 64) << 3;
            GLD16(Bhi + (size_t)row * K + kb + (sch << 3), lds + bufo + AE + wb);
            GLD16(Blo + (size_t)row * K + kb + (sch << 3), lds + bufo + AE + BT + wb);
        }
    };

    stage(0, 0);
    __syncthreads();

    for (int kt = 0; kt < nk; ++kt) {
        const int cur = kt & 1;
        if (kt + 1 < nk) stage(cur ^ 1, kt + 1);

        const bf16* la  = lds + cur * BUFE;
        const bf16* lbh = la + AE;
        const bf16* lbl = la + AE + BT;

        #pragma unroll
        for (int kk2 = 0; kk2 < 2; ++kk2) {
            const int cc = gK + kk2 * 4;
            const int row = wr * 16 + rL;
            const bf16x8 af = *(const bf16x8*)(la + row * 64 + ((cc ^ (row & 7)) << 3));
            bf16x8 bh[4], bl[4];
            #pragma unroll
            for (int nf = 0; nf < 4; ++nf) {
                const int col = wc * 64 + nf * 16 + rL;
                const int off = col * 64 + ((cc ^ (col & 7)) << 3);
                bh[nf] = *(const bf16x8*)(lbh + off);
                bl[nf] = *(const bf16x8*)(lbl + off);
            }
            #pragma unroll
            for (int nf = 0; nf < 4; ++nf) {
                acc[nf] = __builtin_amdgcn_mfma_f32_16x16x32_bf16(af, bh[nf], acc[nf], 0, 0, 0);
                acc[nf] = __builtin_amdgcn_mfma_f32_16x16x32_bf16(af, bl[nf], acc[nf], 0, 0, 0);
            }
        }
        __syncthreads();
    }

    float (*tile)[133] = (float(*)[133])smem;
    #pragma unroll
    for (int nf = 0; nf < 4; ++nf) {
        const int col = wc * 64 + nf * 16 + rL;
        const float bs = bias[col];
        #pragma unroll
        for (int qq = 0; qq < 4; ++qq) {
            const int rrow = wr * 16 + gK * 4 + qq;
            const float v = acc[nf][qq] + bs;
            tile[rrow][col] = v > 0.f ? v : 0.1f * v;
        }
    }
    __syncthreads();

    const int mrow = m0 + mb;
    const int b = mrow >> 12, n0 = mrow & (NPT - 1);
    for (int e = tid; e < BM * MIDD; e += 256) {
        const int o = e / BM, i = e % BM;
        out_t[((size_t)b * MIDD + o) * NPT + n0 + i] = tile[i][o];
    }
}

// ---------------------------------------------------------------------------
extern "C" void kernel_launch(void* const* d_in, const int* in_sizes, int n_in,
                              void* d_out, int out_size, void* d_ws, size_t ws_size,
                              hipStream_t stream)
{
    (void)in_sizes; (void)n_in; (void)out_size;
    const float* pc1    = (const float*)d_in[0];
    const float* pc2    = (const float*)d_in[1];
    const float* feat1  = (const float*)d_in[2];
    const float* feat2  = (const float*)d_in[3];
    const float* wn1_w0 = (const float*)d_in[4];
    const float* wn1_b0 = (const float*)d_in[5];
    const float* wn1_w1 = (const float*)d_in[6];
    const float* wn1_b1 = (const float*)d_in[7];
    const float* wn1_w2 = (const float*)d_in[8];
    const float* wn1_b2 = (const float*)d_in[9];
    const float* lin1_w = (const float*)d_in[10];
    const float* lin1_b = (const float*)d_in[11];
    const float* wn2_w0 = (const float*)d_in[12];
    const float* wn2_b0 = (const float*)d_in[13];
    const float* wn2_w1 = (const float*)d_in[14];
    const float* wn2_b1 = (const float*)d_in[15];
    const float* wn2_w2 = (const float*)d_in[16];
    const float* wn2_b2 = (const float*)d_in[17];
    const float* lin2_w = (const float*)d_in[18];
    const float* lin2_b = (const float*)d_in[19];
    float* out = (float*)d_out;

    const int M  = BB * NPT;
    const int M2 = 2 * M;
    const int K1 = 2 * CDIM * WD;     // 2048
    const int K2 = 2 * MIDD * WD;     // 4096

    char* ws = (char*)d_ws;
    float* p1pm = (float*)ws;
    float* p2pm = p1pm + (size_t)M * CDIM;
    float* fpm  = p2pm + (size_t)M * CDIM;
    bf16*  p1b  = (bf16*)(fpm + (size_t)M2 * MIDD);
    bf16*  p2b  = p1b + (size_t)M * CDIM;
    bf16*  fb   = p2b + (size_t)M * CDIM;
    int* idx12  = (int*)(fb + (size_t)M2 * MIDD);
    int* idx21  = idx12 + (size_t)M * NBR;
    bf16* b1hi  = (bf16*)(idx21 + (size_t)M * NBR);
    bf16* b1lo  = b1hi + (size_t)MIDD * K1;
    bf16* b2hi  = b1lo + (size_t)MIDD * K1;
    bf16* b2lo  = b2hi + (size_t)MIDD * K2;
    float* swbuf = (float*)(b2lo + (size_t)MIDD * K2);
    bf16* aggbuf = (bf16*)(swbuf + (size_t)(M2 + 64) * 16);
    const size_t used = (size_t)((char*)aggbuf - ws);
    const size_t avail = ws_size > used ? ws_size - used : 0;

    float* f1t = out;
    float* fft = out + 2 * (size_t)BB * MIDD * NPT;

    prep_kernel<<<2816, 256, 0, stream>>>(feat1, feat2, p1pm, p1b, p2pm, p2b,
                                          lin1_w, b1hi, b1lo, lin2_w, b2hi, b2lo);
    knn_kernel<<<dim3(NPT / KQ, BB, 2), 256, 0, stream>>>(pc1, pc2, idx12, idx21);

    auto chunk_rows = [&](int K) -> int {
        long rows = (long)(avail / ((size_t)K * sizeof(bf16)));
        int cm = (int)(rows > M2 ? M2 : rows) & ~127;
        if (cm < 128) cm = 128;
        return cm;
    };

    {   // cross 1 + cross 2 merged (K = 2048); BM=64, BK=32
        const int CMr = chunk_rows(K1);
        for (int m0 = 0; m0 < M2; m0 += CMr) {
            const int cm = (M2 - m0 < CMr) ? (M2 - m0) : CMr;
            agg_kernel<CDIM, 8><<<cm / 8, 256, 0, stream>>>(
                pc1, pc2, p2b, idx12,
                pc2, pc1, p1b, idx21, M,
                wn1_w0, wn1_b0, wn1_w1, wn1_b1, wn1_w2, wn1_b2,
                aggbuf, swbuf, m0);
            gemm_mfma<64><<<cm / 64, 256, 0, stream>>>(aggbuf, b1hi, b1lo, lin1_b,
                                                       p1pm, swbuf,
                                                       f1t, fpm, fb, m0, K1);
        }
    }
    {   // cross 3 (K = 4096); BM=32, BK=64
        const int CMr = chunk_rows(K2);
        for (int m0 = 0; m0 < M; m0 += CMr) {
            const int cm = (M - m0 < CMr) ? (M - m0) : CMr;
            agg_kernel<MIDD, 4><<<cm / 4, 256, 0, stream>>>(
                pc1, pc2, fb + (size_t)M * MIDD, idx12,
                nullptr, nullptr, nullptr, nullptr, M2,
                wn2_w0, wn2_b0, wn2_w1, wn2_b1, wn2_w2, wn2_b2,
                aggbuf, swbuf, m0);
            gemm_mfma_k64<<<cm / 32, 256, 0, stream>>>(aggbuf, b2hi, b2lo, lin2_b,
                                                       fpm, swbuf, fft, m0, K2);
        }
    }
}

// Round 21
// 277.504 us; speedup vs baseline: 1.6550x; 1.0552x over previous
//
#include <hip/hip_runtime.h>
#include <hip/hip_bf16.h>
#include <cstddef>
#include <cstdint>

typedef __hip_bfloat16 bf16;
typedef __attribute__((ext_vector_type(8))) short bf16x8;   // 8 bf16 = 4 VGPRs
typedef __attribute__((ext_vector_type(4))) float f32x4;

#define NPT 4096   // points per cloud
#define BB  4      // batch
#define NBR 16     // neighbors (nsample)
#define WD  16     // weightnet output width
#define CDIM 64    // input feature channels
#define MIDD 128   // lin1/lin2 output channels

// async global->LDS, 16B per lane; LDS dest is wave-uniform base + lane*16
#define GLD16(g, l) __builtin_amdgcn_global_load_lds( \
    (const __attribute__((address_space(1))) unsigned int*)(const void*)(g), \
    (__attribute__((address_space(3))) unsigned int*)(void*)(l), 16, 0, 0)

// ---------------------------------------------------------------------------
// Fused prelude: blocks [0,2048) run KNN v8 (round-19 body, verbatim);
// blocks [2048,4864) run prep (transposes + weight splits, verbatim).
// Independent work; prep's BW-bound blocks overlap knn's VALU-bound ones.
// ---------------------------------------------------------------------------
#define KQ     16
#define KSEG   16
#define KCH    64
#define KSTAGE 1024
#define KRING  96

__global__ __launch_bounds__(256)
void pre_kernel(const float* __restrict__ pcA, const float* __restrict__ pcB,
                int* __restrict__ idxAB, int* __restrict__ idxBA,
                const float* __restrict__ feat1, const float* __restrict__ feat2,
                float* __restrict__ p1pm, bf16* __restrict__ p1b,
                float* __restrict__ p2pm, bf16* __restrict__ p2b,
                const float* __restrict__ lin1_w, bf16* __restrict__ b1hi, bf16* __restrict__ b1lo,
                const float* __restrict__ lin2_w, bf16* __restrict__ b2hi, bf16* __restrict__ b2lo)
{
    __shared__ float4 cf[KSTAGE + KSTAGE / KCH];   // skewed
    __shared__ float  pubd[2][KSEG][KQ];
    __shared__ float4 qc[KQ];
    __shared__ float  u16s[KQ];
    __shared__ int    rcnt[KQ];
    __shared__ int    wtot;
    __shared__ int    wl[256];
    __shared__ float  ringd[KQ][KRING + 1];
    __shared__ int    ringi[KQ][KRING + 1];
    __shared__ float  t[32][33];

    const int bid = blockIdx.x;
    const int tid = threadIdx.x;

    if (bid < 2048) {
        // =================== KNN v8 ===================
        const int dir = bid >> 10;            // 0: A->B, 1: B->A
        const int b   = (bid >> 8) & 3;
        const int g   = bid & 255;
        const float* qxyz = dir ? pcB : pcA;
        const float* cxyz = dir ? pcA : pcB;
        int* idx_out      = dir ? idxBA : idxAB;

        const int q = tid & (KQ - 1);
        const int s = tid >> 4;
        const int n = g * KQ + q;

        const float* qp = qxyz + (size_t)b * 3 * NPT;
        const float qx = qp[n], qy = qp[NPT + n], qz = qp[2 * NPT + n];
        const float q2 = fmaf(qx, qx, fmaf(qy, qy, qz * qz));
        const float* c = cxyz + (size_t)b * 3 * NPT;

        if (tid < KQ) rcnt[tid] = 0;
        if (tid == 0) wtot = 0;
        if (s == 0) qc[q] = make_float4(qx, qy, qz, q2);

        float b0 = 3.4e38f, b1 = 3.4e38f;
        int   i0 = 0;
        for (int st = 0; st < NPT; st += KSTAGE) {
            __syncthreads();
            {
                #pragma unroll
                for (int r = 0; r < KSTAGE / 256; ++r) {
                    const int j = r * 256 + tid;
                    const int gg = st + j;
                    const float x = c[gg], y = c[NPT + gg], z = c[2 * NPT + gg];
                    cf[j + (j >> 6)] = make_float4(x, y, z,
                        fmaf(x, x, fmaf(y, y, z * z)));
                }
            }
            __syncthreads();
            const int base = s * (KCH + 1);
            const int gidx = st + s * KCH;
            #pragma unroll 4
            for (int jj = 0; jj < KCH; ++jj) {
                const float4 pv = cf[base + jj];
                const float dot = fmaf(qx, pv.x, fmaf(qy, pv.y, qz * pv.z));
                const float d = q2 + pv.w - 2.f * dot;
                i0 = (d < b0) ? (gidx + jj) : i0;
                const float tt = fmaxf(b0, d);
                b0 = fminf(b0, d);
                b1 = fminf(b1, tt);
            }
        }
        pubd[0][s][q] = b0;
        pubd[1][s][q] = b1;
        __syncthreads();

        {
            float tv[32];
            #pragma unroll
            for (int j = 0; j < 32; ++j) tv[j] = pubd[j >> 4][j & 15][q];
            #pragma unroll
            for (int rep = 0; rep < 2; ++rep) {
                const int j = rep * 16 + s;
                const float vj = pubd[rep][s][q];
                int rank = 0;
                #pragma unroll
                for (int k = 0; k < 32; ++k)
                    rank += (tv[k] < vj || (tv[k] == vj && k < j)) ? 1 : 0;
                if (rank == 15) u16s[q] = vj;
            }
        }
        __syncthreads();

        {
            const float gate = u16s[q];
            if (b0 <= gate) {
                if (b1 > gate) {
                    const int slot = atomicAdd(&rcnt[q], 1);
                    if (slot < KRING) { ringd[q][slot] = b0; ringi[q][slot] = i0; }
                } else {
                    const int u = atomicAdd(&wtot, 1);
                    wl[u] = (q << 4) | s;
                }
            }
        }
        __syncthreads();

        {
            const int W = wtot;
            const int lu = tid & 15;
            for (int u = tid >> 4; u < W; u += 16) {
                const int qq  = wl[u] >> 4;
                const int seg = wl[u] & 15;
                const float4 qv = qc[qq];
                const float gate = u16s[qq];
                #pragma unroll
                for (int ch = 0; ch < 4; ++ch) {
                    const int j = ch * KSTAGE + seg * KCH + lu * 4;
                    const float4 xs = *(const float4*)(c + j);
                    const float4 ys = *(const float4*)(c + NPT + j);
                    const float4 zs = *(const float4*)(c + 2 * NPT + j);
                    const float xv[4] = { xs.x, xs.y, xs.z, xs.w };
                    const float yv[4] = { ys.x, ys.y, ys.z, ys.w };
                    const float zv[4] = { zs.x, zs.y, zs.z, zs.w };
                    #pragma unroll
                    for (int e = 0; e < 4; ++e) {
                        const float p2 = fmaf(xv[e], xv[e], fmaf(yv[e], yv[e], zv[e] * zv[e]));
                        const float dot = fmaf(qv.x, xv[e], fmaf(qv.y, yv[e], qv.z * zv[e]));
                        const float d = qv.w + p2 - 2.f * dot;
                        if (d <= gate) {
                            const int slot = atomicAdd(&rcnt[qq], 1);
                            if (slot < KRING) { ringd[qq][slot] = d; ringi[qq][slot] = j + e; }
                        }
                    }
                }
            }
        }
        __syncthreads();

        {
            const int cnt = min(rcnt[q], KRING);
            int* op = idx_out + ((size_t)b * NPT + n) * NBR;
            for (int e = s; e < cnt; e += KSEG) {
                const float de = ringd[q][e];
                const int   ie = ringi[q][e];
                int rank = 0;
                for (int k = 0; k < cnt; ++k) {
                    const float dk = ringd[q][k];
                    const int   ik = ringi[q][k];
                    rank += (dk < de || (dk == de && ik < ie)) ? 1 : 0;
                }
                if (rank < NBR) op[rank] = ie;
            }
        }
    } else {
        // =================== prep ===================
        const int tx = tid & 31, ty = tid >> 5;
        const int id = bid - 2048;
        if (id < 2048) {
            const int which = id >> 10;
            const int nt = id & 1023;
            const int n0 = (nt & 127) * 32;
            const int c0 = ((nt >> 7) & 1) * 32;
            const int b  = nt >> 8;
            const float* in = which ? feat2 : feat1;
            float* out  = which ? p2pm : p1pm;
            bf16*  outb = which ? p2b  : p1b;
            #pragma unroll
            for (int r = ty; r < 32; r += 8)
                t[r][tx] = in[((size_t)b * CDIM + c0 + r) * NPT + n0 + tx];
            __syncthreads();
            #pragma unroll
            for (int r = ty; r < 32; r += 8) {
                const float v = t[tx][r];
                out [((size_t)b * NPT + n0 + r) * CDIM + c0 + tx] = v;
                outb[((size_t)b * NPT + n0 + r) * CDIM + c0 + tx] = __float2bfloat16(v);
            }
        } else {
            const float* w; bf16 *hi, *lo; int K, k0, o0;
            if (id < 2304) {
                const int id2 = id - 2048;
                w = lin1_w; hi = b1hi; lo = b1lo; K = 2048;
                k0 = (id2 & 63) * 32; o0 = (id2 >> 6) * 32;
            } else {
                const int id2 = id - 2304;
                w = lin2_w; hi = b2hi; lo = b2lo; K = 4096;
                k0 = (id2 & 127) * 32; o0 = (id2 >> 7) * 32;
            }
            #pragma unroll
            for (int r = ty; r < 32; r += 8)
                t[r][tx] = w[(size_t)(k0 + r) * MIDD + o0 + tx];
            __syncthreads();
            #pragma unroll
            for (int r = ty; r < 32; r += 8) {
                const float v = t[tx][r];
                const bf16 h = __float2bfloat16(v);
                const bf16 l2 = __float2bfloat16(v - __bfloat162float(h));
                hi[(size_t)(o0 + r) * K + k0 + tx] = h;
                lo[(size_t)(o0 + r) * K + k0 + tx] = l2;
            }
        }
    }
}

// ---------------------------------------------------------------------------
// Weightnet + aggregation v7 (round-17, unchanged).
// ---------------------------------------------------------------------------
template<int D2, int PTS>
__global__ __launch_bounds__(256)
void agg_kernel(const float* __restrict__ qA, const float* __restrict__ cA,
                const bf16* __restrict__ nbrA, const int* __restrict__ idxA,
                const float* __restrict__ qB, const float* __restrict__ cB,
                const bf16* __restrict__ nbrB, const int* __restrict__ idxB,
                int Msplit,
                const float* __restrict__ w0, const float* __restrict__ b0,
                const float* __restrict__ w1, const float* __restrict__ b1,
                const float* __restrict__ w2, const float* __restrict__ b2,
                bf16* __restrict__ agg, float* __restrict__ swb, int m0)
{
    constexpr int TPP  = 256 / PTS;
    constexpr int ND   = D2 / TPP;      // 2
    constexpr int WSTR = 276;

    __shared__ float wp[248];
    __shared__ int   nb[PTS * NBR];
    __shared__ float wgt[PTS * WSTR];

    const int tid = threadIdx.x;
    const int mbase = m0 + (int)blockIdx.x * PTS;
    const bool second = mbase >= Msplit;
    const int mrow = second ? mbase - Msplit : mbase;
    const float* qxyz   = second ? qB   : qA;
    const float* cxyz   = second ? cB   : cA;
    const bf16*  nbr_b  = second ? nbrB : nbrA;
    const int*   idx    = second ? idxB : idxA;
    const int b = mrow >> 12;
    const int nbase = mrow & (NPT - 1);

    if (tid < 248) {
        float v;
        if      (tid <  24) v = w0[tid];
        else if (tid <  32) v = b0[tid - 24];
        else if (tid <  96) v = w1[tid - 32];
        else if (tid < 104) v = b1[tid - 96];
        else if (tid < 232) v = w2[tid - 104];
        else                v = b2[tid - 232];
        wp[tid] = v;
    }
    if (tid < PTS * NBR)
        nb[tid] = idx[(size_t)mrow * NBR + tid];
    __syncthreads();

    const int p  = tid & (PTS - 1);
    const int dg = tid / PTS;
    const int d0 = dg * ND;

    unsigned int F[NBR];
    {
        const bf16* base = nbr_b + (size_t)b * NPT * D2 + d0;
        #pragma unroll
        for (int k = 0; k < NBR; ++k) {
            const int j = nb[p * NBR + k];
            F[k] = *(const unsigned int*)(base + (size_t)j * D2);
        }
    }

    if (tid < PTS * NBR) {
        const int pp = tid / NBR, k = tid % NBR;
        const int n = nbase + pp;
        const int j = nb[tid];
        const float* q = qxyz + (size_t)b * 3 * NPT;
        const float* c = cxyz + (size_t)b * 3 * NPT;
        const float dx = c[j]           - q[n];
        const float dy = c[NPT + j]     - q[NPT + n];
        const float dz = c[2 * NPT + j] - q[2 * NPT + n];
        float h1[8], h2[8];
        #pragma unroll
        for (int o = 0; o < 8; ++o) {
            float v = wp[24 + o];
            v = fmaf(dx, wp[o], v);
            v = fmaf(dy, wp[8 + o], v);
            v = fmaf(dz, wp[16 + o], v);
            h1[o] = fmaxf(v, 0.f);
        }
        #pragma unroll
        for (int o = 0; o < 8; ++o) {
            float v = wp[96 + o];
            #pragma unroll
            for (int i = 0; i < 8; ++i) v = fmaf(h1[i], wp[32 + i * 8 + o], v);
            h2[o] = fmaxf(v, 0.f);
        }
        #pragma unroll
        for (int o = 0; o < WD; ++o) {
            float v = wp[232 + o];
            #pragma unroll
            for (int i = 0; i < 8; ++i) v = fmaf(h2[i], wp[104 + i * WD + o], v);
            wgt[pp * WSTR + k * WD + o] = fmaxf(v, 0.f);
        }
    }
    __syncthreads();

    if (tid < PTS * 16) {
        const int pp = tid >> 4, w = tid & 15;
        const float* wgp = wgt + pp * WSTR + w;
        float sv = 0.f;
        #pragma unroll
        for (int k = 0; k < NBR; ++k) sv += wgp[k * WD];
        swb[(size_t)((int)blockIdx.x * PTS + pp) * 16 + w] = sv;
    }

    {
        const float* wg = wgt + p * WSTR;
        bf16* aout = agg + ((size_t)((int)blockIdx.x * PTS + p)) * (2 * D2 * WD);
        float acc[ND][16];
        #pragma unroll
        for (int di = 0; di < ND; ++di)
            #pragma unroll
            for (int w = 0; w < 16; ++w) acc[di][w] = 0.f;
        #pragma unroll
        for (int k = 0; k < NBR; ++k) {
            union { unsigned int u; bf16 h[2]; } uf;
            uf.u = F[k];
            float Fv[ND];
            #pragma unroll
            for (int j = 0; j < ND; ++j) Fv[j] = __bfloat162float(uf.h[j]);
            const float4 v0 = *(const float4*)(wg + k * WD);
            const float4 v1 = *(const float4*)(wg + k * WD + 4);
            const float4 v2 = *(const float4*)(wg + k * WD + 8);
            const float4 v3 = *(const float4*)(wg + k * WD + 12);
            float w16[16];
            w16[0]  = v0.x; w16[1]  = v0.y; w16[2]  = v0.z; w16[3]  = v0.w;
            w16[4]  = v1.x; w16[5]  = v1.y; w16[6]  = v1.z; w16[7]  = v1.w;
            w16[8]  = v2.x; w16[9]  = v2.y; w16[10] = v2.z; w16[11] = v2.w;
            w16[12] = v3.x; w16[13] = v3.y; w16[14] = v3.z; w16[15] = v3.w;
            #pragma unroll
            for (int di = 0; di < ND; ++di)
                #pragma unroll
                for (int w = 0; w < 16; ++w)
                    acc[di][w] = fmaf(Fv[di], w16[w], acc[di][w]);
        }
        #pragma unroll
        for (int di = 0; di < ND; ++di) {
            union { bf16 h[16]; uint4 q[2]; } pk;
            #pragma unroll
            for (int w = 0; w < 16; ++w) pk.h[w] = __float2bfloat16(acc[di][w]);
            bf16* dst = aout + (D2 + d0 + di) * WD;
            *(uint4*)dst       = pk.q[0];
            *(uint4*)(dst + 8) = pk.q[1];
        }
    }
}

// ---------------------------------------------------------------------------
// MFMA GEMM k64 (templated BM): BK=64, 8-chunk swizzle sch = ch ^ (row&7)
// (matched involution; read bank-quads sweep all 8 per 8 rows). Own-half
// (kt < nk/2): d = kt*4 + (sch>>1), w0 = (sch&1)*8 — round-20-verified
// algebra. MFMA order k-ascending, hi-then-lo per nf -> bit-identical.
// BM=64: A tile = 2 staging rounds (2 sww sets); BM=32: 1 round.
// ---------------------------------------------------------------------------
template<int BM>
__global__ __launch_bounds__(256)
void gemm_mfma_k64(const bf16* __restrict__ A, const bf16* __restrict__ Bhi,
                   const bf16* __restrict__ Blo, const float* __restrict__ bias,
                   const float* __restrict__ ownf, const float* __restrict__ swb,
                   float* __restrict__ out_t, float* __restrict__ out_pm,
                   bf16* __restrict__ out_pmb, int m0, int K)
{
    constexpr int AE   = BM * 64;
    constexpr int BT   = 128 * 64;
    constexpr int BUFE = AE + 2 * BT;
    constexpr int MF   = BM / 32;
    constexpr int RA   = BM * 8 / 256;     // A staging rounds (1 or 2)
    __shared__ __align__(16) char smem[2 * BUFE * 2];
    bf16* lds = (bf16*)smem;

    const int tid  = threadIdx.x;
    const int w    = tid >> 6;
    const int lane = tid & 63;
    const int wr   = w >> 1, wc = w & 1;
    const int mb   = (int)blockIdx.x * BM;
    const int gK   = lane >> 4;
    const int rL   = lane & 15;
    const int D2v  = K / 32;

    // A staging constants per round
    int rowA[RA], schA[RA];
    float sww[RA][8];
    const float* ownrow_g[RA];
    #pragma unroll
    for (int r = 0; r < RA; ++r) {
        const int slot = r * 256 + tid;
        rowA[r] = slot >> 3;
        const int ch = slot & 7;
        schA[r] = ch ^ (rowA[r] & 7);
        const int w0 = (schA[r] & 1) * 8;
        const float* sp = swb + (size_t)(mb + rowA[r]) * 16 + w0;
        const float4 a = *(const float4*)sp;
        const float4 b2 = *(const float4*)(sp + 4);
        sww[r][0] = a.x;  sww[r][1] = a.y;  sww[r][2] = a.z;  sww[r][3] = a.w;
        sww[r][4] = b2.x; sww[r][5] = b2.y; sww[r][6] = b2.z; sww[r][7] = b2.w;
        ownrow_g[r] = ownf + (size_t)(m0 + mb + rowA[r]) * D2v;
    }

    f32x4 acc[MF][4];
    #pragma unroll
    for (int i = 0; i < MF; ++i)
        #pragma unroll
        for (int j = 0; j < 4; ++j) acc[i][j] = (f32x4)0.f;

    const int nk = K / 64;
    const int nkOwn = nk / 2;

    auto stage = [&](int buf, int kt) {
        const int kb = kt * 64;
        const int bufo = buf * BUFE;
        if (kt < nkOwn) {
            #pragma unroll
            for (int r = 0; r < RA; ++r) {
                const int d = kt * 4 + (schA[r] >> 1);
                const float f = ownrow_g[r][d];
                union { bf16 h[8]; uint4 q; } pk;
                #pragma unroll
                for (int j = 0; j < 8; ++j) pk.h[j] = __float2bfloat16(f * sww[r][j]);
                *(uint4*)(lds + bufo + (r * 256 + tid) * 8) = pk.q;
            }
        } else {
            #pragma unroll
            for (int r = 0; r < RA; ++r)
                GLD16(A + (size_t)(mb + rowA[r]) * K + kb + (schA[r] << 3),
                      lds + bufo + ((r * 256 + w * 64) << 3));
        }
        #pragma unroll
        for (int i = 0; i < 4; ++i) {   // B tiles: 128 rows x 8 chunks
            const int s2 = i * 256 + tid;
            const int row = s2 >> 3, ch = s2 & 7;
            const int sch = ch ^ (row & 7);
            const int wb = (i * 256 + w * 64) << 3;
            GLD16(Bhi + (size_t)row * K + kb + (sch << 3), lds + bufo + AE + wb);
            GLD16(Blo + (size_t)row * K + kb + (sch << 3), lds + bufo + AE + BT + wb);
        }
    };

    stage(0, 0);
    __syncthreads();

    for (int kt = 0; kt < nk; ++kt) {
        const int cur = kt & 1;
        if (kt + 1 < nk) stage(cur ^ 1, kt + 1);

        const bf16* la  = lds + cur * BUFE;
        const bf16* lbh = la + AE;
        const bf16* lbl = la + AE + BT;

        #pragma unroll
        for (int kk2 = 0; kk2 < 2; ++kk2) {
            const int cc = gK + kk2 * 4;
            bf16x8 af[MF], bh[4], bl[4];
            #pragma unroll
            for (int mf = 0; mf < MF; ++mf) {
                const int row = wr * (BM / 2) + mf * 16 + rL;
                af[mf] = *(const bf16x8*)(la + row * 64 + ((cc ^ (row & 7)) << 3));
            }
            #pragma unroll
            for (int nf = 0; nf < 4; ++nf) {
                const int col = wc * 64 + nf * 16 + rL;
                const int off = col * 64 + ((cc ^ (col & 7)) << 3);
                bh[nf] = *(const bf16x8*)(lbh + off);
                bl[nf] = *(const bf16x8*)(lbl + off);
            }
            #pragma unroll
            for (int mf = 0; mf < MF; ++mf)
                #pragma unroll
                for (int nf = 0; nf < 4; ++nf) {
                    acc[mf][nf] = __builtin_amdgcn_mfma_f32_16x16x32_bf16(af[mf], bh[nf], acc[mf][nf], 0, 0, 0);
                    acc[mf][nf] = __builtin_amdgcn_mfma_f32_16x16x32_bf16(af[mf], bl[nf], acc[mf][nf], 0, 0, 0);
                }
        }
        __syncthreads();
    }

    float (*tile)[133] = (float(*)[133])smem;
    #pragma unroll
    for (int mf = 0; mf < MF; ++mf)
        #pragma unroll
        for (int nf = 0; nf < 4; ++nf) {
            const int col = wc * 64 + nf * 16 + rL;
            const float bs = bias[col];
            #pragma unroll
            for (int qq = 0; qq < 4; ++qq) {
                const int rrow = wr * (BM / 2) + mf * 16 + gK * 4 + qq;
                const float v = acc[mf][nf][qq] + bs;
                tile[rrow][col] = v > 0.f ? v : 0.1f * v;
            }
        }
    __syncthreads();

    const int mrow = m0 + mb;
    const int b = mrow >> 12, n0 = mrow & (NPT - 1);
    for (int e = tid; e < BM * MIDD; e += 256) {
        const int o = e / BM, i = e % BM;
        out_t[((size_t)b * MIDD + o) * NPT + n0 + i] = tile[i][o];
    }
    if (out_pm) {
        for (int e = tid; e < BM * MIDD; e += 256) {
            const int i = e >> 7, o = e & 127;
            const float v = tile[i][o];
            out_pm [(size_t)(mrow + i) * MIDD + o] = v;
            out_pmb[(size_t)(mrow + i) * MIDD + o] = __float2bfloat16(v);
        }
    }
}

// ---------------------------------------------------------------------------
extern "C" void kernel_launch(void* const* d_in, const int* in_sizes, int n_in,
                              void* d_out, int out_size, void* d_ws, size_t ws_size,
                              hipStream_t stream)
{
    (void)in_sizes; (void)n_in; (void)out_size;
    const float* pc1    = (const float*)d_in[0];
    const float* pc2    = (const float*)d_in[1];
    const float* feat1  = (const float*)d_in[2];
    const float* feat2  = (const float*)d_in[3];
    const float* wn1_w0 = (const float*)d_in[4];
    const float* wn1_b0 = (const float*)d_in[5];
    const float* wn1_w1 = (const float*)d_in[6];
    const float* wn1_b1 = (const float*)d_in[7];
    const float* wn1_w2 = (const float*)d_in[8];
    const float* wn1_b2 = (const float*)d_in[9];
    const float* lin1_w = (const float*)d_in[10];
    const float* lin1_b = (const float*)d_in[11];
    const float* wn2_w0 = (const float*)d_in[12];
    const float* wn2_b0 = (const float*)d_in[13];
    const float* wn2_w1 = (const float*)d_in[14];
    const float* wn2_b1 = (const float*)d_in[15];
    const float* wn2_w2 = (const float*)d_in[16];
    const float* wn2_b2 = (const float*)d_in[17];
    const float* lin2_w = (const float*)d_in[18];
    const float* lin2_b = (const float*)d_in[19];
    float* out = (float*)d_out;

    const int M  = BB * NPT;
    const int M2 = 2 * M;
    const int K1 = 2 * CDIM * WD;     // 2048
    const int K2 = 2 * MIDD * WD;     // 4096

    char* ws = (char*)d_ws;
    float* p1pm = (float*)ws;
    float* p2pm = p1pm + (size_t)M * CDIM;
    float* fpm  = p2pm + (size_t)M * CDIM;
    bf16*  p1b  = (bf16*)(fpm + (size_t)M2 * MIDD);
    bf16*  p2b  = p1b + (size_t)M * CDIM;
    bf16*  fb   = p2b + (size_t)M * CDIM;
    int* idx12  = (int*)(fb + (size_t)M2 * MIDD);
    int* idx21  = idx12 + (size_t)M * NBR;
    bf16* b1hi  = (bf16*)(idx21 + (size_t)M * NBR);
    bf16* b1lo  = b1hi + (size_t)MIDD * K1;
    bf16* b2hi  = b1lo + (size_t)MIDD * K1;
    bf16* b2lo  = b2hi + (size_t)MIDD * K2;
    float* swbuf = (float*)(b2lo + (size_t)MIDD * K2);
    bf16* aggbuf = (bf16*)(swbuf + (size_t)(M2 + 64) * 16);
    const size_t used = (size_t)((char*)aggbuf - ws);
    const size_t avail = ws_size > used ? ws_size - used : 0;

    float* f1t = out;
    float* fft = out + 2 * (size_t)BB * MIDD * NPT;

    pre_kernel<<<2048 + 2816, 256, 0, stream>>>(
        pc1, pc2, idx12, idx21,
        feat1, feat2, p1pm, p1b, p2pm, p2b,
        lin1_w, b1hi, b1lo, lin2_w, b2hi, b2lo);

    auto chunk_rows = [&](int K) -> int {
        long rows = (long)(avail / ((size_t)K * sizeof(bf16)));
        int cm = (int)(rows > M2 ? M2 : rows) & ~127;
        if (cm < 128) cm = 128;
        return cm;
    };

    {   // cross 1 + cross 2 merged (K = 2048); BM=64, BK=64
        const int CMr = chunk_rows(K1);
        for (int m0 = 0; m0 < M2; m0 += CMr) {
            const int cm = (M2 - m0 < CMr) ? (M2 - m0) : CMr;
            agg_kernel<CDIM, 8><<<cm / 8, 256, 0, stream>>>(
                pc1, pc2, p2b, idx12,
                pc2, pc1, p1b, idx21, M,
                wn1_w0, wn1_b0, wn1_w1, wn1_b1, wn1_w2, wn1_b2,
                aggbuf, swbuf, m0);
            gemm_mfma_k64<64><<<cm / 64, 256, 0, stream>>>(aggbuf, b1hi, b1lo, lin1_b,
                                                           p1pm, swbuf,
                                                           f1t, fpm, fb, m0, K1);
        }
    }
    {   // cross 3 (K = 4096); BM=32, BK=64
        const int CMr = chunk_rows(K2);
        for (int m0 = 0; m0 < M; m0 += CMr) {
            const int cm = (M - m0 < CMr) ? (M - m0) : CMr;
            agg_kernel<MIDD, 4><<<cm / 4, 256, 0, stream>>>(
                pc1, pc2, fb + (size_t)M * MIDD, idx12,
                nullptr, nullptr, nullptr, nullptr, M2,
                wn2_w0, wn2_b0, wn2_w1, wn2_b1, wn2_w2, wn2_b2,
                aggbuf, swbuf, m0);
            gemm_mfma_k64<32><<<cm / 32, 256, 0, stream>>>(aggbuf, b2hi, b2lo, lin2_b,
                                                           fpm, swbuf,
                                                           fft, nullptr, nullptr, m0, K2);
        }
    }
}

// Round 22
// 268.995 us; speedup vs baseline: 1.7073x; 1.0316x over previous
//
#include <hip/hip_runtime.h>
#include <hip/hip_bf16.h>
#include <cstddef>
#include <cstdint>

typedef __hip_bfloat16 bf16;
typedef __attribute__((ext_vector_type(8))) short bf16x8;   // 8 bf16 = 4 VGPRs
typedef __attribute__((ext_vector_type(4))) float f32x4;

#define NPT 4096   // points per cloud
#define BB  4      // batch
#define NBR 16     // neighbors (nsample)
#define WD  16     // weightnet output width
#define CDIM 64    // input feature channels
#define MIDD 128   // lin1/lin2 output channels

// async global->LDS, 16B per lane; LDS dest is wave-uniform base + lane*16
#define GLD16(g, l) __builtin_amdgcn_global_load_lds( \
    (const __attribute__((address_space(1))) unsigned int*)(const void*)(g), \
    (__attribute__((address_space(3))) unsigned int*)(void*)(l), 16, 0, 0)

// ---------------------------------------------------------------------------
// Fused prelude: blocks [0,2048) run KNN v8; blocks [2048,4864) run prep.
// ---------------------------------------------------------------------------
#define KQ     16
#define KSEG   16
#define KCH    64
#define KSTAGE 1024
#define KRING  96

__global__ __launch_bounds__(256)
void pre_kernel(const float* __restrict__ pcA, const float* __restrict__ pcB,
                int* __restrict__ idxAB, int* __restrict__ idxBA,
                const float* __restrict__ feat1, const float* __restrict__ feat2,
                float* __restrict__ p1pm, bf16* __restrict__ p1b,
                float* __restrict__ p2pm, bf16* __restrict__ p2b,
                const float* __restrict__ lin1_w, bf16* __restrict__ b1hi, bf16* __restrict__ b1lo,
                const float* __restrict__ lin2_w, bf16* __restrict__ b2hi, bf16* __restrict__ b2lo)
{
    __shared__ float4 cf[KSTAGE + KSTAGE / KCH];   // skewed
    __shared__ float  pubd[2][KSEG][KQ];
    __shared__ float4 qc[KQ];
    __shared__ float  u16s[KQ];
    __shared__ int    rcnt[KQ];
    __shared__ int    wtot;
    __shared__ int    wl[256];
    __shared__ float  ringd[KQ][KRING + 1];
    __shared__ int    ringi[KQ][KRING + 1];
    __shared__ float  t[32][33];

    const int bid = blockIdx.x;
    const int tid = threadIdx.x;

    if (bid < 2048) {
        // =================== KNN v8 ===================
        const int dir = bid >> 10;
        const int b   = (bid >> 8) & 3;
        const int g   = bid & 255;
        const float* qxyz = dir ? pcB : pcA;
        const float* cxyz = dir ? pcA : pcB;
        int* idx_out      = dir ? idxBA : idxAB;

        const int q = tid & (KQ - 1);
        const int s = tid >> 4;
        const int n = g * KQ + q;

        const float* qp = qxyz + (size_t)b * 3 * NPT;
        const float qx = qp[n], qy = qp[NPT + n], qz = qp[2 * NPT + n];
        const float q2 = fmaf(qx, qx, fmaf(qy, qy, qz * qz));
        const float* c = cxyz + (size_t)b * 3 * NPT;

        if (tid < KQ) rcnt[tid] = 0;
        if (tid == 0) wtot = 0;
        if (s == 0) qc[q] = make_float4(qx, qy, qz, q2);

        float b0 = 3.4e38f, b1 = 3.4e38f;
        int   i0 = 0;
        for (int st = 0; st < NPT; st += KSTAGE) {
            __syncthreads();
            {
                #pragma unroll
                for (int r = 0; r < KSTAGE / 256; ++r) {
                    const int j = r * 256 + tid;
                    const int gg = st + j;
                    const float x = c[gg], y = c[NPT + gg], z = c[2 * NPT + gg];
                    cf[j + (j >> 6)] = make_float4(x, y, z,
                        fmaf(x, x, fmaf(y, y, z * z)));
                }
            }
            __syncthreads();
            const int base = s * (KCH + 1);
            const int gidx = st + s * KCH;
            #pragma unroll 4
            for (int jj = 0; jj < KCH; ++jj) {
                const float4 pv = cf[base + jj];
                const float dot = fmaf(qx, pv.x, fmaf(qy, pv.y, qz * pv.z));
                const float d = q2 + pv.w - 2.f * dot;
                i0 = (d < b0) ? (gidx + jj) : i0;
                const float tt = fmaxf(b0, d);
                b0 = fminf(b0, d);
                b1 = fminf(b1, tt);
            }
        }
        pubd[0][s][q] = b0;
        pubd[1][s][q] = b1;
        __syncthreads();

        {
            float tv[32];
            #pragma unroll
            for (int j = 0; j < 32; ++j) tv[j] = pubd[j >> 4][j & 15][q];
            #pragma unroll
            for (int rep = 0; rep < 2; ++rep) {
                const int j = rep * 16 + s;
                const float vj = pubd[rep][s][q];
                int rank = 0;
                #pragma unroll
                for (int k = 0; k < 32; ++k)
                    rank += (tv[k] < vj || (tv[k] == vj && k < j)) ? 1 : 0;
                if (rank == 15) u16s[q] = vj;
            }
        }
        __syncthreads();

        {
            const float gate = u16s[q];
            if (b0 <= gate) {
                if (b1 > gate) {
                    const int slot = atomicAdd(&rcnt[q], 1);
                    if (slot < KRING) { ringd[q][slot] = b0; ringi[q][slot] = i0; }
                } else {
                    const int u = atomicAdd(&wtot, 1);
                    wl[u] = (q << 4) | s;
                }
            }
        }
        __syncthreads();

        {
            const int W = wtot;
            const int lu = tid & 15;
            for (int u = tid >> 4; u < W; u += 16) {
                const int qq  = wl[u] >> 4;
                const int seg = wl[u] & 15;
                const float4 qv = qc[qq];
                const float gate = u16s[qq];
                #pragma unroll
                for (int ch = 0; ch < 4; ++ch) {
                    const int j = ch * KSTAGE + seg * KCH + lu * 4;
                    const float4 xs = *(const float4*)(c + j);
                    const float4 ys = *(const float4*)(c + NPT + j);
                    const float4 zs = *(const float4*)(c + 2 * NPT + j);
                    const float xv[4] = { xs.x, xs.y, xs.z, xs.w };
                    const float yv[4] = { ys.x, ys.y, ys.z, ys.w };
                    const float zv[4] = { zs.x, zs.y, zs.z, zs.w };
                    #pragma unroll
                    for (int e = 0; e < 4; ++e) {
                        const float p2 = fmaf(xv[e], xv[e], fmaf(yv[e], yv[e], zv[e] * zv[e]));
                        const float dot = fmaf(qv.x, xv[e], fmaf(qv.y, yv[e], qv.z * zv[e]));
                        const float d = qv.w + p2 - 2.f * dot;
                        if (d <= gate) {
                            const int slot = atomicAdd(&rcnt[qq], 1);
                            if (slot < KRING) { ringd[qq][slot] = d; ringi[qq][slot] = j + e; }
                        }
                    }
                }
            }
        }
        __syncthreads();

        {
            const int cnt = min(rcnt[q], KRING);
            int* op = idx_out + ((size_t)b * NPT + n) * NBR;
            for (int e = s; e < cnt; e += KSEG) {
                const float de = ringd[q][e];
                const int   ie = ringi[q][e];
                int rank = 0;
                for (int k = 0; k < cnt; ++k) {
                    const float dk = ringd[q][k];
                    const int   ik = ringi[q][k];
                    rank += (dk < de || (dk == de && ik < ie)) ? 1 : 0;
                }
                if (rank < NBR) op[rank] = ie;
            }
        }
    } else {
        // =================== prep ===================
        const int tx = tid & 31, ty = tid >> 5;
        const int id = bid - 2048;
        if (id < 2048) {
            const int which = id >> 10;
            const int nt = id & 1023;
            const int n0 = (nt & 127) * 32;
            const int c0 = ((nt >> 7) & 1) * 32;
            const int b  = nt >> 8;
            const float* in = which ? feat2 : feat1;
            float* out  = which ? p2pm : p1pm;
            bf16*  outb = which ? p2b  : p1b;
            #pragma unroll
            for (int r = ty; r < 32; r += 8)
                t[r][tx] = in[((size_t)b * CDIM + c0 + r) * NPT + n0 + tx];
            __syncthreads();
            #pragma unroll
            for (int r = ty; r < 32; r += 8) {
                const float v = t[tx][r];
                out [((size_t)b * NPT + n0 + r) * CDIM + c0 + tx] = v;
                outb[((size_t)b * NPT + n0 + r) * CDIM + c0 + tx] = __float2bfloat16(v);
            }
        } else {
            const float* w; bf16 *hi, *lo; int K, k0, o0;
            if (id < 2304) {
                const int id2 = id - 2048;
                w = lin1_w; hi = b1hi; lo = b1lo; K = 2048;
                k0 = (id2 & 63) * 32; o0 = (id2 >> 6) * 32;
            } else {
                const int id2 = id - 2304;
                w = lin2_w; hi = b2hi; lo = b2lo; K = 4096;
                k0 = (id2 & 127) * 32; o0 = (id2 >> 7) * 32;
            }
            #pragma unroll
            for (int r = ty; r < 32; r += 8)
                t[r][tx] = w[(size_t)(k0 + r) * MIDD + o0 + tx];
            __syncthreads();
            #pragma unroll
            for (int r = ty; r < 32; r += 8) {
                const float v = t[tx][r];
                const bf16 h = __float2bfloat16(v);
                const bf16 l2 = __float2bfloat16(v - __bfloat162float(h));
                hi[(size_t)(o0 + r) * K + k0 + tx] = h;
                lo[(size_t)(o0 + r) * K + k0 + tx] = l2;
            }
        }
    }
}

// ---------------------------------------------------------------------------
// Weightnet + aggregation v8: same math as v7, thread REMAP for the gather /
// accumulate phase: p = tid / TPP, dg = tid % TPP (was p = tid & (PTS-1)).
// Consecutive lanes now share a row: gather loads become 2x128B contiguous
// transactions per wave (was 8x32B), wgt LDS reads become same-address
// broadcasts, output stores become one contiguous span per wave. Pure
// thread permutation — per-(p,d,w) values/order unchanged -> bit-identical.
// ---------------------------------------------------------------------------
template<int D2, int PTS>
__global__ __launch_bounds__(256)
void agg_kernel(const float* __restrict__ qA, const float* __restrict__ cA,
                const bf16* __restrict__ nbrA, const int* __restrict__ idxA,
                const float* __restrict__ qB, const float* __restrict__ cB,
                const bf16* __restrict__ nbrB, const int* __restrict__ idxB,
                int Msplit,
                const float* __restrict__ w0, const float* __restrict__ b0,
                const float* __restrict__ w1, const float* __restrict__ b1,
                const float* __restrict__ w2, const float* __restrict__ b2,
                bf16* __restrict__ agg, float* __restrict__ swb, int m0)
{
    constexpr int TPP  = 256 / PTS;
    constexpr int ND   = D2 / TPP;      // 2
    constexpr int WSTR = 276;

    __shared__ float wp[248];
    __shared__ int   nb[PTS * NBR];
    __shared__ float wgt[PTS * WSTR];

    const int tid = threadIdx.x;
    const int mbase = m0 + (int)blockIdx.x * PTS;
    const bool second = mbase >= Msplit;
    const int mrow = second ? mbase - Msplit : mbase;
    const float* qxyz   = second ? qB   : qA;
    const float* cxyz   = second ? cB   : cA;
    const bf16*  nbr_b  = second ? nbrB : nbrA;
    const int*   idx    = second ? idxB : idxA;
    const int b = mrow >> 12;
    const int nbase = mrow & (NPT - 1);

    if (tid < 248) {
        float v;
        if      (tid <  24) v = w0[tid];
        else if (tid <  32) v = b0[tid - 24];
        else if (tid <  96) v = w1[tid - 32];
        else if (tid < 104) v = b1[tid - 96];
        else if (tid < 232) v = w2[tid - 104];
        else                v = b2[tid - 232];
        wp[tid] = v;
    }
    if (tid < PTS * NBR)
        nb[tid] = idx[(size_t)mrow * NBR + tid];
    __syncthreads();

    // remapped: lanes within a TPP-group share the row p
    const int p  = tid / TPP;
    const int dg = tid % TPP;
    const int d0 = dg * ND;

    unsigned int F[NBR];
    {
        const bf16* base = nbr_b + (size_t)b * NPT * D2 + d0;
        #pragma unroll
        for (int k = 0; k < NBR; ++k) {
            const int j = nb[p * NBR + k];
            F[k] = *(const unsigned int*)(base + (size_t)j * D2);
        }
    }

    if (tid < PTS * NBR) {
        const int pp = tid / NBR, k = tid % NBR;
        const int n = nbase + pp;
        const int j = nb[tid];
        const float* q = qxyz + (size_t)b * 3 * NPT;
        const float* c = cxyz + (size_t)b * 3 * NPT;
        const float dx = c[j]           - q[n];
        const float dy = c[NPT + j]     - q[NPT + n];
        const float dz = c[2 * NPT + j] - q[2 * NPT + n];
        float h1[8], h2[8];
        #pragma unroll
        for (int o = 0; o < 8; ++o) {
            float v = wp[24 + o];
            v = fmaf(dx, wp[o], v);
            v = fmaf(dy, wp[8 + o], v);
            v = fmaf(dz, wp[16 + o], v);
            h1[o] = fmaxf(v, 0.f);
        }
        #pragma unroll
        for (int o = 0; o < 8; ++o) {
            float v = wp[96 + o];
            #pragma unroll
            for (int i = 0; i < 8; ++i) v = fmaf(h1[i], wp[32 + i * 8 + o], v);
            h2[o] = fmaxf(v, 0.f);
        }
        #pragma unroll
        for (int o = 0; o < WD; ++o) {
            float v = wp[232 + o];
            #pragma unroll
            for (int i = 0; i < 8; ++i) v = fmaf(h2[i], wp[104 + i * WD + o], v);
            wgt[pp * WSTR + k * WD + o] = fmaxf(v, 0.f);
        }
    }
    __syncthreads();

    if (tid < PTS * 16) {
        const int pp = tid >> 4, w = tid & 15;
        const float* wgp = wgt + pp * WSTR + w;
        float sv = 0.f;
        #pragma unroll
        for (int k = 0; k < NBR; ++k) sv += wgp[k * WD];
        swb[(size_t)((int)blockIdx.x * PTS + pp) * 16 + w] = sv;
    }

    {
        const float* wg = wgt + p * WSTR;
        bf16* aout = agg + ((size_t)((int)blockIdx.x * PTS + p)) * (2 * D2 * WD);
        float acc[ND][16];
        #pragma unroll
        for (int di = 0; di < ND; ++di)
            #pragma unroll
            for (int w = 0; w < 16; ++w) acc[di][w] = 0.f;
        #pragma unroll
        for (int k = 0; k < NBR; ++k) {
            union { unsigned int u; bf16 h[2]; } uf;
            uf.u = F[k];
            float Fv[ND];
            #pragma unroll
            for (int j = 0; j < ND; ++j) Fv[j] = __bfloat162float(uf.h[j]);
            const float4 v0 = *(const float4*)(wg + k * WD);
            const float4 v1 = *(const float4*)(wg + k * WD + 4);
            const float4 v2 = *(const float4*)(wg + k * WD + 8);
            const float4 v3 = *(const float4*)(wg + k * WD + 12);
            float w16[16];
            w16[0]  = v0.x; w16[1]  = v0.y; w16[2]  = v0.z; w16[3]  = v0.w;
            w16[4]  = v1.x; w16[5]  = v1.y; w16[6]  = v1.z; w16[7]  = v1.w;
            w16[8]  = v2.x; w16[9]  = v2.y; w16[10] = v2.z; w16[11] = v2.w;
            w16[12] = v3.x; w16[13] = v3.y; w16[14] = v3.z; w16[15] = v3.w;
            #pragma unroll
            for (int di = 0; di < ND; ++di)
                #pragma unroll
                for (int w = 0; w < 16; ++w)
                    acc[di][w] = fmaf(Fv[di], w16[w], acc[di][w]);
        }
        #pragma unroll
        for (int di = 0; di < ND; ++di) {
            union { bf16 h[16]; uint4 q[2]; } pk;
            #pragma unroll
            for (int w = 0; w < 16; ++w) pk.h[w] = __float2bfloat16(acc[di][w]);
            bf16* dst = aout + (D2 + d0 + di) * WD;
            *(uint4*)dst       = pk.q[0];
            *(uint4*)(dst + 8) = pk.q[1];
        }
    }
}

// ---------------------------------------------------------------------------
// MFMA GEMM k64 (round-21, unchanged): templated BM, BK=64, 8-chunk swizzle,
// own-half reconstruction.
// ---------------------------------------------------------------------------
template<int BM>
__global__ __launch_bounds__(256)
void gemm_mfma_k64(const bf16* __restrict__ A, const bf16* __restrict__ Bhi,
                   const bf16* __restrict__ Blo, const float* __restrict__ bias,
                   const float* __restrict__ ownf, const float* __restrict__ swb,
                   float* __restrict__ out_t, float* __restrict__ out_pm,
                   bf16* __restrict__ out_pmb, int m0, int K)
{
    constexpr int AE   = BM * 64;
    constexpr int BT   = 128 * 64;
    constexpr int BUFE = AE + 2 * BT;
    constexpr int MF   = BM / 32;
    constexpr int RA   = BM * 8 / 256;
    __shared__ __align__(16) char smem[2 * BUFE * 2];
    bf16* lds = (bf16*)smem;

    const int tid  = threadIdx.x;
    const int w    = tid >> 6;
    const int lane = tid & 63;
    const int wr   = w >> 1, wc = w & 1;
    const int mb   = (int)blockIdx.x * BM;
    const int gK   = lane >> 4;
    const int rL   = lane & 15;
    const int D2v  = K / 32;

    int rowA[RA], schA[RA];
    float sww[RA][8];
    const float* ownrow_g[RA];
    #pragma unroll
    for (int r = 0; r < RA; ++r) {
        const int slot = r * 256 + tid;
        rowA[r] = slot >> 3;
        const int ch = slot & 7;
        schA[r] = ch ^ (rowA[r] & 7);
        const int w0 = (schA[r] & 1) * 8;
        const float* sp = swb + (size_t)(mb + rowA[r]) * 16 + w0;
        const float4 a = *(const float4*)sp;
        const float4 b2 = *(const float4*)(sp + 4);
        sww[r][0] = a.x;  sww[r][1] = a.y;  sww[r][2] = a.z;  sww[r][3] = a.w;
        sww[r][4] = b2.x; sww[r][5] = b2.y; sww[r][6] = b2.z; sww[r][7] = b2.w;
        ownrow_g[r] = ownf + (size_t)(m0 + mb + rowA[r]) * D2v;
    }

    f32x4 acc[MF][4];
    #pragma unroll
    for (int i = 0; i < MF; ++i)
        #pragma unroll
        for (int j = 0; j < 4; ++j) acc[i][j] = (f32x4)0.f;

    const int nk = K / 64;
    const int nkOwn = nk / 2;

    auto stage = [&](int buf, int kt) {
        const int kb = kt * 64;
        const int bufo = buf * BUFE;
        if (kt < nkOwn) {
            #pragma unroll
            for (int r = 0; r < RA; ++r) {
                const int d = kt * 4 + (schA[r] >> 1);
                const float f = ownrow_g[r][d];
                union { bf16 h[8]; uint4 q; } pk;
                #pragma unroll
                for (int j = 0; j < 8; ++j) pk.h[j] = __float2bfloat16(f * sww[r][j]);
                *(uint4*)(lds + bufo + (r * 256 + tid) * 8) = pk.q;
            }
        } else {
            #pragma unroll
            for (int r = 0; r < RA; ++r)
                GLD16(A + (size_t)(mb + rowA[r]) * K + kb + (schA[r] << 3),
                      lds + bufo + ((r * 256 + w * 64) << 3));
        }
        #pragma unroll
        for (int i = 0; i < 4; ++i) {
            const int s2 = i * 256 + tid;
            const int row = s2 >> 3, ch = s2 & 7;
            const int sch = ch ^ (row & 7);
            const int wb = (i * 256 + w * 64) << 3;
            GLD16(Bhi + (size_t)row * K + kb + (sch << 3), lds + bufo + AE + wb);
            GLD16(Blo + (size_t)row * K + kb + (sch << 3), lds + bufo + AE + BT + wb);
        }
    };

    stage(0, 0);
    __syncthreads();

    for (int kt = 0; kt < nk; ++kt) {
        const int cur = kt & 1;
        if (kt + 1 < nk) stage(cur ^ 1, kt + 1);

        const bf16* la  = lds + cur * BUFE;
        const bf16* lbh = la + AE;
        const bf16* lbl = la + AE + BT;

        #pragma unroll
        for (int kk2 = 0; kk2 < 2; ++kk2) {
            const int cc = gK + kk2 * 4;
            bf16x8 af[MF], bh[4], bl[4];
            #pragma unroll
            for (int mf = 0; mf < MF; ++mf) {
                const int row = wr * (BM / 2) + mf * 16 + rL;
                af[mf] = *(const bf16x8*)(la + row * 64 + ((cc ^ (row & 7)) << 3));
            }
            #pragma unroll
            for (int nf = 0; nf < 4; ++nf) {
                const int col = wc * 64 + nf * 16 + rL;
                const int off = col * 64 + ((cc ^ (col & 7)) << 3);
                bh[nf] = *(const bf16x8*)(lbh + off);
                bl[nf] = *(const bf16x8*)(lbl + off);
            }
            #pragma unroll
            for (int mf = 0; mf < MF; ++mf)
                #pragma unroll
                for (int nf = 0; nf < 4; ++nf) {
                    acc[mf][nf] = __builtin_amdgcn_mfma_f32_16x16x32_bf16(af[mf], bh[nf], acc[mf][nf], 0, 0, 0);
                    acc[mf][nf] = __builtin_amdgcn_mfma_f32_16x16x32_bf16(af[mf], bl[nf], acc[mf][nf], 0, 0, 0);
                }
        }
        __syncthreads();
    }

    float (*tile)[133] = (float(*)[133])smem;
    #pragma unroll
    for (int mf = 0; mf < MF; ++mf)
        #pragma unroll
        for (int nf = 0; nf < 4; ++nf) {
            const int col = wc * 64 + nf * 16 + rL;
            const float bs = bias[col];
            #pragma unroll
            for (int qq = 0; qq < 4; ++qq) {
                const int rrow = wr * (BM / 2) + mf * 16 + gK * 4 + qq;
                const float v = acc[mf][nf][qq] + bs;
                tile[rrow][col] = v > 0.f ? v : 0.1f * v;
            }
        }
    __syncthreads();

    const int mrow = m0 + mb;
    const int b = mrow >> 12, n0 = mrow & (NPT - 1);
    for (int e = tid; e < BM * MIDD; e += 256) {
        const int o = e / BM, i = e % BM;
        out_t[((size_t)b * MIDD + o) * NPT + n0 + i] = tile[i][o];
    }
    if (out_pm) {
        for (int e = tid; e < BM * MIDD; e += 256) {
            const int i = e >> 7, o = e & 127;
            const float v = tile[i][o];
            out_pm [(size_t)(mrow + i) * MIDD + o] = v;
            out_pmb[(size_t)(mrow + i) * MIDD + o] = __float2bfloat16(v);
        }
    }
}

// ---------------------------------------------------------------------------
extern "C" void kernel_launch(void* const* d_in, const int* in_sizes, int n_in,
                              void* d_out, int out_size, void* d_ws, size_t ws_size,
                              hipStream_t stream)
{
    (void)in_sizes; (void)n_in; (void)out_size;
    const float* pc1    = (const float*)d_in[0];
    const float* pc2    = (const float*)d_in[1];
    const float* feat1  = (const float*)d_in[2];
    const float* feat2  = (const float*)d_in[3];
    const float* wn1_w0 = (const float*)d_in[4];
    const float* wn1_b0 = (const float*)d_in[5];
    const float* wn1_w1 = (const float*)d_in[6];
    const float* wn1_b1 = (const float*)d_in[7];
    const float* wn1_w2 = (const float*)d_in[8];
    const float* wn1_b2 = (const float*)d_in[9];
    const float* lin1_w = (const float*)d_in[10];
    const float* lin1_b = (const float*)d_in[11];
    const float* wn2_w0 = (const float*)d_in[12];
    const float* wn2_b0 = (const float*)d_in[13];
    const float* wn2_w1 = (const float*)d_in[14];
    const float* wn2_b1 = (const float*)d_in[15];
    const float* wn2_w2 = (const float*)d_in[16];
    const float* wn2_b2 = (const float*)d_in[17];
    const float* lin2_w = (const float*)d_in[18];
    const float* lin2_b = (const float*)d_in[19];
    float* out = (float*)d_out;

    const int M  = BB * NPT;
    const int M2 = 2 * M;
    const int K1 = 2 * CDIM * WD;     // 2048
    const int K2 = 2 * MIDD * WD;     // 4096

    char* ws = (char*)d_ws;
    float* p1pm = (float*)ws;
    float* p2pm = p1pm + (size_t)M * CDIM;
    float* fpm  = p2pm + (size_t)M * CDIM;
    bf16*  p1b  = (bf16*)(fpm + (size_t)M2 * MIDD);
    bf16*  p2b  = p1b + (size_t)M * CDIM;
    bf16*  fb   = p2b + (size_t)M * CDIM;
    int* idx12  = (int*)(fb + (size_t)M2 * MIDD);
    int* idx21  = idx12 + (size_t)M * NBR;
    bf16* b1hi  = (bf16*)(idx21 + (size_t)M * NBR);
    bf16* b1lo  = b1hi + (size_t)MIDD * K1;
    bf16* b2hi  = b1lo + (size_t)MIDD * K1;
    bf16* b2lo  = b2hi + (size_t)MIDD * K2;
    float* swbuf = (float*)(b2lo + (size_t)MIDD * K2);
    bf16* aggbuf = (bf16*)(swbuf + (size_t)(M2 + 64) * 16);
    const size_t used = (size_t)((char*)aggbuf - ws);
    const size_t avail = ws_size > used ? ws_size - used : 0;

    float* f1t = out;
    float* fft = out + 2 * (size_t)BB * MIDD * NPT;

    pre_kernel<<<2048 + 2816, 256, 0, stream>>>(
        pc1, pc2, idx12, idx21,
        feat1, feat2, p1pm, p1b, p2pm, p2b,
        lin1_w, b1hi, b1lo, lin2_w, b2hi, b2lo);

    auto chunk_rows = [&](int K) -> int {
        long rows = (long)(avail / ((size_t)K * sizeof(bf16)));
        int cm = (int)(rows > M2 ? M2 : rows) & ~127;
        if (cm < 128) cm = 128;
        return cm;
    };

    {   // cross 1 + cross 2 merged (K = 2048); BM=64, BK=64
        const int CMr = chunk_rows(K1);
        for (int m0 = 0; m0 < M2; m0 += CMr) {
            const int cm = (M2 - m0 < CMr) ? (M2 - m0) : CMr;
            agg_kernel<CDIM, 8><<<cm / 8, 256, 0, stream>>>(
                pc1, pc2, p2b, idx12,
                pc2, pc1, p1b, idx21, M,
                wn1_w0, wn1_b0, wn1_w1, wn1_b1, wn1_w2, wn1_b2,
                aggbuf, swbuf, m0);
            gemm_mfma_k64<64><<<cm / 64, 256, 0, stream>>>(aggbuf, b1hi, b1lo, lin1_b,
                                                           p1pm, swbuf,
                                                           f1t, fpm, fb, m0, K1);
        }
    }
    {   // cross 3 (K = 4096); BM=32, BK=64
        const int CMr = chunk_rows(K2);
        for (int m0 = 0; m0 < M; m0 += CMr) {
            const int cm = (M - m0 < CMr) ? (M - m0) : CMr;
            agg_kernel<MIDD, 4><<<cm / 4, 256, 0, stream>>>(
                pc1, pc2, fb + (size_t)M * MIDD, idx12,
                nullptr, nullptr, nullptr, nullptr, M2,
                wn2_w0, wn2_b0, wn2_w1, wn2_b1, wn2_w2, wn2_b2,
                aggbuf, swbuf, m0);
            gemm_mfma_k64<32><<<cm / 32, 256, 0, stream>>>(aggbuf, b2hi, b2lo, lin2_b,
                                                           fpm, swbuf,
                                                           fft, nullptr, nullptr, m0, K2);
        }
    }
}